// Round 5
// baseline (942.338 us; speedup 1.0000x reference)
//
#include <hip/hip_runtime.h>
#include <hip/hip_bf16.h>

#define NN 100000
#define DD 128
#define VV 3
#define EE 500000
#define TOT (VV * NN)                 // 300000 rows
#define NB ((TOT + 255) / 256)        // 1172 scan blocks
#define RGB ((NN + 127) / 128)        // 782 mfma blocks

typedef unsigned short u16;
typedef unsigned int u32;
typedef short s8v __attribute__((ext_vector_type(8)));   // 8 bf16 (4 VGPRs)
typedef float f4v __attribute__((ext_vector_type(4)));   // MFMA accumulator

__device__ __forceinline__ float bf2f(u16 u) {
    return __uint_as_float(((u32)u) << 16);
}
__device__ __forceinline__ u16 f2bf(float f) {
    u32 x = __float_as_uint(f);
    u32 r = (x + 0x7fffu + ((x >> 16) & 1u)) >> 16;
    return (u16)r;
}

__device__ __forceinline__ float fexp2(float x) {
#if __has_builtin(__builtin_amdgcn_exp2f)
    return __builtin_amdgcn_exp2f(x);
#else
    return exp2f(x);
#endif
}
__device__ __forceinline__ float frcp(float x) {
#if __has_builtin(__builtin_amdgcn_rcpf)
    return __builtin_amdgcn_rcpf(x);
#else
    return 1.f / x;
#endif
}
__device__ __forceinline__ float fsigmoid(float x) {
    return frcp(1.f + fexp2(-1.4426950408889634f * x));
}

// packed bf16 atomic add (fallback path only)
__device__ __forceinline__ void atomAddBf16x2(u16* addr, float f0, float f1) {
#if __has_builtin(__builtin_amdgcn_global_atomic_fadd_v2bf16)
    typedef short v2s __attribute__((ext_vector_type(2)));
    typedef v2s __attribute__((address_space(1)))* v2s_gp;
    v2s v;
    v.x = (short)f2bf(f0);
    v.y = (short)f2bf(f1);
    __builtin_amdgcn_global_atomic_fadd_v2bf16((v2s_gp)(void*)addr, v);
#else
    u32* p = (u32*)addr;
    u32 old = *(volatile u32*)p;
    while (true) {
        float lo = bf2f((u16)(old & 0xffffu)) + f0;
        float hi = bf2f((u16)(old >> 16)) + f1;
        u32 nv = (u32)f2bf(lo) | ((u32)f2bf(hi) << 16);
        u32 prev = atomicCAS(p, old, nv);
        if (prev == old) break;
        old = prev;
    }
#endif
}

// ---- generic VALU GEMM accumulate (fallback path) ----
template<int XSTR, int WSTR>
__device__ __forceinline__ void gemm16(float acc[4][4], const float* Xs,
                                       const float* Ws, int n0, int o0, int kbase) {
    #pragma unroll 4
    for (int kk = 0; kk < 64; kk += 4) {
        float4 w0 = *reinterpret_cast<const float4*>(Ws + (kk + 0) * WSTR + o0);
        float4 w1 = *reinterpret_cast<const float4*>(Ws + (kk + 1) * WSTR + o0);
        float4 w2 = *reinterpret_cast<const float4*>(Ws + (kk + 2) * WSTR + o0);
        float4 w3 = *reinterpret_cast<const float4*>(Ws + (kk + 3) * WSTR + o0);
        #pragma unroll
        for (int i = 0; i < 4; ++i) {
            float4 x = *reinterpret_cast<const float4*>(Xs + (n0 + i) * XSTR + kbase + kk);
            acc[i][0] = fmaf(x.x, w0.x, fmaf(x.y, w1.x, fmaf(x.z, w2.x, fmaf(x.w, w3.x, acc[i][0]))));
            acc[i][1] = fmaf(x.x, w0.y, fmaf(x.y, w1.y, fmaf(x.z, w2.y, fmaf(x.w, w3.y, acc[i][1]))));
            acc[i][2] = fmaf(x.x, w0.z, fmaf(x.y, w1.z, fmaf(x.z, w2.z, fmaf(x.w, w3.z, acc[i][2]))));
            acc[i][3] = fmaf(x.x, w0.w, fmaf(x.y, w1.w, fmaf(x.z, w2.w, fmaf(x.w, w3.w, acc[i][3]))));
        }
    }
}

template<int WSTR, int NT>
__device__ __forceinline__ void stage_w_f32(float* Ws, const float* __restrict__ src, int tid) {
    #pragma unroll
    for (int rep = 0; rep < 2048 / NT; ++rep) {
        int flat = rep * NT + tid;
        int kk = flat >> 5;
        int c4 = flat & 31;
        float4 q = *reinterpret_cast<const float4*>(src + kk * 128 + c4 * 4);
        *reinterpret_cast<float4*>(Ws + kk * WSTR + c4 * 4) = q;
    }
}

template<int XSTR, int NT>
__device__ __forceinline__ void stage_x_f32(float* Xs, const float* __restrict__ src, int tid) {
    #pragma unroll
    for (int rep = 0; rep < 1024 / NT; ++rep) {
        int flat = rep * NT + tid;
        int n = flat >> 5;
        int c4 = flat & 31;
        float4 q = *reinterpret_cast<const float4*>(src + (size_t)n * 128 + c4 * 4);
        *reinterpret_cast<float4*>(Xs + n * XSTR + c4 * 4) = q;
    }
}

template<int XSTR, int NT>
__device__ __forceinline__ void stage_x_bf16(float* Xs, const u16* __restrict__ src, int tid) {
    #pragma unroll
    for (int rep = 0; rep < 512 / NT; ++rep) {
        int flat = rep * NT + tid;
        int n = flat >> 4;
        int c8 = flat & 15;
        uint4 q = *reinterpret_cast<const uint4*>(src + (size_t)n * 128 + c8 * 8);
        float* d = Xs + n * XSTR + c8 * 8;
        d[0] = bf2f((u16)(q.x & 0xffffu)); d[1] = bf2f((u16)(q.x >> 16));
        d[2] = bf2f((u16)(q.y & 0xffffu)); d[3] = bf2f((u16)(q.y >> 16));
        d[4] = bf2f((u16)(q.z & 0xffffu)); d[5] = bf2f((u16)(q.z >> 16));
        d[6] = bf2f((u16)(q.w & 0xffffu)); d[7] = bf2f((u16)(q.w >> 16));
    }
}

// ======== fused-kernel staging / fragment helpers (256 threads) ========

// full 128x128 bf16 weight tile -> Wf (cols 0..127; row padding untouched)
__device__ __forceinline__ void stageWf(u16 (*Wf)[136], const u16* __restrict__ src, int tid) {
    #pragma unroll
    for (int rep = 0; rep < 8; ++rep) {
        int flat = rep * 256 + tid;
        int n = flat >> 4, c8 = flat & 15;
        *reinterpret_cast<uint4*>(&Wf[n][c8 * 8]) =
            *reinterpret_cast<const uint4*>(src + (size_t)n * DD + c8 * 8);
    }
}

// 128x64 half-k weight tile -> Wt (src already offset by h*64)
__device__ __forceinline__ void stageWtHalf(u16 (*Wt)[72], const u16* __restrict__ src, int tid) {
    #pragma unroll
    for (int rep = 0; rep < 4; ++rep) {
        int flat = rep * 256 + tid;
        int n = flat >> 3, c8 = flat & 7;
        *reinterpret_cast<uint4*>(&Wt[n][c8 * 8]) =
            *reinterpret_cast<const uint4*>(src + (size_t)n * DD + c8 * 8);
    }
}

// two [128][64] half-K tiles side-by-side in Wf: A -> cols 0..63, B -> cols 64..127
__device__ __forceinline__ void stageHalf2(u16 (*Wf)[136], const u16* __restrict__ A,
                                           const u16* __restrict__ B, int tid) {
    #pragma unroll
    for (int rep = 0; rep < 4; ++rep) {
        int flat = rep * 256 + tid;
        int n = flat >> 3, c8 = flat & 7;
        *reinterpret_cast<uint4*>(&Wf[n][c8 * 8]) =
            *reinterpret_cast<const uint4*>(A + (size_t)n * DD + c8 * 8);
        *reinterpret_cast<uint4*>(&Wf[n][64 + c8 * 8]) =
            *reinterpret_cast<const uint4*>(B + (size_t)n * DD + c8 * 8);
    }
}

// 128-row X tile (row-clamped) -> Wf
__device__ __forceinline__ void stageX(u16 (*Wf)[136], const u16* __restrict__ src,
                                       int row0, int tid) {
    #pragma unroll
    for (int rep = 0; rep < 8; ++rep) {
        int flat = rep * 256 + tid;
        int n = flat >> 4, c8 = flat & 15;
        int gr = row0 + n; if (gr >= NN) gr = NN - 1;
        *reinterpret_cast<uint4*>(&Wf[n][c8 * 8]) =
            *reinterpret_cast<const uint4*>(src + (size_t)gr * DD + c8 * 8);
    }
}

// A-fragments (whole K=128) for this wave's 32 rows from LDS
__device__ __forceinline__ void loadFrags(s8v af[2][2][2], u16 (*Wf)[136],
                                          int wv, int l15, int quad) {
    #pragma unroll
    for (int h = 0; h < 2; ++h)
        #pragma unroll
        for (int t = 0; t < 2; ++t) {
            int kl = h * 64 + t * 32 + quad * 8;
            af[h][t][0] = *reinterpret_cast<const s8v*>(&Wf[wv * 32 + l15][kl]);
            af[h][t][1] = *reinterpret_cast<const s8v*>(&Wf[wv * 32 + 16 + l15][kl]);
        }
}

// A-fragments (whole K=128) loaded DIRECTLY from global (rows clamped).
// Rows are private to one lane-group -> no reuse -> LDS staging is overhead.
__device__ __forceinline__ void loadFragsG(s8v af[2][2][2], const u16* __restrict__ X,
                                           int row0, int wv, int l15, int quad) {
    int r0 = row0 + wv * 32 + l15;
    int r1 = r0 + 16;
    if (r0 >= NN) r0 = NN - 1;
    if (r1 >= NN) r1 = NN - 1;
    #pragma unroll
    for (int h = 0; h < 2; ++h)
        #pragma unroll
        for (int t = 0; t < 2; ++t) {
            int kl = h * 64 + t * 32 + quad * 8;
            af[h][t][0] = *reinterpret_cast<const s8v*>(X + (size_t)r0 * DD + kl);
            af[h][t][1] = *reinterpret_cast<const s8v*>(X + (size_t)r1 * DD + kl);
        }
}

// acc += af[h] (x) Wt  (half-k, 8 col-tiles, 32 MFMA)
__device__ __forceinline__ void mfmaWt8(f4v acc[2][8], const s8v af[2][2][2], int h,
                                        u16 (*Wt)[72], int l15, int quad) {
    #pragma unroll
    for (int t = 0; t < 2; ++t) {
        int kl = t * 32 + quad * 8;
        #pragma unroll
        for (int c = 0; c < 8; ++c) {
            s8v b = *reinterpret_cast<const s8v*>(&Wt[c * 16 + l15][kl]);
            acc[0][c] = __builtin_amdgcn_mfma_f32_16x16x32_bf16(af[h][t][0], b, acc[0][c], 0, 0, 0);
            acc[1][c] = __builtin_amdgcn_mfma_f32_16x16x32_bf16(af[h][t][1], b, acc[1][c], 0, 0, 0);
        }
    }
}

// acc += af (x) Wf  (full-k, 8 col-tiles, 64 MFMA)
__device__ __forceinline__ void mfmaWfFull(f4v acc[2][8], const s8v af[2][2][2],
                                           u16 (*Wf)[136], int l15, int quad) {
    #pragma unroll
    for (int h = 0; h < 2; ++h)
        #pragma unroll
        for (int t = 0; t < 2; ++t) {
            int kl = h * 64 + t * 32 + quad * 8;
            #pragma unroll
            for (int c = 0; c < 8; ++c) {
                s8v b = *reinterpret_cast<const s8v*>(&Wf[c * 16 + l15][kl]);
                acc[0][c] = __builtin_amdgcn_mfma_f32_16x16x32_bf16(af[h][t][0], b, acc[0][c], 0, 0, 0);
                acc[1][c] = __builtin_amdgcn_mfma_f32_16x16x32_bf16(af[h][t][1], b, acc[1][c], 0, 0, 0);
            }
        }
}

// dual half-K GEMM step: acc1 += af[h] (x) Wf[cols 0..63], acc2 += af[h] (x) Wf[cols 64..127]
__device__ __forceinline__ void mfmaHalf2(f4v acc1[2][8], f4v acc2[2][8],
                                          const s8v af[2][2][2], int h,
                                          u16 (*Wf)[136], int l15, int quad) {
    #pragma unroll
    for (int t = 0; t < 2; ++t) {
        int kl = t * 32 + quad * 8;
        #pragma unroll
        for (int c = 0; c < 8; ++c) {
            s8v bA = *reinterpret_cast<const s8v*>(&Wf[c * 16 + l15][kl]);
            s8v bB = *reinterpret_cast<const s8v*>(&Wf[c * 16 + l15][64 + kl]);
            acc1[0][c] = __builtin_amdgcn_mfma_f32_16x16x32_bf16(af[h][t][0], bA, acc1[0][c], 0, 0, 0);
            acc1[1][c] = __builtin_amdgcn_mfma_f32_16x16x32_bf16(af[h][t][1], bA, acc1[1][c], 0, 0, 0);
            acc2[0][c] = __builtin_amdgcn_mfma_f32_16x16x32_bf16(af[h][t][0], bB, acc2[0][c], 0, 0, 0);
            acc2[1][c] = __builtin_amdgcn_mfma_f32_16x16x32_bf16(af[h][t][1], bB, acc2[1][c], 0, 0, 0);
        }
    }
}

// ---------------- prep: Wsf = selfW @ fusW_top ; c1 = selfb @ fusW_top + fusb ----
__global__ void prep_kernel(const float* __restrict__ selfW, const float* __restrict__ selfb,
                            const float* __restrict__ fusW, const float* __restrict__ fusb,
                            float* __restrict__ Wsf, float* __restrict__ c1) {
    int o = threadIdx.x;
    int k = blockIdx.x;
    if (k < 128) {
        float acc = 0.f;
        for (int m = 0; m < 128; ++m)
            acc += selfW[k * 128 + m] * fusW[m * 128 + o];
        Wsf[k * 128 + o] = acc;
    } else {
        float acc = 0.f;
        for (int m = 0; m < 128; ++m)
            acc += selfb[m] * fusW[m * 128 + o];
        c1[o] = acc + fusb[o];
    }
}

// ---------------- wprep: transpose+convert relW/gateW -> bf16 [v][n][k] ----
__global__ __launch_bounds__(128) void wprep_kernel(
        const float* __restrict__ relW, const float* __restrict__ gateW,
        u16* __restrict__ relWb, u16* __restrict__ gateWb) {
    int k = threadIdx.x;
    int n = blockIdx.x & 127;
    int v = blockIdx.x >> 7;
    size_t o = ((size_t)v * 128 + n) * 128 + k;
    size_t i = ((size_t)v * 128 + k) * 128 + n;
    relWb[o]  = f2bf(relW[i]);
    gateWb[o] = f2bf(gateW[i]);
}

// ---------------- wprep2: bf16 n-major Wsf / featW / fusW_bot ----
__global__ __launch_bounds__(128) void wprep2_kernel(
        const float* __restrict__ Wsf, const float* __restrict__ featW,
        const float* __restrict__ fusW,
        u16* __restrict__ WsfB, u16* __restrict__ featWB, u16* __restrict__ fusWbB) {
    int k = threadIdx.x;
    int n = blockIdx.x;
    WsfB[n * 128 + k]   = f2bf(Wsf[k * 128 + n]);
    featWB[n * 128 + k] = f2bf(featW[k * 128 + n]);
    fusWbB[n * 128 + k] = f2bf(fusW[(size_t)(128 + k) * 128 + n]);
}

// ---------------- wprep3: attW1 [c][k][h] -> bf16 n-major [o=c*64+h][k] ----
__global__ __launch_bounds__(128) void wprep3_kernel(
        const float* __restrict__ attW1, u16* __restrict__ attW1B) {
    int k = threadIdx.x;
    int o = blockIdx.x;                 // 0..127
    int c = o >> 6, h = o & 63;
    attW1B[o * 128 + k] = f2bf(attW1[((size_t)c * 128 + k) * 64 + h]);
}

// ---------------- wprep4: vattW1p[v][h][k] = bf16(view_pref[v][k] * vattW1[k][h]) ----
__global__ __launch_bounds__(128) void wprep4_kernel(
        const float* __restrict__ vattW1, const float* __restrict__ view_pref,
        u16* __restrict__ vattW1p) {
    int k = threadIdx.x;
    int h = blockIdx.x & 63;
    int v = blockIdx.x >> 6;            // 0..2
    vattW1p[((size_t)v * 64 + h) * 128 + k] =
        f2bf(view_pref[v * 128 + k] * vattW1[k * 64 + h]);
}

// ---------------- wprep5: W12b[v][p][d] = bf16(relW[v]@gateW[v]) n-major;
//                  rgb[v][p] = relb[v]@gateW[v] ----
__global__ __launch_bounds__(128) void wprep5_kernel(
        const float* __restrict__ relW, const float* __restrict__ gateW,
        const float* __restrict__ relb,
        u16* __restrict__ W12b, float* __restrict__ rgb) {
    int p = threadIdx.x;
    int b = blockIdx.x;                 // v*129 + d  (d==128 -> rgb row)
    int v = b / 129;
    int d = b - v * 129;
    const float* gW = gateW + (size_t)v * 128 * 128;
    if (d < 128) {
        const float* rW = relW + ((size_t)v * 128 + d) * 128;
        float acc = 0.f;
        for (int o = 0; o < 128; ++o) acc += rW[o] * gW[o * 128 + p];
        W12b[((size_t)v * 128 + p) * 128 + d] = f2bf(acc);
    } else {
        const float* rb = relb + (size_t)v * 128;
        float acc = 0.f;
        for (int o = 0; o < 128; ++o) acc += rb[o] * gW[o * 128 + p];
        rgb[v * 128 + p] = acc;
    }
}

// ---------------- featconv: feat fp32 -> bf16 ----
__global__ __launch_bounds__(256) void featconv_kernel(
        const float* __restrict__ feat, u16* __restrict__ featB) {
    int t = blockIdx.x * 256 + threadIdx.x;   // 3.2M float4 chunks
    float4 q = *reinterpret_cast<const float4*>(feat + (size_t)t * 4);
    ushort4 r;
    r.x = f2bf(q.x); r.y = f2bf(q.y); r.z = f2bf(q.z); r.w = f2bf(q.w);
    *reinterpret_cast<ushort4*>(featB + (size_t)t * 4) = r;
}

// ================= CSR build (hierarchical scan) + gather =================

__global__ __launch_bounds__(256) void count_kernel(
        const int* __restrict__ edst, int* __restrict__ C) {
    int t = blockIdx.x * 256 + threadIdx.x;
    if (t >= VV * EE) return;
    int v = t / EE;
    atomicAdd(&C[v * NN + edst[t]], 1);
}

__global__ __launch_bounds__(256) void scanA_kernel(
        const int* __restrict__ C, int* __restrict__ bs) {
    int b = blockIdx.x, t = threadIdx.x;
    int i = b * 256 + t;
    int v = (i < TOT) ? C[i] : 0;
    __shared__ int s[256];
    s[t] = v;
    __syncthreads();
    #pragma unroll
    for (int off = 128; off > 0; off >>= 1) {
        if (t < off) s[t] += s[t + off];
        __syncthreads();
    }
    if (t == 0) bs[b] = s[0];
}

__global__ __launch_bounds__(1024) void scanB_kernel(int* __restrict__ bs) {
    __shared__ int s[2048];
    int t = threadIdx.x;
    int v0 = (t < NB) ? bs[t] : 0;
    int v1 = (t + 1024 < NB) ? bs[t + 1024] : 0;
    s[t] = v0; s[t + 1024] = v1;
    __syncthreads();
    #pragma unroll
    for (int off = 1; off < 2048; off <<= 1) {
        int x0 = (t >= off) ? s[t - off] : 0;
        int x1 = (t + 1024 >= off) ? s[t + 1024 - off] : 0;
        __syncthreads();
        s[t] += x0; s[t + 1024] += x1;
        __syncthreads();
    }
    if (t < NB) bs[t] = s[t] - v0;
    if (t + 1024 < NB) bs[t + 1024] = s[t + 1024] - v1;
}

__global__ __launch_bounds__(256) void scanC_kernel(
        int* __restrict__ C, const int* __restrict__ bs) {
    int b = blockIdx.x, t = threadIdx.x;
    int i = b * 256 + t;
    int v = (i < TOT) ? C[i] : 0;
    __shared__ int s[256];
    s[t] = v;
    __syncthreads();
    #pragma unroll
    for (int off = 1; off < 256; off <<= 1) {
        int x = (t >= off) ? s[t - off] : 0;
        __syncthreads();
        s[t] += x;
        __syncthreads();
    }
    if (i < TOT) C[i] = s[t] - v + bs[b];
}

// fill: packed (src, w) per bucket slot; C becomes inclusive row ends
__global__ __launch_bounds__(256) void fill_kernel(
        const int* __restrict__ esrc, const int* __restrict__ edst,
        const float* __restrict__ ew, int* __restrict__ C,
        int2* __restrict__ bsw) {
    int t = blockIdx.x * 256 + threadIdx.x;
    if (t >= VV * EE) return;
    int v = t / EE;
    int pos = atomicAdd(&C[v * NN + edst[t]], 1);
    int2 p;
    p.x = esrc[t];
    p.y = __float_as_int(ew[t]);
    bsw[pos] = p;
}

// one wave per (v,dst) row, unroll-4 to overlap the load chains
__global__ __launch_bounds__(256) void gather_kernel(
        const u16* __restrict__ featB, const int* __restrict__ C,
        const int2* __restrict__ bsw,
        u16* __restrict__ aggB, float* __restrict__ wsum) {
    int wid = (blockIdx.x * 256 + threadIdx.x) >> 6;
    int lane = threadIdx.x & 63;
    int end = C[wid];
    int start = (wid == 0) ? 0 : C[wid - 1];
    float a0 = 0.f, a1 = 0.f, wacc = 0.f;
    int e = start;
    for (; e + 4 <= end; e += 4) {
        int2 p0 = bsw[e], p1 = bsw[e + 1], p2 = bsw[e + 2], p3 = bsw[e + 3];
        u32 f0 = *reinterpret_cast<const u32*>(featB + (size_t)p0.x * DD + lane * 2);
        u32 f1 = *reinterpret_cast<const u32*>(featB + (size_t)p1.x * DD + lane * 2);
        u32 f2 = *reinterpret_cast<const u32*>(featB + (size_t)p2.x * DD + lane * 2);
        u32 f3 = *reinterpret_cast<const u32*>(featB + (size_t)p3.x * DD + lane * 2);
        float w0 = __int_as_float(p0.y), w1 = __int_as_float(p1.y);
        float w2 = __int_as_float(p2.y), w3 = __int_as_float(p3.y);
        a0 = fmaf(w0, bf2f((u16)(f0 & 0xffffu)), a0);
        a1 = fmaf(w0, bf2f((u16)(f0 >> 16)), a1);
        a0 = fmaf(w1, bf2f((u16)(f1 & 0xffffu)), a0);
        a1 = fmaf(w1, bf2f((u16)(f1 >> 16)), a1);
        a0 = fmaf(w2, bf2f((u16)(f2 & 0xffffu)), a0);
        a1 = fmaf(w2, bf2f((u16)(f2 >> 16)), a1);
        a0 = fmaf(w3, bf2f((u16)(f3 & 0xffffu)), a0);
        a1 = fmaf(w3, bf2f((u16)(f3 >> 16)), a1);
        wacc += (w0 + w1) + (w2 + w3);
    }
    for (; e < end; ++e) {
        int2 p = bsw[e];
        float w = __int_as_float(p.y);
        u32 f = *reinterpret_cast<const u32*>(featB + (size_t)p.x * DD + lane * 2);
        a0 = fmaf(w, bf2f((u16)(f & 0xffffu)), a0);
        a1 = fmaf(w, bf2f((u16)(f >> 16)), a1);
        wacc += w;
    }
    u32 packed = (u32)f2bf(a0) | ((u32)f2bf(a1) << 16);
    *reinterpret_cast<u32*>(aggB + (size_t)wid * DD + lane * 2) = packed;
    if (lane == 0) wsum[wid] = wacc;
}

// ================= fallback: atomic scatter =================
__global__ __launch_bounds__(256) void scatter_kernel(
        const int* __restrict__ esrc, const int* __restrict__ edst,
        const float* __restrict__ ew, const float* __restrict__ feat,
        u16* __restrict__ aggB, float* __restrict__ wsum) {
    long long t = (long long)blockIdx.x * 256 + threadIdx.x;
    int lane = (int)(t & 31);
    int eg = (int)(t >> 5);
    int v = eg / EE;
    int src = 0, dst = 0; float w = 0.f;
    if (lane == 0) {
        src = esrc[eg]; dst = edst[eg]; w = ew[eg];
    }
    src = __shfl(src, 0, 32);
    dst = __shfl(dst, 0, 32);
    w   = __shfl(w, 0, 32);
    const float* fr = feat + (size_t)src * DD + lane * 4;
    float4 q = *reinterpret_cast<const float4*>(fr);
    u16* outp = aggB + ((size_t)v * NN + dst) * DD + lane * 4;
    atomAddBf16x2(outp,     w * q.x, w * q.y);
    atomAddBf16x2(outp + 2, w * q.z, w * q.w);
    if (lane == 0) atomicAdd(wsum + v * NN + dst, w);
}

// ---------------- MFMA label attention: node_att + class_probs ----
__global__ __launch_bounds__(256) void label_mfma_kernel(
        const u16* __restrict__ featB, const u16* __restrict__ attW1B,
        const float* __restrict__ clsW, const float* __restrict__ clsb,
        const float* __restrict__ attb1, const float* __restrict__ attW2,
        const float* __restrict__ attb2, const float* __restrict__ att_bias,
        float* __restrict__ node_att, float* __restrict__ probs_out) {
    __shared__ u16 Xs[128][136];
    __shared__ u16 Wt[128][72];
    int tid = threadIdx.x;
    int wv = tid >> 6, lane = tid & 63;
    int quad = lane >> 4, l15 = lane & 15;
    int row0 = blockIdx.x * 128;

    stageX(Xs, featB, row0, tid);
    stageWtHalf(Wt, attW1B, tid);
    __syncthreads();
    s8v af[2][2][2];
    loadFrags(af, Xs, wv, l15, quad);
    f4v acc[2][8];
    #pragma unroll
    for (int rt = 0; rt < 2; ++rt)
        #pragma unroll
        for (int c = 0; c < 8; ++c)
            acc[rt][c] = f4v{0.f, 0.f, 0.f, 0.f};
    mfmaWt8(acc, af, 0, Wt, l15, quad);
    __syncthreads();
    stageWtHalf(Wt, attW1B + 64, tid);
    __syncthreads();
    mfmaWt8(acc, af, 1, Wt, l15, quad);

    float ab1[8], aw2[8];
    #pragma unroll
    for (int c = 0; c < 8; ++c) {
        int col = c * 16 + l15;
        ab1[c] = attb1[col];
        aw2[c] = attW2[col];
    }
    float cw0[8], cw1[8];
    #pragma unroll
    for (int j = 0; j < 8; ++j) {
        int k = l15 * 8 + j;
        cw0[j] = clsW[k * 2];
        cw1[j] = clsW[k * 2 + 1];
    }
    float cb0 = clsb[0], cb1 = clsb[1];
    float b20 = attb2[0], b21 = attb2[1];
    float abias = att_bias[0];

    #pragma unroll
    for (int rt = 0; rt < 2; ++rt)
        #pragma unroll
        for (int r = 0; r < 4; ++r) {
            int n = wv * 32 + rt * 16 + quad * 4 + r;
            int gr = row0 + n;
            float p0 = 0.f, p1 = 0.f;
            #pragma unroll
            for (int c = 0; c < 4; ++c) {
                float hv = acc[rt][c][r] + ab1[c];
                hv = hv > 0.f ? hv : 0.f;
                p0 += hv * aw2[c];
            }
            #pragma unroll
            for (int c = 4; c < 8; ++c) {
                float hv = acc[rt][c][r] + ab1[c];
                hv = hv > 0.f ? hv : 0.f;
                p1 += hv * aw2[c];
            }
            uint4 q = *reinterpret_cast<const uint4*>(&Xs[n][l15 * 8]);
            float f[8];
            f[0] = bf2f((u16)(q.x & 0xffffu)); f[1] = bf2f((u16)(q.x >> 16));
            f[2] = bf2f((u16)(q.y & 0xffffu)); f[3] = bf2f((u16)(q.y >> 16));
            f[4] = bf2f((u16)(q.z & 0xffffu)); f[5] = bf2f((u16)(q.z >> 16));
            f[6] = bf2f((u16)(q.w & 0xffffu)); f[7] = bf2f((u16)(q.w >> 16));
            float l0 = 0.f, l1 = 0.f;
            #pragma unroll
            for (int j = 0; j < 8; ++j) {
                l0 = fmaf(f[j], cw0[j], l0);
                l1 = fmaf(f[j], cw1[j], l1);
            }
            #pragma unroll
            for (int m = 1; m < 16; m <<= 1) {
                p0 += __shfl_xor(p0, m);
                p1 += __shfl_xor(p1, m);
                l0 += __shfl_xor(l0, m);
                l1 += __shfl_xor(l1, m);
            }
            if (l15 == 0 && gr < NN) {
                float s0 = 1.f / (1.f + expf(-(p0 + b20)));
                float s1 = 1.f / (1.f + expf(-(p1 + b21)));
                l0 += cb0; l1 += cb1;
                float mm = fmaxf(l0, l1);
                float e0 = expf(l0 - mm), e1 = expf(l1 - mm);
                float inv = 1.f / (e0 + e1);
                float q0 = e0 * inv, q1 = e1 * inv;
                node_att[gr] = q0 * s0 + q1 * s1 + abias;
                probs_out[gr * 2]     = q0;
                probs_out[gr * 2 + 1] = q1;
            }
        }
}

// ---------------- fallback VALU label ----------------
__global__ __launch_bounds__(256) void label_kernel(
        const float* __restrict__ feat, const float* __restrict__ clsW, const float* __restrict__ clsb,
        const float* __restrict__ attW1, const float* __restrict__ attb1,
        const float* __restrict__ attW2, const float* __restrict__ attb2,
        const float* __restrict__ att_bias,
        float* __restrict__ node_att, float* __restrict__ probs_out) {
    __shared__ float Xs[32][132];
    __shared__ float Ws[64][132];
    int tid = threadIdx.x;
    int row0 = blockIdx.x * 32;
    stage_x_f32<132, 256>(&Xs[0][0], feat + (size_t)row0 * DD, tid);
    int to = tid & 31, tn = tid >> 5;
    int o0 = to * 4, n0 = tn * 4;
    float acc[4][4] = {};
    for (int half = 0; half < 2; ++half) {
        __syncthreads();
        #pragma unroll
        for (int rep = 0; rep < 8; ++rep) {
            int flat = rep * 256 + tid;
            int kk = flat >> 5, o4 = flat & 31;
            int o = o4 * 4;
            int c = o >> 6, h = o & 63;
            int k = half * 64 + kk;
            float4 q = *reinterpret_cast<const float4*>(attW1 + (size_t)(c * 128 + k) * 64 + h);
            *reinterpret_cast<float4*>(&Ws[kk][o]) = q;
        }
        __syncthreads();
        gemm16<132, 132>(acc, &Xs[0][0], &Ws[0][0], n0, o0, half * 64);
    }
    int c = o0 >> 6, h0 = o0 & 63;
    float b1j[4], w2j[4];
    #pragma unroll
    for (int j = 0; j < 4; ++j) {
        b1j[j] = attb1[c * 64 + h0 + j];
        w2j[j] = attW2[c * 64 + h0 + j];
    }
    float part[4];
    #pragma unroll
    for (int i = 0; i < 4; ++i) {
        float s = 0.f;
        #pragma unroll
        for (int j = 0; j < 4; ++j) {
            float hv = acc[i][j] + b1j[j];
            hv = hv > 0.f ? hv : 0.f;
            s += hv * w2j[j];
        }
        part[i] = s;
    }
    __syncthreads();
    float* red = &Ws[0][0];          // [32][33]
    float* Ssc = red + 32 * 33;      // [32][2]
    float* Lsc = Ssc + 64;           // [32][2]
    #pragma unroll
    for (int i = 0; i < 4; ++i) red[(n0 + i) * 33 + to] = part[i];
    __syncthreads();
    if (tid < 64) {
        int n = tid >> 1, cc = tid & 1;
        float l = 0.f;
        for (int k = 0; k < 128; k += 4) {
            float4 x = *reinterpret_cast<const float4*>(&Xs[n][k]);
            l += x.x * clsW[(k + 0) * 2 + cc];
            l += x.y * clsW[(k + 1) * 2 + cc];
            l += x.z * clsW[(k + 2) * 2 + cc];
            l += x.w * clsW[(k + 3) * 2 + cc];
        }
        Lsc[n * 2 + cc] = l + clsb[cc];
        float s = 0.f;
        for (int u = 0; u < 16; ++u) s += red[n * 33 + cc * 16 + u];
        s += attb2[cc];
        Ssc[n * 2 + cc] = 1.f / (1.f + expf(-s));
    }
    __syncthreads();
    if (tid < 32) {
        int n = tid;
        float l0 = Lsc[n * 2], l1 = Lsc[n * 2 + 1];
        float m = fmaxf(l0, l1);
        float e0 = expf(l0 - m), e1 = expf(l1 - m);
        float inv = 1.f / (e0 + e1);
        float p0 = e0 * inv, p1 = e1 * inv;
        float na = p0 * Ssc[n * 2] + p1 * Ssc[n * 2 + 1] + att_bias[0];
        int row = row0 + n;
        node_att[row] = na;
        probs_out[row * 2]     = p0;
        probs_out[row * 2 + 1] = p1;
    }
}

// ---------------- MFMA relgate: VIEW LOOP INSIDE ----
// Grid = RGB (1-D); each block processes its 128 rows for v=0,1,2 in sequence.
// All 782 blocks are co-resident (34.8 KB LDS -> 4 blocks/CU), so at any
// instant the machine streams ONE view slab (~51 MB r+w) -> L3-resident,
// no thrash. Per-view compute = R4's harness-verified path (dual half-K
// GEMM from one buffer, reg gate-pack, same-wave LDS transpose, streamed
// 16 KB score-B).
__global__ __launch_bounds__(256, 4) void relgate_mfma_kernel(
        const u16* __restrict__ relWb, const float* __restrict__ relb,
        const u16* __restrict__ W12b, const float* __restrict__ rgbv,
        const float* __restrict__ gateb,
        const u16* __restrict__ vattW1p, const float* __restrict__ vattb1,
        const float* __restrict__ vattW2, const float* __restrict__ vattb2,
        u16* __restrict__ aggB, const float* __restrict__ wsum,
        float* __restrict__ vscores) {
    __shared__ u16 Wf[128][136];
    int tid = threadIdx.x;
    int wv = tid >> 6, lane = tid & 63;
    int quad = lane >> 4, l15 = lane & 15;
    int row0 = blockIdx.x * 128;

    for (int v = 0; v < VV; ++v) {
        const size_t vbase = (size_t)v * NN;

        // A-fragments direct from global (rows private to lane-groups)
        s8v af[2][2][2];
        loadFragsG(af, aggB + vbase * DD, row0, wv, l15, quad);

        const u16* W1 = relWb + (size_t)v * DD * DD;
        const u16* W2 = W12b + (size_t)v * DD * DD;

        float wsn[2][4];
        #pragma unroll
        for (int rt = 0; rt < 2; ++rt)
            #pragma unroll
            for (int r = 0; r < 4; ++r) {
                int gr = row0 + wv * 32 + rt * 16 + quad * 4 + r;
                wsn[rt][r] = wsum[vbase + (gr < NN ? gr : NN - 1)];
            }

        f4v acc1[2][8], acc2[2][8];
        #pragma unroll
        for (int rt = 0; rt < 2; ++rt)
            #pragma unroll
            for (int c = 0; c < 8; ++c) {
                acc1[rt][c] = f4v{0.f, 0.f, 0.f, 0.f};
                acc2[rt][c] = f4v{0.f, 0.f, 0.f, 0.f};
            }

        __syncthreads();                    // Wf free (prev view's score GEMM done)
        stageHalf2(Wf, W1, W2, tid);
        __syncthreads();
        mfmaHalf2(acc1, acc2, af, 0, Wf, l15, quad);
        __syncthreads();
        stageHalf2(Wf, W1 + 64, W2 + 64, tid);
        __syncthreads();
        mfmaHalf2(acc1, acc2, af, 1, Wf, l15, quad);

        // gate pack (register-only)
        u32 gpk[2][8][2];
        #pragma unroll
        for (int c = 0; c < 8; ++c) {
            int col = c * 16 + l15;
            float rg2 = rgbv[v * DD + col];
            float gb2 = gateb[v * DD + col];
            #pragma unroll
            for (int rt = 0; rt < 2; ++rt)
                #pragma unroll
                for (int rp = 0; rp < 2; ++rp) {
                    float g0 = fsigmoid(acc2[rt][c][2 * rp]     + wsn[rt][2 * rp] * rg2 + gb2);
                    float g1 = fsigmoid(acc2[rt][c][2 * rp + 1] + wsn[rt][2 * rp + 1] * rg2 + gb2);
                    gpk[rt][c][rp] = (u32)f2bf(g0) | ((u32)f2bf(g1) << 16);
                }
        }
        __syncthreads();                    // all waves done reading Wf weights

        // view_out = gate * (agg + wsum*relb) -> Wf (own 32 rows, C-layout)
        #pragma unroll
        for (int c = 0; c < 8; ++c) {
            float rbc = relb[v * DD + c * 16 + l15];
            #pragma unroll
            for (int rt = 0; rt < 2; ++rt)
                #pragma unroll
                for (int r = 0; r < 4; ++r) {
                    float a = acc1[rt][c][r] + wsn[rt][r] * rbc;
                    u32 gp = gpk[rt][c][r >> 1];
                    float g = bf2f((u16)((r & 1) ? (gp >> 16) : (gp & 0xffffu)));
                    Wf[wv * 32 + rt * 16 + quad * 4 + r][c * 16 + l15] = f2bf(g * a);
                }
        }

        // store view_out -> aggB (own rows)
        #pragma unroll
        for (int rep = 0; rep < 8; ++rep) {
            int n = wv * 32 + rep * 4 + quad;
            int gr = row0 + n;
            if (gr < NN)
                *reinterpret_cast<uint4*>(aggB + (vbase + gr) * DD + l15 * 8) =
                    *reinterpret_cast<const uint4*>(&Wf[n][l15 * 8]);
        }

        // view-score GEMM: A = view_out (own LDS rows, same-wave RAW),
        // B = vattW1p streamed from L2 (16 KB, shared by all blocks)
        s8v a2[2][2][2];
        loadFrags(a2, Wf, wv, l15, quad);
        const u16* Wv = vattW1p + (size_t)v * 64 * DD;
        f4v acc3[2][4];
        #pragma unroll
        for (int rt = 0; rt < 2; ++rt)
            #pragma unroll
            for (int c = 0; c < 4; ++c)
                acc3[rt][c] = f4v{0.f, 0.f, 0.f, 0.f};
        #pragma unroll
        for (int h = 0; h < 2; ++h)
            #pragma unroll
            for (int t = 0; t < 2; ++t) {
                int kl = t * 32 + quad * 8;
                #pragma unroll
                for (int c = 0; c < 4; ++c) {
                    s8v b = *reinterpret_cast<const s8v*>(
                        Wv + (size_t)(c * 16 + l15) * DD + h * 64 + kl);
                    acc3[0][c] = __builtin_amdgcn_mfma_f32_16x16x32_bf16(a2[h][t][0], b, acc3[0][c], 0, 0, 0);
                    acc3[1][c] = __builtin_amdgcn_mfma_f32_16x16x32_bf16(a2[h][t][1], b, acc3[1][c], 0, 0, 0);
                }
            }
        float vb1[4], vw2[4];
        #pragma unroll
        for (int c = 0; c < 4; ++c) {
            int col = c * 16 + l15;
            vb1[c] = vattb1[col];
            vw2[c] = vattW2[col];
        }
        float vb2 = vattb2[0];
        #pragma unroll
        for (int rt = 0; rt < 2; ++rt)
            #pragma unroll
            for (int r = 0; r < 4; ++r) {
                float p = 0.f;
                #pragma unroll
                for (int c = 0; c < 4; ++c) {
                    float hv = acc3[rt][c][r] + vb1[c];
                    hv = hv > 0.f ? hv : 0.f;
                    p += hv * vw2[c];
                }
                #pragma unroll
                for (int m = 1; m < 16; m <<= 1)
                    p += __shfl_xor(p, m);
                int gr = row0 + wv * 32 + rt * 16 + quad * 4 + r;
                if (l15 == 0 && gr < NN)
                    vscores[vbase + gr] = p + vb2;
            }
    }
}

// ---------------- fallback VALU relgate ----------------
__global__ __launch_bounds__(256) void relgate_kernel(
        const float* __restrict__ relW, const float* __restrict__ relb,
        const float* __restrict__ gateW, const float* __restrict__ gateb,
        u16* __restrict__ aggB, const float* __restrict__ wsum) {
    __shared__ float Xs[32][128];
    __shared__ float Ws[64][132];
    int tid = threadIdx.x;
    int v = blockIdx.y;
    int row0 = blockIdx.x * 32;
    u16* base = aggB + ((size_t)v * NN + row0) * DD;
    stage_x_bf16<128, 256>(&Xs[0][0], base, tid);
    int to = tid & 31, tn = tid >> 5;
    int o0 = to * 4, n0 = tn * 4;
    float acc[4][4] = {};
    const float* W1 = relW + (size_t)v * DD * DD;
    for (int half = 0; half < 2; ++half) {
        __syncthreads();
        stage_w_f32<132, 256>(&Ws[0][0], W1 + half * 64 * DD, tid);
        __syncthreads();
        gemm16<128, 132>(acc, &Xs[0][0], &Ws[0][0], n0, o0, half * 64);
    }
    float wsn[4], rb[4];
    #pragma unroll
    for (int i = 0; i < 4; ++i) wsn[i] = wsum[v * NN + row0 + n0 + i];
    #pragma unroll
    for (int j = 0; j < 4; ++j) rb[j] = relb[v * DD + o0 + j];
    #pragma unroll
    for (int i = 0; i < 4; ++i)
        #pragma unroll
        for (int j = 0; j < 4; ++j) acc[i][j] += wsn[i] * rb[j];
    __syncthreads();
    #pragma unroll
    for (int i = 0; i < 4; ++i)
        *reinterpret_cast<float4*>(&Xs[n0 + i][o0]) = make_float4(acc[i][0], acc[i][1], acc[i][2], acc[i][3]);
    float acc2[4][4] = {};
    const float* W2 = gateW + (size_t)v * DD * DD;
    for (int half = 0; half < 2; ++half) {
        __syncthreads();
        stage_w_f32<132, 256>(&Ws[0][0], W2 + half * 64 * DD, tid);
        __syncthreads();
        gemm16<128, 132>(acc2, &Xs[0][0], &Ws[0][0], n0, o0, half * 64);
    }
    float gb[4];
    #pragma unroll
    for (int j = 0; j < 4; ++j) gb[j] = gateb[v * DD + o0 + j];
    #pragma unroll
    for (int i = 0; i < 4; ++i) {
        float g0 = 1.f / (1.f + expf(-(acc2[i][0] + gb[0])));
        float g1 = 1.f / (1.f + expf(-(acc2[i][1] + gb[1])));
        float g2 = 1.f / (1.f + expf(-(acc2[i][2] + gb[2])));
        float g3 = 1.f / (1.f + expf(-(acc2[i][3] + gb[3])));
        ushort4 r;
        r.x = f2bf(g0 * acc[i][0]); r.y = f2bf(g1 * acc[i][1]);
        r.z = f2bf(g2 * acc[i][2]); r.w = f2bf(g3 * acc[i][3]);
        *reinterpret_cast<ushort4*>(base + (size_t)(n0 + i) * DD + o0) = r;
    }
}

// ---------------- fallback view attention scores ----------------
__global__ __launch_bounds__(128) void vatt_kernel(
        const u16* __restrict__ aggB, const float* __restrict__ view_pref,
        const float* __restrict__ vattW1, const float* __restrict__ vattb1,
        const float* __restrict__ vattW2, const float* __restrict__ vattb2,
        float* __restrict__ vscores) {
    __shared__ float Xs[32][132];
    __shared__ float Ws[128][68];
    int tid = threadIdx.x;
    int v = blockIdx.y;
    int row0 = blockIdx.x * 32;
    const u16* base = aggB + ((size_t)v * NN + row0) * DD;
    #pragma unroll
    for (int rep = 0; rep < 4; ++rep) {
        int flat = rep * 128 + tid;
        int n = flat >> 4, c8 = flat & 15;
        uint4 q = *reinterpret_cast<const uint4*>(base + (size_t)n * DD + c8 * 8);
        float4 pa = *reinterpret_cast<const float4*>(view_pref + v * DD + c8 * 8);
        float4 pb = *reinterpret_cast<const float4*>(view_pref + v * DD + c8 * 8 + 4);
        float* d = &Xs[n][c8 * 8];
        d[0] = bf2f((u16)(q.x & 0xffffu)) * pa.x; d[1] = bf2f((u16)(q.x >> 16)) * pa.y;
        d[2] = bf2f((u16)(q.y & 0xffffu)) * pa.z; d[3] = bf2f((u16)(q.y >> 16)) * pa.w;
        d[4] = bf2f((u16)(q.z & 0xffffu)) * pb.x; d[5] = bf2f((u16)(q.z >> 16)) * pb.y;
        d[6] = bf2f((u16)(q.w & 0xffffu)) * pb.z; d[7] = bf2f((u16)(q.w >> 16)) * pb.w;
    }
    #pragma unroll
    for (int rep = 0; rep < 16; ++rep) {
        int flat = rep * 128 + tid;
        int k = flat >> 4, c4 = flat & 15;
        float4 q = *reinterpret_cast<const float4*>(vattW1 + k * 64 + c4 * 4);
        *reinterpret_cast<float4*>(&Ws[k][c4 * 4]) = q;
    }
    __syncthreads();
    int to = tid & 15, tn = tid >> 4;
    int o0 = to * 4, n0 = tn * 4;
    float acc[4][4] = {};
    gemm16<132, 68>(acc, &Xs[0][0], &Ws[0][0], n0, o0, 0);
    gemm16<132, 68>(acc, &Xs[0][0], &Ws[64][0], n0, o0, 64);
    float b1[4], w2[4];
    #pragma unroll
    for (int j = 0; j < 4; ++j) {
        b1[j] = vattb1[o0 + j];
        w2[j] = vattW2[o0 + j];
    }
    float part[4];
    #pragma unroll
    for (int i = 0; i < 4; ++i) {
        float s = 0.f;
        #pragma unroll
        for (int j = 0; j < 4; ++j) {
            float hv = acc[i][j] + b1[j];
            hv = hv > 0.f ? hv : 0.f;
            s += hv * w2[j];
        }
        part[i] = s;
    }
    __syncthreads();
    float* red = &Ws[0][0];   // [32][17]
    #pragma unroll
    for (int i = 0; i < 4; ++i) red[(n0 + i) * 17 + to] = part[i];
    __syncthreads();
    if (tid < 32) {
        float s = 0.f;
        for (int u = 0; u < 16; ++u) s += red[tid * 17 + u];
        vscores[(size_t)v * NN + row0 + tid] = s + vattb2[0];
    }
}

// ---------------- fallback combine ----------------
__global__ __launch_bounds__(256) void combine_kernel(
        u16* __restrict__ aggB, const float* __restrict__ vscores,
        const float* __restrict__ node_att) {
    int t = blockIdx.x * 256 + threadIdx.x;
    int n = t >> 5, c4 = t & 31;
    float s0 = vscores[n], s1 = vscores[NN + n], s2 = vscores[2 * NN + n];
    float m = fmaxf(s0, fmaxf(s1, s2));
    float e0 = expf(s0 - m), e1 = expf(s1 - m), e2 = expf(s2 - m);
    float inv = 1.f / (e0 + e1 + e2);
    float w0 = e0 * inv, w1 = e1 * inv, w2 = e2 * inv;
    float na = node_att[n];
    size_t off = (size_t)n * DD + c4 * 4;
    ushort4 q0 = *reinterpret_cast<const ushort4*>(aggB + off);
    ushort4 q1 = *reinterpret_cast<const ushort4*>(aggB + (size_t)NN * DD + off);
    ushort4 q2 = *reinterpret_cast<const ushort4*>(aggB + 2 * (size_t)NN * DD + off);
    ushort4 r;
    r.x = f2bf((bf2f(q0.x) * w0 + bf2f(q1.x) * w1 + bf2f(q2.x) * w2) * na);
    r.y = f2bf((bf2f(q0.y) * w0 + bf2f(q1.y) * w1 + bf2f(q2.y) * w2) * na);
    r.z = f2bf((bf2f(q0.z) * w0 + bf2f(q1.z) * w1 + bf2f(q2.z) * w2) * na);
    r.w = f2bf((bf2f(q0.w) * w0 + bf2f(q1.w) * w1 + bf2f(q2.w) * w2) * na);
    *reinterpret_cast<ushort4*>(aggB + off) = r;
}

// ---------------- MFMA final + fused combine (R1 version, unchanged) ----
__global__ __launch_bounds__(256, 3) void final_mfma_kernel(
        const u16* __restrict__ featB, const u16* __restrict__ aggB,
        const float* __restrict__ vsc, const float* __restrict__ natt,
        const u16* __restrict__ WsfB, const u16* __restrict__ featWB,
        const u16* __restrict__ fusWbB,
        const float* __restrict__ c1, const float* __restrict__ featb,
        const float* __restrict__ ln_g, const float* __restrict__ ln_b,
        float* __restrict__ outp) {
    __shared__ u16 Wf[128][136];   // cols 128..133 hold 3 f32 combine weights/row
    __shared__ u16 Wt[128][72];
    int tid = threadIdx.x;
    int wv = tid >> 6, lane = tid & 63;
    int quad = lane >> 4, l15 = lane & 15;
    int row0 = blockIdx.x * 128;

    #pragma unroll
    for (int rep = 0; rep < 8; ++rep) {
        int flat = rep * 256 + tid;
        int n = flat >> 4, c8 = flat & 15;
        int gr = row0 + n; if (gr >= NN) gr = NN - 1;
        uint4 q = *reinterpret_cast<const uint4*>(featB + (size_t)gr * DD + c8 * 8);
        *reinterpret_cast<uint4*>(&Wf[n][c8 * 8]) = q;
    }
    // per-row combine weights -> Wf row padding
    if (tid < 128) {
        int gr = row0 + tid; if (gr >= NN) gr = NN - 1;
        float s0 = vsc[gr], s1 = vsc[NN + gr], s2 = vsc[2 * NN + gr];
        float m = fmaxf(s0, fmaxf(s1, s2));
        const float L2E = 1.4426950408889634f;
        float e0 = fexp2((s0 - m) * L2E);
        float e1 = fexp2((s1 - m) * L2E);
        float e2 = fexp2((s2 - m) * L2E);
        float na = natt[gr] * frcp(e0 + e1 + e2);
        float* rwp = reinterpret_cast<float*>(&Wf[tid][128]);
        rwp[0] = e0 * na;
        rwp[1] = e1 * na;
        rwp[2] = e2 * na;
    }
    __syncthreads();                                     // S1

    s8v af[2][2][2];
    #pragma unroll
    for (int h = 0; h < 2; ++h)
        #pragma unroll
        for (int t = 0; t < 2; ++t) {
            int kl = h * 64 + t * 32 + quad * 8;
            af[h][t][0] = *reinterpret_cast<const s8v*>(&Wf[wv * 32 + l15][kl]);
            af[h][t][1] = *reinterpret_cast<const s8v*>(&Wf[wv * 32 + 16 + l15][kl]);
        }
    __syncthreads();                                     // S2

    // stage WsfB FULL -> Wf (cols 0..127 only; padding preserved) ; featWB h0 -> Wt
    #pragma unroll
    for (int rep = 0; rep < 8; ++rep) {
        int flat = rep * 256 + tid;
        int n = flat >> 4, c8 = flat & 15;
        *reinterpret_cast<uint4*>(&Wf[n][c8 * 8]) =
            *reinterpret_cast<const uint4*>(WsfB + (size_t)n * DD + c8 * 8);
    }
    #pragma unroll
    for (int rep = 0; rep < 4; ++rep) {
        int flat = rep * 256 + tid;
        int n = flat >> 3, c8 = flat & 7;
        *reinterpret_cast<uint4*>(&Wt[n][c8 * 8]) =
            *reinterpret_cast<const uint4*>(featWB + (size_t)n * DD + c8 * 8);
    }
    __syncthreads();                                     // S3

    f4v acc1[2][8], acc2[2][8];
    #pragma unroll
    for (int rt = 0; rt < 2; ++rt)
        #pragma unroll
        for (int c = 0; c < 8; ++c) {
            acc1[rt][c] = f4v{0.f, 0.f, 0.f, 0.f};
            acc2[rt][c] = f4v{0.f, 0.f, 0.f, 0.f};
        }

    mfmaWfFull(acc1, af, Wf, l15, quad);
    mfmaWt8(acc2, af, 0, Wt, l15, quad);
    __syncthreads();                                     // S4
    #pragma unroll
    for (int rep = 0; rep < 4; ++rep) {
        int flat = rep * 256 + tid;
        int n = flat >> 3, c8 = flat & 7;
        *reinterpret_cast<uint4*>(&Wt[n][c8 * 8]) =
            *reinterpret_cast<const uint4*>(featWB + (size_t)n * DD + 64 + c8 * 8);
    }
    __syncthreads();                                     // S5
    mfmaWt8(acc2, af, 1, Wt, l15, quad);

    // fused combine: Wf cols 0..127 = bf16( rw0*view0 + rw1*view1 + rw2*view2 )
    #pragma unroll
    for (int rep = 0; rep < 8; ++rep) {
        int flat = rep * 256 + tid;
        int n = flat >> 4, c8 = flat & 15;
        int gr = row0 + n; if (gr >= NN) gr = NN - 1;
        size_t off = (size_t)gr * DD + c8 * 8;
        uint4 q0 = *reinterpret_cast<const uint4*>(aggB + off);
        uint4 q1 = *reinterpret_cast<const uint4*>(aggB + (size_t)NN * DD + off);
        uint4 q2 = *reinterpret_cast<const uint4*>(aggB + 2 * (size_t)NN * DD + off);
        const float* rwp = reinterpret_cast<const float*>(&Wf[n][128]);
        float w0 = rwp[0], w1 = rwp[1], w2 = rwp[2];
        u32 o[4];
        const u32* a = &q0.x; const u32* b = &q1.x; const u32* c = &q2.x;
        #pragma unroll
        for (int j = 0; j < 4; ++j) {
            float lo = bf2f((u16)(a[j] & 0xffffu)) * w0 + bf2f((u16)(b[j] & 0xffffu)) * w1
                     + bf2f((u16)(c[j] & 0xffffu)) * w2;
            float hi = bf2f((u16)(a[j] >> 16)) * w0 + bf2f((u16)(b[j] >> 16)) * w1
                     + bf2f((u16)(c[j] >> 16)) * w2;
            o[j] = (u32)f2bf(lo) | ((u32)f2bf(hi) << 16);
        }
        uint4 r; r.x = o[0]; r.y = o[1]; r.z = o[2]; r.w = o[3];
        *reinterpret_cast<uint4*>(&Wf[n][c8 * 8]) = r;
    }
    __syncthreads();                                     // S6

    // fus GEMM half0
    #pragma unroll
    for (int rep = 0; rep < 4; ++rep) {
        int flat = rep * 256 + tid;
        int n = flat >> 3, c8 = flat & 7;
        *reinterpret_cast<uint4*>(&Wt[n][c8 * 8]) =
            *reinterpret_cast<const uint4*>(fusWbB + (size_t)n * DD + c8 * 8);
    }
    __syncthreads();                                     // S7
    #pragma unroll
    for (int t = 0; t < 2; ++t) {
        int kl = t * 32 + quad * 8;
        s8v a0 = *reinterpret_cast<const s8v*>(&Wf[wv * 32 + l15][kl]);
        s8v a1 = *reinterpret_cast<const s8v*>(&Wf[wv * 32 + 16 + l15][kl]);
        #pragma unroll
        for (int c = 0; c < 8; ++c) {
            s8v b = *reinterpret_cast<const s8v*>(&Wt[c * 16 + l15][kl]);
            acc1[0][c] = __builtin_amdgcn_mfma_f32_16x16x32_bf16(a0, b, acc1[0][c], 0, 0, 0);
            acc1[1][c] = __builtin_amdgcn_mfma_f32_16x16x32_bf16(a1, b, acc1[1][c], 0, 0, 0);
        }
    }
    __syncthreads();                                     // S8
    #pragma unroll
    for (int rep = 0; rep < 4; ++rep) {
        int flat = rep * 256 + tid;
        int n = flat >> 3, c8 = flat & 7;
        *reinterpret_cast<uint4*>(&Wt[n][c8 * 8]) =
            *reinterpret_cast<const uint4*>(fusWbB + (size_t)n * DD + 64 + c8 * 8);
    }
    __syncthreads();                                     // S9
    #pragma unroll
    for (int t = 0; t < 2; ++t) {
        int kl = t * 32 + quad * 8;
        s8v a0 = *reinterpret_cast<const s8v*>(&Wf[wv * 32 + l15][64 + kl]);
        s8v a1 = *reinterpret_cast<const s8v*>(&Wf[wv * 32 + 16 + l15][64 + kl]);
        #pragma unroll
        for (int c = 0; c < 8; ++c) {
            s8v b = *reinterpret_cast<const s8v*>(&Wt[c * 16 + l15][kl]);
            acc1[0][c] = __builtin_amdgcn_mfma_f32_16x16x32_bf16(a0, b, acc1[0][c], 0, 0, 0);
            acc1[1][c] = __builtin_amdgcn_mfma_f32_16x16x32_bf16(a1, b, acc1[1][c], 0, 0, 0);
        }
    }

    float c1j[8], fbj[8], gj[8], bj[8];
    #pragma unroll
    for (int c = 0; c < 8; ++c) {
        int col = c * 16 + l15;
        c1j[c] = c1[col];
        fbj[c] = featb[col];
        gj[c]  = ln_g[col];
        bj[c]  = ln_b[col];
    }
    #pragma unroll
    for (int rt = 0; rt < 2; ++rt)
        #pragma unroll
        for (int c = 0; c < 8; ++c)
            #pragma unroll
            for (int r = 0; r < 4; ++r) {
                float f = acc1[rt][c][r] + c1j[c];
                f = f > 0.f ? f : 0.f;
                acc1[rt][c][r] = f + acc2[rt][c][r] + fbj[c];
            }
    #pragma unroll
    for (int rt = 0; rt < 2; ++rt)
        #pragma unroll
        for (int r = 0; r < 4; ++r) {
            float s = 0.f, q = 0.f;
            #pragma unroll
            for (int c = 0; c < 8; ++c) {
                float x = acc1[rt][c][r];
                s += x; q += x * x;
            }
            #pragma unroll
            for (int m = 1; m < 16; m <<= 1) {
                s += __shfl_xor(s, m);
                q += __shfl_xor(q, m);
            }
            float mu = s * (1.f / 128.f);
            float var = q * (1.f / 128.f) - mu * mu;
            float rs = rsqrtf(var + 1e-5f);
            int gr = row0 + wv * 32 + rt * 16 + quad * 4 + r;
            if (gr < NN) {
                #pragma unroll
                for (int c = 0; c < 8; ++c)
                    outp[(size_t)gr * DD + c * 16 + l15] =
                        (acc1[rt][c][r] - mu) * rs * gj[c] + bj[c];
            }
        }
}

// ---------------- fallback VALU final ----------------
__global__ __launch_bounds__(256) void final_kernel(
        const float* __restrict__ feat, const u16* __restrict__ weightedB,
        const float* __restrict__ Wsf, const float* __restrict__ c1,
        const float* __restrict__ fusW, const float* __restrict__ featW,
        const float* __restrict__ featb, const float* __restrict__ ln_g,
        const float* __restrict__ ln_b, float* __restrict__ outp) {
    __shared__ float Xs[32][128];
    __shared__ float Ws[64][128];
    int tid = threadIdx.x;
    int row0 = blockIdx.x * 32;
    stage_x_f32<128, 256>(&Xs[0][0], feat + (size_t)row0 * DD, tid);
    int to = tid & 31, tn = tid >> 5;
    int o0 = to * 4, n0 = tn * 4;
    float acc1[4][4] = {}, acc2[4][4] = {};
    for (int half = 0; half < 2; ++half) {
        __syncthreads();
        stage_w_f32<128, 256>(&Ws[0][0], Wsf + half * 64 * 128, tid);
        __syncthreads();
        gemm16<128, 128>(acc1, &Xs[0][0], &Ws[0][0], n0, o0, half * 64);
    }
    for (int half = 0; half < 2; ++half) {
        __syncthreads();
        stage_w_f32<128, 256>(&Ws[0][0], featW + half * 64 * 128, tid);
        __syncthreads();
        gemm16<128, 128>(acc2, &Xs[0][0], &Ws[0][0], n0, o0, half * 64);
    }
    __syncthreads();
    stage_x_bf16<128, 256>(&Xs[0][0], weightedB + (size_t)row0 * DD, tid);
    for (int half = 0; half < 2; ++half) {
        __syncthreads();
        stage_w_f32<128, 256>(&Ws[0][0], fusW + (size_t)(128 + half * 64) * 128, tid);
        __syncthreads();
        gemm16<128, 128>(acc1, &Xs[0][0], &Ws[0][0], n0, o0, half * 64);
    }
    float c1j[4], fbj[4], gj[4], bj[4];
    #pragma unroll
    for (int j = 0; j < 4; ++j) {
        c1j[j] = c1[o0 + j];
        fbj[j] = featb[o0 + j];
        gj[j]  = ln_g[o0 + j];
        bj[j]  = ln_b[o0 + j];
    }
    float val[4][4];
    #pragma unroll
    for (int i = 0; i < 4; ++i)
        #pragma unroll
        for (int j = 0; j < 4; ++j) {
            float f = acc1[i][j] + c1j[j];
            f = f > 0.f ? f : 0.f;
            val[i][j] = f + acc2[i][j] + fbj[j];
        }
    __syncthreads();
    float* red_s = &Ws[0][0];
    float* red_q = red_s + 32 * 33;
    float* mus   = red_q + 32 * 33;
    float* rss   = mus + 32;
    #pragma unroll
    for (int i = 0; i < 4; ++i) {
        float s = 0.f, q = 0.f;
        #pragma unroll
        for (int j = 0; j < 4; ++j) { s += val[i][j]; q += val[i][j] * val[i][j]; }
        red_s[(n0 + i) * 33 + to] = s;
        red_q[(n0 + i) * 33 + to] = q;
    }
    __syncthreads();
    if (tid < 32) {
        float s = 0.f, q = 0.f;
        for (int u = 0; u < 32; ++u) { s += red_s[tid * 33 + u]; q += red_q[tid * 33 + u]; }
        float mu = s / 128.f;
        float var = q / 128.f - mu * mu;
        mus[tid] = mu;
        rss[tid] = rsqrtf(var + 1e-5f);
    }
    __syncthreads();
    #pragma unroll
    for (int i = 0; i < 4; ++i) {
        float mu = mus[n0 + i], rs = rss[n0 + i];
        float4 o;
        o.x = (val[i][0] - mu) * rs * gj[0] + bj[0];
        o.y = (val[i][1] - mu) * rs * gj[1] + bj[1];
        o.z = (val[i][2] - mu) * rs * gj[2] + bj[2];
        o.w = (val[i][3] - mu) * rs * gj[3] + bj[3];
        *reinterpret_cast<float4*>(outp + (size_t)(row0 + n0 + i) * DD + o0) = o;
    }
}

extern "C" void kernel_launch(void* const* d_in, const int* in_sizes, int n_in,
                              void* d_out, int out_size, void* d_ws, size_t ws_size,
                              hipStream_t stream) {
    (void)in_sizes; (void)n_in; (void)out_size;
    const float* feat      = (const float*)d_in[0];
    const int*   esrc      = (const int*)d_in[1];
    const int*   edst      = (const int*)d_in[2];
    const float* ew        = (const float*)d_in[3];
    const float* clsW      = (const float*)d_in[4];
    const float* clsb      = (const float*)d_in[5];
    const float* attW1     = (const float*)d_in[6];
    const float* attb1     = (const float*)d_in[7];
    const float* attW2     = (const float*)d_in[8];
    const float* attb2     = (const float*)d_in[9];
    const float* att_bias  = (const float*)d_in[10];
    const float* relW      = (const float*)d_in[11];
    const float* relb      = (const float*)d_in[12];
    const float* gateW     = (const float*)d_in[13];
    const float* gateb     = (const float*)d_in[14];
    const float* view_pref = (const float*)d_in[15];
    const float* vattW1    = (const float*)d_in[16];
    const float* vattb1    = (const float*)d_in[17];
    const float* vattW2    = (const float*)d_in[18];
    const float* vattb2    = (const float*)d_in[19];
    const float* selfW     = (const float*)d_in[20];
    const float* selfb     = (const float*)d_in[21];
    const float* featW     = (const float*)d_in[22];
    const float* featb     = (const float*)d_in[23];
    const float* fusW      = (const float*)d_in[24];
    const float* fusb      = (const float*)d_in[25];
    const float* ln_g      = (const float*)d_in[26];
    const float* ln_b      = (const float*)d_in[27];

    // workspace layout (~120 MiB):
    u16*   aggB = (u16*)d_ws;                                   // [3][N][128] bf16
    float* wsum = (float*)(aggB + (size_t)VV * NN * DD);        // [3][N]
    float* natt = wsum + (size_t)VV * NN;                       // [N]
    float* vsc  = natt + NN;                                    // [3][N]
    float* Wsf  = vsc + (size_t)VV * NN;                        // [128][128]
    float* c1   = Wsf + DD * DD;                                // [128]
    u16* relWb  = (u16*)(c1 + DD);                              // [3][128][128] bf16
    u16* gateWb = relWb + (size_t)VV * DD * DD;                 // [3][128][128] bf16
    u16* WsfB   = gateWb + (size_t)VV * DD * DD;                // [128][128] bf16
    u16* featWB = WsfB + DD * DD;                               // [128][128] bf16
    u16* fusWbB = featWB + DD * DD;                             // [128][128] bf16
    u16* attW1B = fusWbB + DD * DD;                             // [128][128] bf16
    u16* vattW1p = attW1B + DD * DD;                            // [3][64][128] bf16
    u16* W12b   = vattW1p + (size_t)VV * 64 * DD;               // [3][128][128] bf16
    float* rgb  = (float*)(W12b + (size_t)VV * DD * DD);        // [3][128]
    int*   C    = (int*)(rgb + VV * DD);                        // [3N]
    int*   bs   = C + (size_t)TOT;                              // [NB]
    int2*  bsw  = (int2*)(bs + NB + 1);                         // [3E] packed (src,w)
    u16* featB  = (u16*)(bsw + (size_t)VV * EE);                // [N][128] bf16
    size_t needed = (size_t)((char*)(featB + (size_t)NN * DD) - (char*)d_ws);

    float* outp  = (float*)d_out;
    float* probs = outp + (size_t)NN * DD;

    prep_kernel<<<129, 128, 0, stream>>>(selfW, selfb, fusW, fusb, Wsf, c1);
    if (ws_size >= needed) {
        featconv_kernel<<<12500, 256, 0, stream>>>(feat, featB);
        wprep_kernel<<<384, 128, 0, stream>>>(relW, gateW, relWb, gateWb);
        wprep2_kernel<<<128, 128, 0, stream>>>(Wsf, featW, fusW, WsfB, featWB, fusWbB);
        wprep3_kernel<<<128, 128, 0, stream>>>(attW1, attW1B);
        wprep4_kernel<<<192, 128, 0, stream>>>(vattW1, view_pref, vattW1p);
        wprep5_kernel<<<VV * 129, 128, 0, stream>>>(relW, gateW, relb, W12b, rgb);
        label_mfma_kernel<<<RGB, 256, 0, stream>>>(featB, attW1B, clsW, clsb, attb1,
                                                   attW2, attb2, att_bias, natt, probs);
        hipMemsetAsync(C, 0, (size_t)TOT * sizeof(int), stream);
        count_kernel<<<(VV * EE + 255) / 256, 256, 0, stream>>>(edst, C);
        scanA_kernel<<<NB, 256, 0, stream>>>(C, bs);
        scanB_kernel<<<1, 1024, 0, stream>>>(bs);
        scanC_kernel<<<NB, 256, 0, stream>>>(C, bs);
        fill_kernel<<<(VV * EE + 255) / 256, 256, 0, stream>>>(esrc, edst, ew, C, bsw);
        gather_kernel<<<(VV * NN) / 4, 256, 0, stream>>>(featB, C, bsw, aggB, wsum);
        relgate_mfma_kernel<<<RGB, 256, 0, stream>>>(relWb, relb, W12b, rgb, gateb,
                                                     vattW1p, vattb1, vattW2, vattb2,
                                                     aggB, wsum, vsc);
        final_mfma_kernel<<<RGB, 256, 0, stream>>>(featB, aggB, vsc, natt,
                                                   WsfB, featWB, fusWbB,
                                                   c1, featb, ln_g, ln_b, outp);
    } else {
        label_kernel<<<3125, 256, 0, stream>>>(feat, clsW, clsb, attW1, attb1, attW2, attb2,
                                               att_bias, natt, probs);
        hipMemsetAsync(d_ws, 0,
                       (size_t)VV * NN * DD * sizeof(u16) + (size_t)VV * NN * sizeof(float),
                       stream);
        scatter_kernel<<<187500, 256, 0, stream>>>(esrc, edst, ew, feat, aggB, wsum);
        relgate_kernel<<<dim3(3125, 3), 256, 0, stream>>>(relW, relb, gateW, gateb, aggB, wsum);
        vatt_kernel<<<dim3(3125, 3), 128, 0, stream>>>(aggB, view_pref, vattW1, vattb1,
                                                       vattW2, vattb2, vsc);
        combine_kernel<<<12500, 256, 0, stream>>>(aggB, vsc, natt);
        final_kernel<<<3125, 256, 0, stream>>>(feat, aggB, Wsf, c1, fusW, featW, featb,
                                               ln_g, ln_b, outp);
    }
}

// Round 7
// 661.521 us; speedup vs baseline: 1.4245x; 1.4245x over previous
//
#include <hip/hip_runtime.h>
#include <hip/hip_bf16.h>

#define NN 100000
#define DD 128
#define VV 3
#define EE 500000
#define TOT (VV * NN)                 // 300000 rows
#define NB ((TOT + 255) / 256)        // 1172 scan blocks
#define RGB ((NN + 127) / 128)        // 782 mfma blocks

typedef unsigned short u16;
typedef unsigned int u32;
typedef short s8v __attribute__((ext_vector_type(8)));   // 8 bf16 (4 VGPRs)
typedef float f4v __attribute__((ext_vector_type(4)));   // MFMA accumulator

__device__ __forceinline__ float bf2f(u16 u) {
    return __uint_as_float(((u32)u) << 16);
}
__device__ __forceinline__ u16 f2bf(float f) {
    u32 x = __float_as_uint(f);
    u32 r = (x + 0x7fffu + ((x >> 16) & 1u)) >> 16;
    return (u16)r;
}

__device__ __forceinline__ float fexp2(float x) {
#if __has_builtin(__builtin_amdgcn_exp2f)
    return __builtin_amdgcn_exp2f(x);
#else
    return exp2f(x);
#endif
}
__device__ __forceinline__ float frcp(float x) {
#if __has_builtin(__builtin_amdgcn_rcpf)
    return __builtin_amdgcn_rcpf(x);
#else
    return 1.f / x;
#endif
}
__device__ __forceinline__ float fsigmoid(float x) {
    return frcp(1.f + fexp2(-1.4426950408889634f * x));
}

// packed bf16 atomic add (fallback path only)
__device__ __forceinline__ void atomAddBf16x2(u16* addr, float f0, float f1) {
#if __has_builtin(__builtin_amdgcn_global_atomic_fadd_v2bf16)
    typedef short v2s __attribute__((ext_vector_type(2)));
    typedef v2s __attribute__((address_space(1)))* v2s_gp;
    v2s v;
    v.x = (short)f2bf(f0);
    v.y = (short)f2bf(f1);
    __builtin_amdgcn_global_atomic_fadd_v2bf16((v2s_gp)(void*)addr, v);
#else
    u32* p = (u32*)addr;
    u32 old = *(volatile u32*)p;
    while (true) {
        float lo = bf2f((u16)(old & 0xffffu)) + f0;
        float hi = bf2f((u16)(old >> 16)) + f1;
        u32 nv = (u32)f2bf(lo) | ((u32)f2bf(hi) << 16);
        u32 prev = atomicCAS(p, old, nv);
        if (prev == old) break;
        old = prev;
    }
#endif
}

// ---- generic VALU GEMM accumulate (fallback path) ----
template<int XSTR, int WSTR>
__device__ __forceinline__ void gemm16(float acc[4][4], const float* Xs,
                                       const float* Ws, int n0, int o0, int kbase) {
    #pragma unroll 4
    for (int kk = 0; kk < 64; kk += 4) {
        float4 w0 = *reinterpret_cast<const float4*>(Ws + (kk + 0) * WSTR + o0);
        float4 w1 = *reinterpret_cast<const float4*>(Ws + (kk + 1) * WSTR + o0);
        float4 w2 = *reinterpret_cast<const float4*>(Ws + (kk + 2) * WSTR + o0);
        float4 w3 = *reinterpret_cast<const float4*>(Ws + (kk + 3) * WSTR + o0);
        #pragma unroll
        for (int i = 0; i < 4; ++i) {
            float4 x = *reinterpret_cast<const float4*>(Xs + (n0 + i) * XSTR + kbase + kk);
            acc[i][0] = fmaf(x.x, w0.x, fmaf(x.y, w1.x, fmaf(x.z, w2.x, fmaf(x.w, w3.x, acc[i][0]))));
            acc[i][1] = fmaf(x.x, w0.y, fmaf(x.y, w1.y, fmaf(x.z, w2.y, fmaf(x.w, w3.y, acc[i][1]))));
            acc[i][2] = fmaf(x.x, w0.z, fmaf(x.y, w1.z, fmaf(x.z, w2.z, fmaf(x.w, w3.z, acc[i][2]))));
            acc[i][3] = fmaf(x.x, w0.w, fmaf(x.y, w1.w, fmaf(x.z, w2.w, fmaf(x.w, w3.w, acc[i][3]))));
        }
    }
}

template<int WSTR, int NT>
__device__ __forceinline__ void stage_w_f32(float* Ws, const float* __restrict__ src, int tid) {
    #pragma unroll
    for (int rep = 0; rep < 2048 / NT; ++rep) {
        int flat = rep * NT + tid;
        int kk = flat >> 5;
        int c4 = flat & 31;
        float4 q = *reinterpret_cast<const float4*>(src + kk * 128 + c4 * 4);
        *reinterpret_cast<float4*>(Ws + kk * WSTR + c4 * 4) = q;
    }
}

template<int XSTR, int NT>
__device__ __forceinline__ void stage_x_f32(float* Xs, const float* __restrict__ src, int tid) {
    #pragma unroll
    for (int rep = 0; rep < 1024 / NT; ++rep) {
        int flat = rep * NT + tid;
        int n = flat >> 5;
        int c4 = flat & 31;
        float4 q = *reinterpret_cast<const float4*>(src + (size_t)n * 128 + c4 * 4);
        *reinterpret_cast<float4*>(Xs + n * XSTR + c4 * 4) = q;
    }
}

template<int XSTR, int NT>
__device__ __forceinline__ void stage_x_bf16(float* Xs, const u16* __restrict__ src, int tid) {
    #pragma unroll
    for (int rep = 0; rep < 512 / NT; ++rep) {
        int flat = rep * NT + tid;
        int n = flat >> 4;
        int c8 = flat & 15;
        uint4 q = *reinterpret_cast<const uint4*>(src + (size_t)n * 128 + c8 * 8);
        float* d = Xs + n * XSTR + c8 * 8;
        d[0] = bf2f((u16)(q.x & 0xffffu)); d[1] = bf2f((u16)(q.x >> 16));
        d[2] = bf2f((u16)(q.y & 0xffffu)); d[3] = bf2f((u16)(q.y >> 16));
        d[4] = bf2f((u16)(q.z & 0xffffu)); d[5] = bf2f((u16)(q.z >> 16));
        d[6] = bf2f((u16)(q.w & 0xffffu)); d[7] = bf2f((u16)(q.w >> 16));
    }
}

// ======== MFMA staging / fragment helpers (256 threads) ========

// full 128x128 bf16 weight tile -> Wf (cols 0..127; row padding untouched)
__device__ __forceinline__ void stageWf(u16 (*Wf)[136], const u16* __restrict__ src, int tid) {
    #pragma unroll
    for (int rep = 0; rep < 8; ++rep) {
        int flat = rep * 256 + tid;
        int n = flat >> 4, c8 = flat & 15;
        *reinterpret_cast<uint4*>(&Wf[n][c8 * 8]) =
            *reinterpret_cast<const uint4*>(src + (size_t)n * DD + c8 * 8);
    }
}

// 128x64 half-k weight tile -> Wt (src already offset by h*64)
__device__ __forceinline__ void stageWtHalf(u16 (*Wt)[72], const u16* __restrict__ src, int tid) {
    #pragma unroll
    for (int rep = 0; rep < 4; ++rep) {
        int flat = rep * 256 + tid;
        int n = flat >> 3, c8 = flat & 7;
        *reinterpret_cast<uint4*>(&Wt[n][c8 * 8]) =
            *reinterpret_cast<const uint4*>(src + (size_t)n * DD + c8 * 8);
    }
}

// 128-row X tile (row-clamped) -> Wf
__device__ __forceinline__ void stageX(u16 (*Wf)[136], const u16* __restrict__ src,
                                       int row0, int tid) {
    #pragma unroll
    for (int rep = 0; rep < 8; ++rep) {
        int flat = rep * 256 + tid;
        int n = flat >> 4, c8 = flat & 15;
        int gr = row0 + n; if (gr >= NN) gr = NN - 1;
        *reinterpret_cast<uint4*>(&Wf[n][c8 * 8]) =
            *reinterpret_cast<const uint4*>(src + (size_t)gr * DD + c8 * 8);
    }
}

// A-fragments (whole K=128) for this wave's 32 rows
__device__ __forceinline__ void loadFrags(s8v af[2][2][2], u16 (*Wf)[136],
                                          int wv, int l15, int quad) {
    #pragma unroll
    for (int h = 0; h < 2; ++h)
        #pragma unroll
        for (int t = 0; t < 2; ++t) {
            int kl = h * 64 + t * 32 + quad * 8;
            af[h][t][0] = *reinterpret_cast<const s8v*>(&Wf[wv * 32 + l15][kl]);
            af[h][t][1] = *reinterpret_cast<const s8v*>(&Wf[wv * 32 + 16 + l15][kl]);
        }
}

// acc += af[h] (x) Wt  (half-k, 8 col-tiles, 32 MFMA)
__device__ __forceinline__ void mfmaWt8(f4v acc[2][8], const s8v af[2][2][2], int h,
                                        u16 (*Wt)[72], int l15, int quad) {
    #pragma unroll
    for (int t = 0; t < 2; ++t) {
        int kl = t * 32 + quad * 8;
        #pragma unroll
        for (int c = 0; c < 8; ++c) {
            s8v b = *reinterpret_cast<const s8v*>(&Wt[c * 16 + l15][kl]);
            acc[0][c] = __builtin_amdgcn_mfma_f32_16x16x32_bf16(af[h][t][0], b, acc[0][c], 0, 0, 0);
            acc[1][c] = __builtin_amdgcn_mfma_f32_16x16x32_bf16(af[h][t][1], b, acc[1][c], 0, 0, 0);
        }
    }
}

// acc += af (x) Wf  (full-k, 8 col-tiles, 64 MFMA)
__device__ __forceinline__ void mfmaWfFull(f4v acc[2][8], const s8v af[2][2][2],
                                           u16 (*Wf)[136], int l15, int quad) {
    #pragma unroll
    for (int h = 0; h < 2; ++h)
        #pragma unroll
        for (int t = 0; t < 2; ++t) {
            int kl = h * 64 + t * 32 + quad * 8;
            #pragma unroll
            for (int c = 0; c < 8; ++c) {
                s8v b = *reinterpret_cast<const s8v*>(&Wf[c * 16 + l15][kl]);
                acc[0][c] = __builtin_amdgcn_mfma_f32_16x16x32_bf16(af[h][t][0], b, acc[0][c], 0, 0, 0);
                acc[1][c] = __builtin_amdgcn_mfma_f32_16x16x32_bf16(af[h][t][1], b, acc[1][c], 0, 0, 0);
            }
        }
}

// ---------------- prep: Wsf = selfW @ fusW_top ; c1 = selfb @ fusW_top + fusb ----
__global__ void prep_kernel(const float* __restrict__ selfW, const float* __restrict__ selfb,
                            const float* __restrict__ fusW, const float* __restrict__ fusb,
                            float* __restrict__ Wsf, float* __restrict__ c1) {
    int o = threadIdx.x;
    int k = blockIdx.x;
    if (k < 128) {
        float acc = 0.f;
        for (int m = 0; m < 128; ++m)
            acc += selfW[k * 128 + m] * fusW[m * 128 + o];
        Wsf[k * 128 + o] = acc;
    } else {
        float acc = 0.f;
        for (int m = 0; m < 128; ++m)
            acc += selfb[m] * fusW[m * 128 + o];
        c1[o] = acc + fusb[o];
    }
}

// ---------------- wprep: transpose+convert relW/gateW -> bf16 [v][n][k] ----
__global__ __launch_bounds__(128) void wprep_kernel(
        const float* __restrict__ relW, const float* __restrict__ gateW,
        u16* __restrict__ relWb, u16* __restrict__ gateWb) {
    int k = threadIdx.x;
    int n = blockIdx.x & 127;
    int v = blockIdx.x >> 7;
    size_t o = ((size_t)v * 128 + n) * 128 + k;
    size_t i = ((size_t)v * 128 + k) * 128 + n;
    relWb[o]  = f2bf(relW[i]);
    gateWb[o] = f2bf(gateW[i]);
}

// ---------------- wprep2: bf16 n-major Wsf / featW / fusW_bot ----
__global__ __launch_bounds__(128) void wprep2_kernel(
        const float* __restrict__ Wsf, const float* __restrict__ featW,
        const float* __restrict__ fusW,
        u16* __restrict__ WsfB, u16* __restrict__ featWB, u16* __restrict__ fusWbB) {
    int k = threadIdx.x;
    int n = blockIdx.x;
    WsfB[n * 128 + k]   = f2bf(Wsf[k * 128 + n]);
    featWB[n * 128 + k] = f2bf(featW[k * 128 + n]);
    fusWbB[n * 128 + k] = f2bf(fusW[(size_t)(128 + k) * 128 + n]);
}

// ---------------- wprep3: attW1 [c][k][h] -> bf16 n-major [o=c*64+h][k] ----
__global__ __launch_bounds__(128) void wprep3_kernel(
        const float* __restrict__ attW1, u16* __restrict__ attW1B) {
    int k = threadIdx.x;
    int o = blockIdx.x;                 // 0..127
    int c = o >> 6, h = o & 63;
    attW1B[o * 128 + k] = f2bf(attW1[((size_t)c * 128 + k) * 64 + h]);
}

// ---------------- wprep4: vattW1p[v][h][k] = bf16(view_pref[v][k] * vattW1[k][h]) ----
__global__ __launch_bounds__(128) void wprep4_kernel(
        const float* __restrict__ vattW1, const float* __restrict__ view_pref,
        u16* __restrict__ vattW1p) {
    int k = threadIdx.x;
    int h = blockIdx.x & 63;
    int v = blockIdx.x >> 6;            // 0..2
    vattW1p[((size_t)v * 64 + h) * 128 + k] =
        f2bf(view_pref[v * 128 + k] * vattW1[k * 64 + h]);
}

// ---------------- wprep5: W12b[v][p][d] = bf16(relW[v]@gateW[v]) n-major;
//                  rgb[v][p] = relb[v]@gateW[v] ----
__global__ __launch_bounds__(128) void wprep5_kernel(
        const float* __restrict__ relW, const float* __restrict__ gateW,
        const float* __restrict__ relb,
        u16* __restrict__ W12b, float* __restrict__ rgb) {
    int p = threadIdx.x;
    int b = blockIdx.x;                 // v*129 + d  (d==128 -> rgb row)
    int v = b / 129;
    int d = b - v * 129;
    const float* gW = gateW + (size_t)v * 128 * 128;
    if (d < 128) {
        const float* rW = relW + ((size_t)v * 128 + d) * 128;
        float acc = 0.f;
        for (int o = 0; o < 128; ++o) acc += rW[o] * gW[o * 128 + p];
        W12b[((size_t)v * 128 + p) * 128 + d] = f2bf(acc);
    } else {
        const float* rb = relb + (size_t)v * 128;
        float acc = 0.f;
        for (int o = 0; o < 128; ++o) acc += rb[o] * gW[o * 128 + p];
        rgb[v * 128 + p] = acc;
    }
}

// ---------------- featconv: feat fp32 -> bf16 ----
__global__ __launch_bounds__(256) void featconv_kernel(
        const float* __restrict__ feat, u16* __restrict__ featB) {
    int t = blockIdx.x * 256 + threadIdx.x;   // 3.2M float4 chunks
    float4 q = *reinterpret_cast<const float4*>(feat + (size_t)t * 4);
    ushort4 r;
    r.x = f2bf(q.x); r.y = f2bf(q.y); r.z = f2bf(q.z); r.w = f2bf(q.w);
    *reinterpret_cast<ushort4*>(featB + (size_t)t * 4) = r;
}

// ================= CSR build (hierarchical scan) + gather =================

__global__ __launch_bounds__(256) void count_kernel(
        const int* __restrict__ edst, int* __restrict__ C) {
    int t = blockIdx.x * 256 + threadIdx.x;
    if (t >= VV * EE) return;
    int v = t / EE;
    atomicAdd(&C[v * NN + edst[t]], 1);
}

__global__ __launch_bounds__(256) void scanA_kernel(
        const int* __restrict__ C, int* __restrict__ bs) {
    int b = blockIdx.x, t = threadIdx.x;
    int i = b * 256 + t;
    int v = (i < TOT) ? C[i] : 0;
    __shared__ int s[256];
    s[t] = v;
    __syncthreads();
    #pragma unroll
    for (int off = 128; off > 0; off >>= 1) {
        if (t < off) s[t] += s[t + off];
        __syncthreads();
    }
    if (t == 0) bs[b] = s[0];
}

__global__ __launch_bounds__(1024) void scanB_kernel(int* __restrict__ bs) {
    __shared__ int s[2048];
    int t = threadIdx.x;
    int v0 = (t < NB) ? bs[t] : 0;
    int v1 = (t + 1024 < NB) ? bs[t + 1024] : 0;
    s[t] = v0; s[t + 1024] = v1;
    __syncthreads();
    #pragma unroll
    for (int off = 1; off < 2048; off <<= 1) {
        int x0 = (t >= off) ? s[t - off] : 0;
        int x1 = (t + 1024 >= off) ? s[t + 1024 - off] : 0;
        __syncthreads();
        s[t] += x0; s[t + 1024] += x1;
        __syncthreads();
    }
    if (t < NB) bs[t] = s[t] - v0;
    if (t + 1024 < NB) bs[t + 1024] = s[t + 1024] - v1;
}

__global__ __launch_bounds__(256) void scanC_kernel(
        int* __restrict__ C, const int* __restrict__ bs) {
    int b = blockIdx.x, t = threadIdx.x;
    int i = b * 256 + t;
    int v = (i < TOT) ? C[i] : 0;
    __shared__ int s[256];
    s[t] = v;
    __syncthreads();
    #pragma unroll
    for (int off = 1; off < 256; off <<= 1) {
        int x = (t >= off) ? s[t - off] : 0;
        __syncthreads();
        s[t] += x;
        __syncthreads();
    }
    if (i < TOT) C[i] = s[t] - v + bs[b];
}

// fill: packed (src, w) per bucket slot; C becomes inclusive row ends
__global__ __launch_bounds__(256) void fill_kernel(
        const int* __restrict__ esrc, const int* __restrict__ edst,
        const float* __restrict__ ew, int* __restrict__ C,
        int2* __restrict__ bsw) {
    int t = blockIdx.x * 256 + threadIdx.x;
    if (t >= VV * EE) return;
    int v = t / EE;
    int pos = atomicAdd(&C[v * NN + edst[t]], 1);
    int2 p;
    p.x = esrc[t];
    p.y = __float_as_int(ew[t]);
    bsw[pos] = p;
}

// one wave per (v,dst) row, unroll-4 to overlap the load chains
__global__ __launch_bounds__(256) void gather_kernel(
        const u16* __restrict__ featB, const int* __restrict__ C,
        const int2* __restrict__ bsw,
        u16* __restrict__ aggB, float* __restrict__ wsum) {
    int wid = (blockIdx.x * 256 + threadIdx.x) >> 6;
    int lane = threadIdx.x & 63;
    int end = C[wid];
    int start = (wid == 0) ? 0 : C[wid - 1];
    float a0 = 0.f, a1 = 0.f, wacc = 0.f;
    int e = start;
    for (; e + 4 <= end; e += 4) {
        int2 p0 = bsw[e], p1 = bsw[e + 1], p2 = bsw[e + 2], p3 = bsw[e + 3];
        u32 f0 = *reinterpret_cast<const u32*>(featB + (size_t)p0.x * DD + lane * 2);
        u32 f1 = *reinterpret_cast<const u32*>(featB + (size_t)p1.x * DD + lane * 2);
        u32 f2 = *reinterpret_cast<const u32*>(featB + (size_t)p2.x * DD + lane * 2);
        u32 f3 = *reinterpret_cast<const u32*>(featB + (size_t)p3.x * DD + lane * 2);
        float w0 = __int_as_float(p0.y), w1 = __int_as_float(p1.y);
        float w2 = __int_as_float(p2.y), w3 = __int_as_float(p3.y);
        a0 = fmaf(w0, bf2f((u16)(f0 & 0xffffu)), a0);
        a1 = fmaf(w0, bf2f((u16)(f0 >> 16)), a1);
        a0 = fmaf(w1, bf2f((u16)(f1 & 0xffffu)), a0);
        a1 = fmaf(w1, bf2f((u16)(f1 >> 16)), a1);
        a0 = fmaf(w2, bf2f((u16)(f2 & 0xffffu)), a0);
        a1 = fmaf(w2, bf2f((u16)(f2 >> 16)), a1);
        a0 = fmaf(w3, bf2f((u16)(f3 & 0xffffu)), a0);
        a1 = fmaf(w3, bf2f((u16)(f3 >> 16)), a1);
        wacc += (w0 + w1) + (w2 + w3);
    }
    for (; e < end; ++e) {
        int2 p = bsw[e];
        float w = __int_as_float(p.y);
        u32 f = *reinterpret_cast<const u32*>(featB + (size_t)p.x * DD + lane * 2);
        a0 = fmaf(w, bf2f((u16)(f & 0xffffu)), a0);
        a1 = fmaf(w, bf2f((u16)(f >> 16)), a1);
        wacc += w;
    }
    u32 packed = (u32)f2bf(a0) | ((u32)f2bf(a1) << 16);
    *reinterpret_cast<u32*>(aggB + (size_t)wid * DD + lane * 2) = packed;
    if (lane == 0) wsum[wid] = wacc;
}

// ================= fallback: atomic scatter =================
__global__ __launch_bounds__(256) void scatter_kernel(
        const int* __restrict__ esrc, const int* __restrict__ edst,
        const float* __restrict__ ew, const float* __restrict__ feat,
        u16* __restrict__ aggB, float* __restrict__ wsum) {
    long long t = (long long)blockIdx.x * 256 + threadIdx.x;
    int lane = (int)(t & 31);
    int eg = (int)(t >> 5);
    int v = eg / EE;
    int src = 0, dst = 0; float w = 0.f;
    if (lane == 0) {
        src = esrc[eg]; dst = edst[eg]; w = ew[eg];
    }
    src = __shfl(src, 0, 32);
    dst = __shfl(dst, 0, 32);
    w   = __shfl(w, 0, 32);
    const float* fr = feat + (size_t)src * DD + lane * 4;
    float4 q = *reinterpret_cast<const float4*>(fr);
    u16* outp = aggB + ((size_t)v * NN + dst) * DD + lane * 4;
    atomAddBf16x2(outp,     w * q.x, w * q.y);
    atomAddBf16x2(outp + 2, w * q.z, w * q.w);
    if (lane == 0) atomicAdd(wsum + v * NN + dst, w);
}

// ---------------- fallback VALU label ----------------
__global__ __launch_bounds__(256) void label_kernel(
        const float* __restrict__ feat, const float* __restrict__ clsW, const float* __restrict__ clsb,
        const float* __restrict__ attW1, const float* __restrict__ attb1,
        const float* __restrict__ attW2, const float* __restrict__ attb2,
        const float* __restrict__ att_bias,
        float* __restrict__ node_att, float* __restrict__ probs_out) {
    __shared__ float Xs[32][132];
    __shared__ float Ws[64][132];
    int tid = threadIdx.x;
    int row0 = blockIdx.x * 32;
    stage_x_f32<132, 256>(&Xs[0][0], feat + (size_t)row0 * DD, tid);
    int to = tid & 31, tn = tid >> 5;
    int o0 = to * 4, n0 = tn * 4;
    float acc[4][4] = {};
    for (int half = 0; half < 2; ++half) {
        __syncthreads();
        #pragma unroll
        for (int rep = 0; rep < 8; ++rep) {
            int flat = rep * 256 + tid;
            int kk = flat >> 5, o4 = flat & 31;
            int o = o4 * 4;
            int c = o >> 6, h = o & 63;
            int k = half * 64 + kk;
            float4 q = *reinterpret_cast<const float4*>(attW1 + (size_t)(c * 128 + k) * 64 + h);
            *reinterpret_cast<float4*>(&Ws[kk][o]) = q;
        }
        __syncthreads();
        gemm16<132, 132>(acc, &Xs[0][0], &Ws[0][0], n0, o0, half * 64);
    }
    int c = o0 >> 6, h0 = o0 & 63;
    float b1j[4], w2j[4];
    #pragma unroll
    for (int j = 0; j < 4; ++j) {
        b1j[j] = attb1[c * 64 + h0 + j];
        w2j[j] = attW2[c * 64 + h0 + j];
    }
    float part[4];
    #pragma unroll
    for (int i = 0; i < 4; ++i) {
        float s = 0.f;
        #pragma unroll
        for (int j = 0; j < 4; ++j) {
            float hv = acc[i][j] + b1j[j];
            hv = hv > 0.f ? hv : 0.f;
            s += hv * w2j[j];
        }
        part[i] = s;
    }
    __syncthreads();
    float* red = &Ws[0][0];          // [32][33]
    float* Ssc = red + 32 * 33;      // [32][2]
    float* Lsc = Ssc + 64;           // [32][2]
    #pragma unroll
    for (int i = 0; i < 4; ++i) red[(n0 + i) * 33 + to] = part[i];
    __syncthreads();
    if (tid < 64) {
        int n = tid >> 1, cc = tid & 1;
        float l = 0.f;
        for (int k = 0; k < 128; k += 4) {
            float4 x = *reinterpret_cast<const float4*>(&Xs[n][k]);
            l += x.x * clsW[(k + 0) * 2 + cc];
            l += x.y * clsW[(k + 1) * 2 + cc];
            l += x.z * clsW[(k + 2) * 2 + cc];
            l += x.w * clsW[(k + 3) * 2 + cc];
        }
        Lsc[n * 2 + cc] = l + clsb[cc];
        float s = 0.f;
        for (int u = 0; u < 16; ++u) s += red[n * 33 + cc * 16 + u];
        s += attb2[cc];
        Ssc[n * 2 + cc] = 1.f / (1.f + expf(-s));
    }
    __syncthreads();
    if (tid < 32) {
        int n = tid;
        float l0 = Lsc[n * 2], l1 = Lsc[n * 2 + 1];
        float m = fmaxf(l0, l1);
        float e0 = expf(l0 - m), e1 = expf(l1 - m);
        float inv = 1.f / (e0 + e1);
        float p0 = e0 * inv, p1 = e1 * inv;
        float na = p0 * Ssc[n * 2] + p1 * Ssc[n * 2 + 1] + att_bias[0];
        int row = row0 + n;
        node_att[row] = na;
        probs_out[row * 2]     = p0;
        probs_out[row * 2 + 1] = p1;
    }
}

// ---------------- MFMA relgate (unchained via W12) + fused view-score ----
// EXACT R1 version (best measured: 118 us warm).
__global__ __launch_bounds__(256, 3) void relgate_mfma_kernel(
        const u16* __restrict__ relWb, const float* __restrict__ relb,
        const u16* __restrict__ W12b, const float* __restrict__ rgbv,
        const float* __restrict__ gateb,
        const u16* __restrict__ vattW1p, const float* __restrict__ vattb1,
        const float* __restrict__ vattW2, const float* __restrict__ vattb2,
        u16* __restrict__ aggB, const float* __restrict__ wsum,
        float* __restrict__ vscores) {
    __shared__ u16 Wf[128][136];   // X, then relW full, then view_out
    __shared__ u16 Wt[128][72];    // W12 halves, then vatt weights
    int tid = threadIdx.x;
    int wv = tid >> 6, lane = tid & 63;
    int quad = lane >> 4, l15 = lane & 15;
    int v = blockIdx.y;
    int row0 = blockIdx.x * 128;
    const size_t vbase = (size_t)v * NN;

    // ---- stage X ----
    #pragma unroll
    for (int rep = 0; rep < 8; ++rep) {
        int flat = rep * 256 + tid;
        int n = flat >> 4, c8 = flat & 15;
        int gr = row0 + n; if (gr >= NN) gr = NN - 1;
        uint4 q = *reinterpret_cast<const uint4*>(aggB + (vbase + gr) * DD + c8 * 8);
        *reinterpret_cast<uint4*>(&Wf[n][c8 * 8]) = q;
    }
    __syncthreads();                                     // S1

    // ---- A fragments (whole K) into registers, shared by both GEMMs ----
    s8v af[2][2][2];
    loadFrags(af, Wf, wv, l15, quad);
    __syncthreads();                                     // S2

    // ---- stage relW FULL -> Wf ; W12 half0 -> Wt ----
    const u16* W1 = relWb + (size_t)v * DD * DD;
    const u16* W2 = W12b + (size_t)v * DD * DD;
    stageWf(Wf, W1, tid);
    stageWtHalf(Wt, W2, tid);
    __syncthreads();                                     // S3

    f4v acc1[2][8], acc2[2][8];
    #pragma unroll
    for (int rt = 0; rt < 2; ++rt)
        #pragma unroll
        for (int c = 0; c < 8; ++c) {
            acc1[rt][c] = f4v{0.f, 0.f, 0.f, 0.f};
            acc2[rt][c] = f4v{0.f, 0.f, 0.f, 0.f};
        }

    // acc1: full rel GEMM (64 MFMA/wave) + acc2 half0 (32 MFMA/wave)
    mfmaWfFull(acc1, af, Wf, l15, quad);
    mfmaWt8(acc2, af, 0, Wt, l15, quad);
    __syncthreads();                                     // S4

    // ---- stage W12 half1 -> Wt ----
    stageWtHalf(Wt, W2 + 64, tid);
    __syncthreads();                                     // S5
    mfmaWt8(acc2, af, 1, Wt, l15, quad);

    // ---- epilogue: agg, gate, view_out -> Wf (bf16) ----
    float wsn[2][4];
    #pragma unroll
    for (int rt = 0; rt < 2; ++rt)
        #pragma unroll
        for (int r = 0; r < 4; ++r) {
            int gr = row0 + wv * 32 + rt * 16 + quad * 4 + r;
            wsn[rt][r] = wsum[vbase + (gr < NN ? gr : NN - 1)];
        }
    float rb[8], rg2[8], gb[8];
    #pragma unroll
    for (int c = 0; c < 8; ++c) {
        int col = c * 16 + l15;
        rb[c]  = relb[v * DD + col];
        rg2[c] = rgbv[v * DD + col];
        gb[c]  = gateb[v * DD + col];
    }
    #pragma unroll
    for (int rt = 0; rt < 2; ++rt)
        #pragma unroll
        for (int c = 0; c < 8; ++c)
            #pragma unroll
            for (int r = 0; r < 4; ++r) {
                float a = acc1[rt][c][r] + wsn[rt][r] * rb[c];
                float g = fsigmoid(acc2[rt][c][r] + wsn[rt][r] * rg2[c] + gb[c]);
                Wf[wv * 32 + rt * 16 + quad * 4 + r][c * 16 + l15] = f2bf(g * a);
            }
    __syncthreads();                                     // S6

    // ---- stage vatt -> Wt, dump view_out -> aggB, a2 frags ----
    {
        const u16* Wv = vattW1p + (size_t)v * 64 * DD;
        #pragma unroll
        for (int rep = 0; rep < 4; ++rep) {
            int flat = rep * 256 + tid;
            int n = flat >> 4, c8 = flat & 15;
            uint4 q = *reinterpret_cast<const uint4*>(Wv + (size_t)n * DD + c8 * 8);
            int half = c8 >> 3;
            *reinterpret_cast<uint4*>(&Wt[half * 64 + n][(c8 & 7) * 8]) = q;
        }
    }
    s8v a2[2][2][2];
    loadFrags(a2, Wf, wv, l15, quad);
    #pragma unroll
    for (int rep = 0; rep < 8; ++rep) {
        int flat = rep * 256 + tid;
        int n = flat >> 4, c8 = flat & 15;
        int gr = row0 + n;
        if (gr < NN)
            *reinterpret_cast<uint4*>(aggB + (vbase + gr) * DD + c8 * 8) =
                *reinterpret_cast<const uint4*>(&Wf[n][c8 * 8]);
    }
    __syncthreads();                                     // S7

    // ---- fused view-score GEMM ----
    f4v acc3[2][4];
    #pragma unroll
    for (int rt = 0; rt < 2; ++rt)
        #pragma unroll
        for (int c = 0; c < 4; ++c)
            acc3[rt][c] = f4v{0.f, 0.f, 0.f, 0.f};
    #pragma unroll
    for (int h = 0; h < 2; ++h)
        #pragma unroll
        for (int t = 0; t < 2; ++t) {
            int kl = t * 32 + quad * 8;
            #pragma unroll
            for (int c = 0; c < 4; ++c) {
                s8v b = *reinterpret_cast<const s8v*>(&Wt[h * 64 + c * 16 + l15][kl]);
                acc3[0][c] = __builtin_amdgcn_mfma_f32_16x16x32_bf16(a2[h][t][0], b, acc3[0][c], 0, 0, 0);
                acc3[1][c] = __builtin_amdgcn_mfma_f32_16x16x32_bf16(a2[h][t][1], b, acc3[1][c], 0, 0, 0);
            }
        }
    float vb1[4], vw2[4];
    #pragma unroll
    for (int c = 0; c < 4; ++c) {
        int col = c * 16 + l15;
        vb1[c] = vattb1[col];
        vw2[c] = vattW2[col];
    }
    float vb2 = vattb2[0];
    #pragma unroll
    for (int rt = 0; rt < 2; ++rt)
        #pragma unroll
        for (int r = 0; r < 4; ++r) {
            float p = 0.f;
            #pragma unroll
            for (int c = 0; c < 4; ++c) {
                float hv = acc3[rt][c][r] + vb1[c];
                hv = hv > 0.f ? hv : 0.f;
                p += hv * vw2[c];
            }
            #pragma unroll
            for (int m = 1; m < 16; m <<= 1)
                p += __shfl_xor(p, m);
            int gr = row0 + wv * 32 + rt * 16 + quad * 4 + r;
            if (l15 == 0 && gr < NN)
                vscores[vbase + gr] = p + vb2;
        }
}

// ---------------- fallback VALU relgate ----------------
__global__ __launch_bounds__(256) void relgate_kernel(
        const float* __restrict__ relW, const float* __restrict__ relb,
        const float* __restrict__ gateW, const float* __restrict__ gateb,
        u16* __restrict__ aggB, const float* __restrict__ wsum) {
    __shared__ float Xs[32][128];
    __shared__ float Ws[64][132];
    int tid = threadIdx.x;
    int v = blockIdx.y;
    int row0 = blockIdx.x * 32;
    u16* base = aggB + ((size_t)v * NN + row0) * DD;
    stage_x_bf16<128, 256>(&Xs[0][0], base, tid);
    int to = tid & 31, tn = tid >> 5;
    int o0 = to * 4, n0 = tn * 4;
    float acc[4][4] = {};
    const float* W1 = relW + (size_t)v * DD * DD;
    for (int half = 0; half < 2; ++half) {
        __syncthreads();
        stage_w_f32<132, 256>(&Ws[0][0], W1 + half * 64 * DD, tid);
        __syncthreads();
        gemm16<128, 132>(acc, &Xs[0][0], &Ws[0][0], n0, o0, half * 64);
    }
    float wsn[4], rb[4];
    #pragma unroll
    for (int i = 0; i < 4; ++i) wsn[i] = wsum[v * NN + row0 + n0 + i];
    #pragma unroll
    for (int j = 0; j < 4; ++j) rb[j] = relb[v * DD + o0 + j];
    #pragma unroll
    for (int i = 0; i < 4; ++i)
        #pragma unroll
        for (int j = 0; j < 4; ++j) acc[i][j] += wsn[i] * rb[j];
    __syncthreads();
    #pragma unroll
    for (int i = 0; i < 4; ++i)
        *reinterpret_cast<float4*>(&Xs[n0 + i][o0]) = make_float4(acc[i][0], acc[i][1], acc[i][2], acc[i][3]);
    float acc2[4][4] = {};
    const float* W2 = gateW + (size_t)v * DD * DD;
    for (int half = 0; half < 2; ++half) {
        __syncthreads();
        stage_w_f32<132, 256>(&Ws[0][0], W2 + half * 64 * DD, tid);
        __syncthreads();
        gemm16<128, 132>(acc2, &Xs[0][0], &Ws[0][0], n0, o0, half * 64);
    }
    float gb[4];
    #pragma unroll
    for (int j = 0; j < 4; ++j) gb[j] = gateb[v * DD + o0 + j];
    #pragma unroll
    for (int i = 0; i < 4; ++i) {
        float g0 = 1.f / (1.f + expf(-(acc2[i][0] + gb[0])));
        float g1 = 1.f / (1.f + expf(-(acc2[i][1] + gb[1])));
        float g2 = 1.f / (1.f + expf(-(acc2[i][2] + gb[2])));
        float g3 = 1.f / (1.f + expf(-(acc2[i][3] + gb[3])));
        ushort4 r;
        r.x = f2bf(g0 * acc[i][0]); r.y = f2bf(g1 * acc[i][1]);
        r.z = f2bf(g2 * acc[i][2]); r.w = f2bf(g3 * acc[i][3]);
        *reinterpret_cast<ushort4*>(base + (size_t)(n0 + i) * DD + o0) = r;
    }
}

// ---------------- fallback view attention scores ----------------
__global__ __launch_bounds__(128) void vatt_kernel(
        const u16* __restrict__ aggB, const float* __restrict__ view_pref,
        const float* __restrict__ vattW1, const float* __restrict__ vattb1,
        const float* __restrict__ vattW2, const float* __restrict__ vattb2,
        float* __restrict__ vscores) {
    __shared__ float Xs[32][132];
    __shared__ float Ws[128][68];
    int tid = threadIdx.x;
    int v = blockIdx.y;
    int row0 = blockIdx.x * 32;
    const u16* base = aggB + ((size_t)v * NN + row0) * DD;
    #pragma unroll
    for (int rep = 0; rep < 4; ++rep) {
        int flat = rep * 128 + tid;
        int n = flat >> 4, c8 = flat & 15;
        uint4 q = *reinterpret_cast<const uint4*>(base + (size_t)n * DD + c8 * 8);
        float4 pa = *reinterpret_cast<const float4*>(view_pref + v * DD + c8 * 8);
        float4 pb = *reinterpret_cast<const float4*>(view_pref + v * DD + c8 * 8 + 4);
        float* d = &Xs[n][c8 * 8];
        d[0] = bf2f((u16)(q.x & 0xffffu)) * pa.x; d[1] = bf2f((u16)(q.x >> 16)) * pa.y;
        d[2] = bf2f((u16)(q.y & 0xffffu)) * pa.z; d[3] = bf2f((u16)(q.y >> 16)) * pa.w;
        d[4] = bf2f((u16)(q.z & 0xffffu)) * pb.x; d[5] = bf2f((u16)(q.z >> 16)) * pb.y;
        d[6] = bf2f((u16)(q.w & 0xffffu)) * pb.z; d[7] = bf2f((u16)(q.w >> 16)) * pb.w;
    }
    #pragma unroll
    for (int rep = 0; rep < 16; ++rep) {
        int flat = rep * 128 + tid;
        int k = flat >> 4, c4 = flat & 15;
        float4 q = *reinterpret_cast<const float4*>(vattW1 + k * 64 + c4 * 4);
        *reinterpret_cast<float4*>(&Ws[k][c4 * 4]) = q;
    }
    __syncthreads();
    int to = tid & 15, tn = tid >> 4;
    int o0 = to * 4, n0 = tn * 4;
    float acc[4][4] = {};
    gemm16<132, 68>(acc, &Xs[0][0], &Ws[0][0], n0, o0, 0);
    gemm16<132, 68>(acc, &Xs[0][0], &Ws[64][0], n0, o0, 64);
    float b1[4], w2[4];
    #pragma unroll
    for (int j = 0; j < 4; ++j) {
        b1[j] = vattb1[o0 + j];
        w2[j] = vattW2[o0 + j];
    }
    float part[4];
    #pragma unroll
    for (int i = 0; i < 4; ++i) {
        float s = 0.f;
        #pragma unroll
        for (int j = 0; j < 4; ++j) {
            float hv = acc[i][j] + b1[j];
            hv = hv > 0.f ? hv : 0.f;
            s += hv * w2[j];
        }
        part[i] = s;
    }
    __syncthreads();
    float* red = &Ws[0][0];   // [32][17]
    #pragma unroll
    for (int i = 0; i < 4; ++i) red[(n0 + i) * 17 + to] = part[i];
    __syncthreads();
    if (tid < 32) {
        float s = 0.f;
        for (int u = 0; u < 16; ++u) s += red[tid * 17 + u];
        vscores[(size_t)v * NN + row0 + tid] = s + vattb2[0];
    }
}

// ---------------- fallback combine ----------------
__global__ __launch_bounds__(256) void combine_kernel(
        u16* __restrict__ aggB, const float* __restrict__ vscores,
        const float* __restrict__ node_att) {
    int t = blockIdx.x * 256 + threadIdx.x;
    int n = t >> 5, c4 = t & 31;
    float s0 = vscores[n], s1 = vscores[NN + n], s2 = vscores[2 * NN + n];
    float m = fmaxf(s0, fmaxf(s1, s2));
    float e0 = expf(s0 - m), e1 = expf(s1 - m), e2 = expf(s2 - m);
    float inv = 1.f / (e0 + e1 + e2);
    float w0 = e0 * inv, w1 = e1 * inv, w2 = e2 * inv;
    float na = node_att[n];
    size_t off = (size_t)n * DD + c4 * 4;
    ushort4 q0 = *reinterpret_cast<const ushort4*>(aggB + off);
    ushort4 q1 = *reinterpret_cast<const ushort4*>(aggB + (size_t)NN * DD + off);
    ushort4 q2 = *reinterpret_cast<const ushort4*>(aggB + 2 * (size_t)NN * DD + off);
    ushort4 r;
    r.x = f2bf((bf2f(q0.x) * w0 + bf2f(q1.x) * w1 + bf2f(q2.x) * w2) * na);
    r.y = f2bf((bf2f(q0.y) * w0 + bf2f(q1.y) * w1 + bf2f(q2.y) * w2) * na);
    r.z = f2bf((bf2f(q0.z) * w0 + bf2f(q1.z) * w1 + bf2f(q2.z) * w2) * na);
    r.w = f2bf((bf2f(q0.w) * w0 + bf2f(q1.w) * w1 + bf2f(q2.w) * w2) * na);
    *reinterpret_cast<ushort4*>(aggB + off) = r;
}

// ---------------- MFMA final + fused LABEL + fused combine ----
// R1's final with the label-attention phase fused in: the attW1 GEMM reuses
// the SAME featB A-fragments; na goes through LDS (no natt round-trip, no
// separate label kernel, no second featB read).
__global__ __launch_bounds__(256, 3) void final_mfma_kernel(
        const u16* __restrict__ featB, const u16* __restrict__ aggB,
        const float* __restrict__ vsc,
        const u16* __restrict__ attW1B,
        const float* __restrict__ clsW, const float* __restrict__ clsb,
        const float* __restrict__ attb1, const float* __restrict__ attW2,
        const float* __restrict__ attb2, const float* __restrict__ att_bias,
        const u16* __restrict__ WsfB, const u16* __restrict__ featWB,
        const u16* __restrict__ fusWbB,
        const float* __restrict__ c1, const float* __restrict__ featb,
        const float* __restrict__ ln_g, const float* __restrict__ ln_b,
        float* __restrict__ outp, float* __restrict__ probs_out) {
    __shared__ u16 Wf[128][136];   // featB, then Wsf, then combined; cols 128..133 = rw
    __shared__ u16 Wt[128][72];
    __shared__ float naS[128];
    int tid = threadIdx.x;
    int wv = tid >> 6, lane = tid & 63;
    int quad = lane >> 4, l15 = lane & 15;
    int row0 = blockIdx.x * 128;

    // stage featB -> Wf ; attW1B half0 -> Wt
    #pragma unroll
    for (int rep = 0; rep < 8; ++rep) {
        int flat = rep * 256 + tid;
        int n = flat >> 4, c8 = flat & 15;
        int gr = row0 + n; if (gr >= NN) gr = NN - 1;
        uint4 q = *reinterpret_cast<const uint4*>(featB + (size_t)gr * DD + c8 * 8);
        *reinterpret_cast<uint4*>(&Wf[n][c8 * 8]) = q;
    }
    stageWtHalf(Wt, attW1B, tid);
    __syncthreads();                                     // S1

    s8v af[2][2][2];
    loadFrags(af, Wf, wv, l15, quad);

    // ---------- label attention phase (fused) ----------
    {
        f4v accL[2][8];
        #pragma unroll
        for (int rt = 0; rt < 2; ++rt)
            #pragma unroll
            for (int c = 0; c < 8; ++c)
                accL[rt][c] = f4v{0.f, 0.f, 0.f, 0.f};
        mfmaWt8(accL, af, 0, Wt, l15, quad);
        __syncthreads();                                 // S2
        stageWtHalf(Wt, attW1B + 64, tid);
        __syncthreads();                                 // S3
        mfmaWt8(accL, af, 1, Wt, l15, quad);

        float ab1[8], aw2[8];
        #pragma unroll
        for (int c = 0; c < 8; ++c) {
            int col = c * 16 + l15;
            ab1[c] = attb1[col];
            aw2[c] = attW2[col];
        }
        float cw0[8], cw1[8];
        #pragma unroll
        for (int j = 0; j < 8; ++j) {
            int k = l15 * 8 + j;
            cw0[j] = clsW[k * 2];
            cw1[j] = clsW[k * 2 + 1];
        }
        float cb0 = clsb[0], cb1 = clsb[1];
        float b20 = attb2[0], b21 = attb2[1];
        float abias = att_bias[0];

        #pragma unroll
        for (int rt = 0; rt < 2; ++rt)
            #pragma unroll
            for (int r = 0; r < 4; ++r) {
                int n = wv * 32 + rt * 16 + quad * 4 + r;
                int gr = row0 + n;
                float p0 = 0.f, p1 = 0.f;
                #pragma unroll
                for (int c = 0; c < 4; ++c) {
                    float hv = accL[rt][c][r] + ab1[c];
                    hv = hv > 0.f ? hv : 0.f;
                    p0 += hv * aw2[c];
                }
                #pragma unroll
                for (int c = 4; c < 8; ++c) {
                    float hv = accL[rt][c][r] + ab1[c];
                    hv = hv > 0.f ? hv : 0.f;
                    p1 += hv * aw2[c];
                }
                uint4 q = *reinterpret_cast<const uint4*>(&Wf[n][l15 * 8]);
                float f[8];
                f[0] = bf2f((u16)(q.x & 0xffffu)); f[1] = bf2f((u16)(q.x >> 16));
                f[2] = bf2f((u16)(q.y & 0xffffu)); f[3] = bf2f((u16)(q.y >> 16));
                f[4] = bf2f((u16)(q.z & 0xffffu)); f[5] = bf2f((u16)(q.z >> 16));
                f[6] = bf2f((u16)(q.w & 0xffffu)); f[7] = bf2f((u16)(q.w >> 16));
                float l0 = 0.f, l1 = 0.f;
                #pragma unroll
                for (int j = 0; j < 8; ++j) {
                    l0 = fmaf(f[j], cw0[j], l0);
                    l1 = fmaf(f[j], cw1[j], l1);
                }
                #pragma unroll
                for (int m = 1; m < 16; m <<= 1) {
                    p0 += __shfl_xor(p0, m);
                    p1 += __shfl_xor(p1, m);
                    l0 += __shfl_xor(l0, m);
                    l1 += __shfl_xor(l1, m);
                }
                if (l15 == 0) {
                    float s0 = 1.f / (1.f + expf(-(p0 + b20)));
                    float s1 = 1.f / (1.f + expf(-(p1 + b21)));
                    l0 += cb0; l1 += cb1;
                    float mm = fmaxf(l0, l1);
                    float e0 = expf(l0 - mm), e1 = expf(l1 - mm);
                    float inv = 1.f / (e0 + e1);
                    float q0 = e0 * inv, q1 = e1 * inv;
                    naS[n] = q0 * s0 + q1 * s1 + abias;
                    if (gr < NN) {
                        probs_out[gr * 2]     = q0;
                        probs_out[gr * 2 + 1] = q1;
                    }
                }
            }
    }
    __syncthreads();                                     // S4: naS visible

    // per-row combine weights (softmax over views * node_att) -> Wf row padding
    if (tid < 128) {
        int gr = row0 + tid; if (gr >= NN) gr = NN - 1;
        float s0 = vsc[gr], s1 = vsc[NN + gr], s2 = vsc[2 * NN + gr];
        float m = fmaxf(s0, fmaxf(s1, s2));
        const float L2E = 1.4426950408889634f;
        float e0 = fexp2((s0 - m) * L2E);
        float e1 = fexp2((s1 - m) * L2E);
        float e2 = fexp2((s2 - m) * L2E);
        float na = naS[tid] * frcp(e0 + e1 + e2);
        float* rwp = reinterpret_cast<float*>(&Wf[tid][128]);
        rwp[0] = e0 * na;
        rwp[1] = e1 * na;
        rwp[2] = e2 * na;
    }

    // stage WsfB FULL -> Wf (cols 0..127 only; padding preserved) ; featWB h0 -> Wt
    stageWf(Wf, WsfB, tid);
    stageWtHalf(Wt, featWB, tid);
    __syncthreads();                                     // S5

    f4v acc1[2][8], acc2[2][8];
    #pragma unroll
    for (int rt = 0; rt < 2; ++rt)
        #pragma unroll
        for (int c = 0; c < 8; ++c) {
            acc1[rt][c] = f4v{0.f, 0.f, 0.f, 0.f};
            acc2[rt][c] = f4v{0.f, 0.f, 0.f, 0.f};
        }

    mfmaWfFull(acc1, af, Wf, l15, quad);      // X @ Wsf
    mfmaWt8(acc2, af, 0, Wt, l15, quad);      // X @ featW (h0)
    __syncthreads();                                     // S6
    stageWtHalf(Wt, featWB + 64, tid);
    __syncthreads();                                     // S7
    mfmaWt8(acc2, af, 1, Wt, l15, quad);      // X @ featW (h1)

    // fused combine: Wf cols 0..127 = bf16( rw0*view0 + rw1*view1 + rw2*view2 )
    #pragma unroll
    for (int rep = 0; rep < 8; ++rep) {
        int flat = rep * 256 + tid;
        int n = flat >> 4, c8 = flat & 15;
        int gr = row0 + n; if (gr >= NN) gr = NN - 1;
        size_t off = (size_t)gr * DD + c8 * 8;
        uint4 q0 = *reinterpret_cast<const uint4*>(aggB + off);
        uint4 q1 = *reinterpret_cast<const uint4*>(aggB + (size_t)NN * DD + off);
        uint4 q2 = *reinterpret_cast<const uint4*>(aggB + 2 * (size_t)NN * DD + off);
        const float* rwp = reinterpret_cast<const float*>(&Wf[n][128]);
        float w0 = rwp[0], w1 = rwp[1], w2 = rwp[2];
        u32 o[4];
        const u32* a = &q0.x; const u32* b = &q1.x; const u32* c = &q2.x;
        #pragma unroll
        for (int j = 0; j < 4; ++j) {
            float lo = bf2f((u16)(a[j] & 0xffffu)) * w0 + bf2f((u16)(b[j] & 0xffffu)) * w1
                     + bf2f((u16)(c[j] & 0xffffu)) * w2;
            float hi = bf2f((u16)(a[j] >> 16)) * w0 + bf2f((u16)(b[j] >> 16)) * w1
                     + bf2f((u16)(c[j] >> 16)) * w2;
            o[j] = (u32)f2bf(lo) | ((u32)f2bf(hi) << 16);
        }
        uint4 r; r.x = o[0]; r.y = o[1]; r.z = o[2]; r.w = o[3];
        *reinterpret_cast<uint4*>(&Wf[n][c8 * 8]) = r;
    }
    __syncthreads();                                     // S8

    // fus GEMM half0
    stageWtHalf(Wt, fusWbB, tid);
    __syncthreads();                                     // S9
    #pragma unroll
    for (int t = 0; t < 2; ++t) {
        int kl = t * 32 + quad * 8;
        s8v a0 = *reinterpret_cast<const s8v*>(&Wf[wv * 32 + l15][kl]);
        s8v a1 = *reinterpret_cast<const s8v*>(&Wf[wv * 32 + 16 + l15][kl]);
        #pragma unroll
        for (int c = 0; c < 8; ++c) {
            s8v b = *reinterpret_cast<const s8v*>(&Wt[c * 16 + l15][kl]);
            acc1[0][c] = __builtin_amdgcn_mfma_f32_16x16x32_bf16(a0, b, acc1[0][c], 0, 0, 0);
            acc1[1][c] = __builtin_amdgcn_mfma_f32_16x16x32_bf16(a1, b, acc1[1][c], 0, 0, 0);
        }
    }
    __syncthreads();                                     // S10
    stageWtHalf(Wt, fusWbB + 64, tid);
    __syncthreads();                                     // S11
    #pragma unroll
    for (int t = 0; t < 2; ++t) {
        int kl = t * 32 + quad * 8;
        s8v a0 = *reinterpret_cast<const s8v*>(&Wf[wv * 32 + l15][64 + kl]);
        s8v a1 = *reinterpret_cast<const s8v*>(&Wf[wv * 32 + 16 + l15][64 + kl]);
        #pragma unroll
        for (int c = 0; c < 8; ++c) {
            s8v b = *reinterpret_cast<const s8v*>(&Wt[c * 16 + l15][kl]);
            acc1[0][c] = __builtin_amdgcn_mfma_f32_16x16x32_bf16(a0, b, acc1[0][c], 0, 0, 0);
            acc1[1][c] = __builtin_amdgcn_mfma_f32_16x16x32_bf16(a1, b, acc1[1][c], 0, 0, 0);
        }
    }

    float c1j[8], fbj[8], gj[8], bj[8];
    #pragma unroll
    for (int c = 0; c < 8; ++c) {
        int col = c * 16 + l15;
        c1j[c] = c1[col];
        fbj[c] = featb[col];
        gj[c]  = ln_g[col];
        bj[c]  = ln_b[col];
    }
    #pragma unroll
    for (int rt = 0; rt < 2; ++rt)
        #pragma unroll
        for (int c = 0; c < 8; ++c)
            #pragma unroll
            for (int r = 0; r < 4; ++r) {
                float f = acc1[rt][c][r] + c1j[c];
                f = f > 0.f ? f : 0.f;
                acc1[rt][c][r] = f + acc2[rt][c][r] + fbj[c];
            }
    #pragma unroll
    for (int rt = 0; rt < 2; ++rt)
        #pragma unroll
        for (int r = 0; r < 4; ++r) {
            float s = 0.f, q = 0.f;
            #pragma unroll
            for (int c = 0; c < 8; ++c) {
                float x = acc1[rt][c][r];
                s += x; q += x * x;
            }
            #pragma unroll
            for (int m = 1; m < 16; m <<= 1) {
                s += __shfl_xor(s, m);
                q += __shfl_xor(q, m);
            }
            float mu = s * (1.f / 128.f);
            float var = q * (1.f / 128.f) - mu * mu;
            float rs = rsqrtf(var + 1e-5f);
            int gr = row0 + wv * 32 + rt * 16 + quad * 4 + r;
            if (gr < NN) {
                #pragma unroll
                for (int c = 0; c < 8; ++c)
                    outp[(size_t)gr * DD + c * 16 + l15] =
                        (acc1[rt][c][r] - mu) * rs * gj[c] + bj[c];
            }
        }
}

// ---------------- fallback VALU final ----------------
__global__ __launch_bounds__(256) void final_kernel(
        const float* __restrict__ feat, const u16* __restrict__ weightedB,
        const float* __restrict__ Wsf, const float* __restrict__ c1,
        const float* __restrict__ fusW, const float* __restrict__ featW,
        const float* __restrict__ featb, const float* __restrict__ ln_g,
        const float* __restrict__ ln_b, float* __restrict__ outp) {
    __shared__ float Xs[32][128];
    __shared__ float Ws[64][128];
    int tid = threadIdx.x;
    int row0 = blockIdx.x * 32;
    stage_x_f32<128, 256>(&Xs[0][0], feat + (size_t)row0 * DD, tid);
    int to = tid & 31, tn = tid >> 5;
    int o0 = to * 4, n0 = tn * 4;
    float acc1[4][4] = {}, acc2[4][4] = {};
    for (int half = 0; half < 2; ++half) {
        __syncthreads();
        stage_w_f32<128, 256>(&Ws[0][0], Wsf + half * 64 * 128, tid);
        __syncthreads();
        gemm16<128, 128>(acc1, &Xs[0][0], &Ws[0][0], n0, o0, half * 64);
    }
    for (int half = 0; half < 2; ++half) {
        __syncthreads();
        stage_w_f32<128, 256>(&Ws[0][0], featW + half * 64 * 128, tid);
        __syncthreads();
        gemm16<128, 128>(acc2, &Xs[0][0], &Ws[0][0], n0, o0, half * 64);
    }
    __syncthreads();
    stage_x_bf16<128, 256>(&Xs[0][0], weightedB + (size_t)row0 * DD, tid);
    for (int half = 0; half < 2; ++half) {
        __syncthreads();
        stage_w_f32<128, 256>(&Ws[0][0], fusW + (size_t)(128 + half * 64) * 128, tid);
        __syncthreads();
        gemm16<128, 128>(acc1, &Xs[0][0], &Ws[0][0], n0, o0, half * 64);
    }
    float c1j[4], fbj[4], gj[4], bj[4];
    #pragma unroll
    for (int j = 0; j < 4; ++j) {
        c1j[j] = c1[o0 + j];
        fbj[j] = featb[o0 + j];
        gj[j]  = ln_g[o0 + j];
        bj[j]  = ln_b[o0 + j];
    }
    float val[4][4];
    #pragma unroll
    for (int i = 0; i < 4; ++i)
        #pragma unroll
        for (int j = 0; j < 4; ++j) {
            float f = acc1[i][j] + c1j[j];
            f = f > 0.f ? f : 0.f;
            val[i][j] = f + acc2[i][j] + fbj[j];
        }
    __syncthreads();
    float* red_s = &Ws[0][0];
    float* red_q = red_s + 32 * 33;
    float* mus   = red_q + 32 * 33;
    float* rss   = mus + 32;
    #pragma unroll
    for (int i = 0; i < 4; ++i) {
        float s = 0.f, q = 0.f;
        #pragma unroll
        for (int j = 0; j < 4; ++j) { s += val[i][j]; q += val[i][j] * val[i][j]; }
        red_s[(n0 + i) * 33 + to] = s;
        red_q[(n0 + i) * 33 + to] = q;
    }
    __syncthreads();
    if (tid < 32) {
        float s = 0.f, q = 0.f;
        for (int u = 0; u < 32; ++u) { s += red_s[tid * 33 + u]; q += red_q[tid * 33 + u]; }
        float mu = s / 128.f;
        float var = q / 128.f - mu * mu;
        mus[tid] = mu;
        rss[tid] = rsqrtf(var + 1e-5f);
    }
    __syncthreads();
    #pragma unroll
    for (int i = 0; i < 4; ++i) {
        float mu = mus[n0 + i], rs = rss[n0 + i];
        float4 o;
        o.x = (val[i][0] - mu) * rs * gj[0] + bj[0];
        o.y = (val[i][1] - mu) * rs * gj[1] + bj[1];
        o.z = (val[i][2] - mu) * rs * gj[2] + bj[2];
        o.w = (val[i][3] - mu) * rs * gj[3] + bj[3];
        *reinterpret_cast<float4*>(outp + (size_t)(row0 + n0 + i) * DD + o0) = o;
    }
}

extern "C" void kernel_launch(void* const* d_in, const int* in_sizes, int n_in,
                              void* d_out, int out_size, void* d_ws, size_t ws_size,
                              hipStream_t stream) {
    (void)in_sizes; (void)n_in; (void)out_size;
    const float* feat      = (const float*)d_in[0];
    const int*   esrc      = (const int*)d_in[1];
    const int*   edst      = (const int*)d_in[2];
    const float* ew        = (const float*)d_in[3];
    const float* clsW      = (const float*)d_in[4];
    const float* clsb      = (const float*)d_in[5];
    const float* attW1     = (const float*)d_in[6];
    const float* attb1     = (const float*)d_in[7];
    const float* attW2     = (const float*)d_in[8];
    const float* attb2     = (const float*)d_in[9];
    const float* att_bias  = (const float*)d_in[10];
    const float* relW      = (const float*)d_in[11];
    const float* relb      = (const float*)d_in[12];
    const float* gateW     = (const float*)d_in[13];
    const float* gateb     = (const float*)d_in[14];
    const float* view_pref = (const float*)d_in[15];
    const float* vattW1    = (const float*)d_in[16];
    const float* vattb1    = (const float*)d_in[17];
    const float* vattW2    = (const float*)d_in[18];
    const float* vattb2    = (const float*)d_in[19];
    const float* selfW     = (const float*)d_in[20];
    const float* selfb     = (const float*)d_in[21];
    const float* featW     = (const float*)d_in[22];
    const float* featb     = (const float*)d_in[23];
    const float* fusW      = (const float*)d_in[24];
    const float* fusb      = (const float*)d_in[25];
    const float* ln_g      = (const float*)d_in[26];
    const float* ln_b      = (const float*)d_in[27];

    // workspace layout (~120 MiB):
    u16*   aggB = (u16*)d_ws;                                   // [3][N][128] bf16
    float* wsum = (float*)(aggB + (size_t)VV * NN * DD);        // [3][N]
    float* natt = wsum + (size_t)VV * NN;                       // [N] (fallback only)
    float* vsc  = natt + NN;                                    // [3][N]
    float* Wsf  = vsc + (size_t)VV * NN;                        // [128][128]
    float* c1   = Wsf + DD * DD;                                // [128]
    u16* relWb  = (u16*)(c1 + DD);                              // [3][128][128] bf16
    u16* gateWb = relWb + (size_t)VV * DD * DD;                 // [3][128][128] bf16
    u16* WsfB   = gateWb + (size_t)VV * DD * DD;                // [128][128] bf16
    u16* featWB = WsfB + DD * DD;                               // [128][128] bf16
    u16* fusWbB = featWB + DD * DD;                             // [128][128] bf16
    u16* attW1B = fusWbB + DD * DD;                             // [128][128] bf16
    u16* vattW1p = attW1B + DD * DD;                            // [3][64][128] bf16
    u16* W12b   = vattW1p + (size_t)VV * 64 * DD;               // [3][128][128] bf16
    float* rgb  = (float*)(W12b + (size_t)VV * DD * DD);        // [3][128]
    int*   C    = (int*)(rgb + VV * DD);                        // [3N]
    int*   bs   = C + (size_t)TOT;                              // [NB]
    int2*  bsw  = (int2*)(bs + NB + 1);                         // [3E] packed (src,w)
    u16* featB  = (u16*)(bsw + (size_t)VV * EE);                // [N][128] bf16
    size_t needed = (size_t)((char*)(featB + (size_t)NN * DD) - (char*)d_ws);

    float* outp  = (float*)d_out;
    float* probs = outp + (size_t)NN * DD;

    prep_kernel<<<129, 128, 0, stream>>>(selfW, selfb, fusW, fusb, Wsf, c1);
    if (ws_size >= needed) {
        featconv_kernel<<<12500, 256, 0, stream>>>(feat, featB);
        wprep_kernel<<<384, 128, 0, stream>>>(relW, gateW, relWb, gateWb);
        wprep2_kernel<<<128, 128, 0, stream>>>(Wsf, featW, fusW, WsfB, featWB, fusWbB);
        wprep3_kernel<<<128, 128, 0, stream>>>(attW1, attW1B);
        wprep4_kernel<<<192, 128, 0, stream>>>(vattW1, view_pref, vattW1p);
        wprep5_kernel<<<VV * 129, 128, 0, stream>>>(relW, gateW, relb, W12b, rgb);
        hipMemsetAsync(C, 0, (size_t)TOT * sizeof(int), stream);
        count_kernel<<<(VV * EE + 255) / 256, 256, 0, stream>>>(edst, C);
        scanA_kernel<<<NB, 256, 0, stream>>>(C, bs);
        scanB_kernel<<<1, 1024, 0, stream>>>(bs);
        scanC_kernel<<<NB, 256, 0, stream>>>(C, bs);
        fill_kernel<<<(VV * EE + 255) / 256, 256, 0, stream>>>(esrc, edst, ew, C, bsw);
        gather_kernel<<<(VV * NN) / 4, 256, 0, stream>>>(featB, C, bsw, aggB, wsum);
        relgate_mfma_kernel<<<dim3(RGB, 3), 256, 0, stream>>>(relWb, relb, W12b, rgb, gateb,
                                                              vattW1p, vattb1, vattW2, vattb2,
                                                              aggB, wsum, vsc);
        final_mfma_kernel<<<RGB, 256, 0, stream>>>(featB, aggB, vsc,
                                                   attW1B, clsW, clsb, attb1, attW2,
                                                   attb2, att_bias,
                                                   WsfB, featWB, fusWbB,
                                                   c1, featb, ln_g, ln_b, outp, probs);
    } else {
        label_kernel<<<3125, 256, 0, stream>>>(feat, clsW, clsb, attW1, attb1, attW2, attb2,
                                               att_bias, natt, probs);
        hipMemsetAsync(d_ws, 0,
                       (size_t)VV * NN * DD * sizeof(u16) + (size_t)VV * NN * sizeof(float),
                       stream);
        scatter_kernel<<<187500, 256, 0, stream>>>(esrc, edst, ew, feat, aggB, wsum);
        relgate_kernel<<<dim3(3125, 3), 256, 0, stream>>>(relW, relb, gateW, gateb, aggB, wsum);
        vatt_kernel<<<dim3(3125, 3), 128, 0, stream>>>(aggB, view_pref, vattW1, vattb1,
                                                       vattW2, vattb2, vsc);
        combine_kernel<<<12500, 256, 0, stream>>>(aggB, vsc, natt);
        final_kernel<<<3125, 256, 0, stream>>>(feat, aggB, Wsf, c1, fusW, featW, featb,
                                               ln_g, ln_b, outp);
    }
}

// Round 8
// 638.499 us; speedup vs baseline: 1.4759x; 1.0361x over previous
//
#include <hip/hip_runtime.h>
#include <hip/hip_bf16.h>

#define NN 100000
#define DD 128
#define VV 3
#define EE 500000
#define TOT (VV * NN)                 // 300000 rows
#define NB ((TOT + 255) / 256)        // 1172 scan blocks
#define RGB ((NN + 127) / 128)        // 782 mfma blocks

typedef unsigned short u16;
typedef unsigned int u32;
typedef short s8v __attribute__((ext_vector_type(8)));   // 8 bf16 (4 VGPRs)
typedef float f4v __attribute__((ext_vector_type(4)));   // MFMA accumulator

__device__ __forceinline__ float bf2f(u16 u) {
    return __uint_as_float(((u32)u) << 16);
}
__device__ __forceinline__ u16 f2bf(float f) {
    u32 x = __float_as_uint(f);
    u32 r = (x + 0x7fffu + ((x >> 16) & 1u)) >> 16;
    return (u16)r;
}

__device__ __forceinline__ float fexp2(float x) {
#if __has_builtin(__builtin_amdgcn_exp2f)
    return __builtin_amdgcn_exp2f(x);
#else
    return exp2f(x);
#endif
}
__device__ __forceinline__ float frcp(float x) {
#if __has_builtin(__builtin_amdgcn_rcpf)
    return __builtin_amdgcn_rcpf(x);
#else
    return 1.f / x;
#endif
}
__device__ __forceinline__ float fsigmoid(float x) {
    return frcp(1.f + fexp2(-1.4426950408889634f * x));
}

// packed bf16 atomic add (fallback path only)
__device__ __forceinline__ void atomAddBf16x2(u16* addr, float f0, float f1) {
#if __has_builtin(__builtin_amdgcn_global_atomic_fadd_v2bf16)
    typedef short v2s __attribute__((ext_vector_type(2)));
    typedef v2s __attribute__((address_space(1)))* v2s_gp;
    v2s v;
    v.x = (short)f2bf(f0);
    v.y = (short)f2bf(f1);
    __builtin_amdgcn_global_atomic_fadd_v2bf16((v2s_gp)(void*)addr, v);
#else
    u32* p = (u32*)addr;
    u32 old = *(volatile u32*)p;
    while (true) {
        float lo = bf2f((u16)(old & 0xffffu)) + f0;
        float hi = bf2f((u16)(old >> 16)) + f1;
        u32 nv = (u32)f2bf(lo) | ((u32)f2bf(hi) << 16);
        u32 prev = atomicCAS(p, old, nv);
        if (prev == old) break;
        old = prev;
    }
#endif
}

// ---- generic VALU GEMM accumulate (fallback path) ----
template<int XSTR, int WSTR>
__device__ __forceinline__ void gemm16(float acc[4][4], const float* Xs,
                                       const float* Ws, int n0, int o0, int kbase) {
    #pragma unroll 4
    for (int kk = 0; kk < 64; kk += 4) {
        float4 w0 = *reinterpret_cast<const float4*>(Ws + (kk + 0) * WSTR + o0);
        float4 w1 = *reinterpret_cast<const float4*>(Ws + (kk + 1) * WSTR + o0);
        float4 w2 = *reinterpret_cast<const float4*>(Ws + (kk + 2) * WSTR + o0);
        float4 w3 = *reinterpret_cast<const float4*>(Ws + (kk + 3) * WSTR + o0);
        #pragma unroll
        for (int i = 0; i < 4; ++i) {
            float4 x = *reinterpret_cast<const float4*>(Xs + (n0 + i) * XSTR + kbase + kk);
            acc[i][0] = fmaf(x.x, w0.x, fmaf(x.y, w1.x, fmaf(x.z, w2.x, fmaf(x.w, w3.x, acc[i][0]))));
            acc[i][1] = fmaf(x.x, w0.y, fmaf(x.y, w1.y, fmaf(x.z, w2.y, fmaf(x.w, w3.y, acc[i][1]))));
            acc[i][2] = fmaf(x.x, w0.z, fmaf(x.y, w1.z, fmaf(x.z, w2.z, fmaf(x.w, w3.z, acc[i][2]))));
            acc[i][3] = fmaf(x.x, w0.w, fmaf(x.y, w1.w, fmaf(x.z, w2.w, fmaf(x.w, w3.w, acc[i][3]))));
        }
    }
}

template<int WSTR, int NT>
__device__ __forceinline__ void stage_w_f32(float* Ws, const float* __restrict__ src, int tid) {
    #pragma unroll
    for (int rep = 0; rep < 2048 / NT; ++rep) {
        int flat = rep * NT + tid;
        int kk = flat >> 5;
        int c4 = flat & 31;
        float4 q = *reinterpret_cast<const float4*>(src + kk * 128 + c4 * 4);
        *reinterpret_cast<float4*>(Ws + kk * WSTR + c4 * 4) = q;
    }
}

template<int XSTR, int NT>
__device__ __forceinline__ void stage_x_f32(float* Xs, const float* __restrict__ src, int tid) {
    #pragma unroll
    for (int rep = 0; rep < 1024 / NT; ++rep) {
        int flat = rep * NT + tid;
        int n = flat >> 5;
        int c4 = flat & 31;
        float4 q = *reinterpret_cast<const float4*>(src + (size_t)n * 128 + c4 * 4);
        *reinterpret_cast<float4*>(Xs + n * XSTR + c4 * 4) = q;
    }
}

template<int XSTR, int NT>
__device__ __forceinline__ void stage_x_bf16(float* Xs, const u16* __restrict__ src, int tid) {
    #pragma unroll
    for (int rep = 0; rep < 512 / NT; ++rep) {
        int flat = rep * NT + tid;
        int n = flat >> 4;
        int c8 = flat & 15;
        uint4 q = *reinterpret_cast<const uint4*>(src + (size_t)n * 128 + c8 * 8);
        float* d = Xs + n * XSTR + c8 * 8;
        d[0] = bf2f((u16)(q.x & 0xffffu)); d[1] = bf2f((u16)(q.x >> 16));
        d[2] = bf2f((u16)(q.y & 0xffffu)); d[3] = bf2f((u16)(q.y >> 16));
        d[4] = bf2f((u16)(q.z & 0xffffu)); d[5] = bf2f((u16)(q.z >> 16));
        d[6] = bf2f((u16)(q.w & 0xffffu)); d[7] = bf2f((u16)(q.w >> 16));
    }
}

// ======== MFMA staging / fragment helpers (256 threads) ========

// full 128x128 bf16 weight tile -> Wf (cols 0..127; row padding untouched)
__device__ __forceinline__ void stageWf(u16 (*Wf)[136], const u16* __restrict__ src, int tid) {
    #pragma unroll
    for (int rep = 0; rep < 8; ++rep) {
        int flat = rep * 256 + tid;
        int n = flat >> 4, c8 = flat & 15;
        *reinterpret_cast<uint4*>(&Wf[n][c8 * 8]) =
            *reinterpret_cast<const uint4*>(src + (size_t)n * DD + c8 * 8);
    }
}

// 128x64 half-k weight tile -> Wt (src already offset by h*64)
__device__ __forceinline__ void stageWtHalf(u16 (*Wt)[72], const u16* __restrict__ src, int tid) {
    #pragma unroll
    for (int rep = 0; rep < 4; ++rep) {
        int flat = rep * 256 + tid;
        int n = flat >> 3, c8 = flat & 7;
        *reinterpret_cast<uint4*>(&Wt[n][c8 * 8]) =
            *reinterpret_cast<const uint4*>(src + (size_t)n * DD + c8 * 8);
    }
}

// 128-row X tile (row-clamped) -> Wf
__device__ __forceinline__ void stageX(u16 (*Wf)[136], const u16* __restrict__ src,
                                       int row0, int tid) {
    #pragma unroll
    for (int rep = 0; rep < 8; ++rep) {
        int flat = rep * 256 + tid;
        int n = flat >> 4, c8 = flat & 15;
        int gr = row0 + n; if (gr >= NN) gr = NN - 1;
        *reinterpret_cast<uint4*>(&Wf[n][c8 * 8]) =
            *reinterpret_cast<const uint4*>(src + (size_t)gr * DD + c8 * 8);
    }
}

// A-fragments (whole K=128) for this wave's 32 rows
__device__ __forceinline__ void loadFrags(s8v af[2][2][2], u16 (*Wf)[136],
                                          int wv, int l15, int quad) {
    #pragma unroll
    for (int h = 0; h < 2; ++h)
        #pragma unroll
        for (int t = 0; t < 2; ++t) {
            int kl = h * 64 + t * 32 + quad * 8;
            af[h][t][0] = *reinterpret_cast<const s8v*>(&Wf[wv * 32 + l15][kl]);
            af[h][t][1] = *reinterpret_cast<const s8v*>(&Wf[wv * 32 + 16 + l15][kl]);
        }
}

// acc += af[h] (x) Wt  (half-k, 8 col-tiles, 32 MFMA)
__device__ __forceinline__ void mfmaWt8(f4v acc[2][8], const s8v af[2][2][2], int h,
                                        u16 (*Wt)[72], int l15, int quad) {
    #pragma unroll
    for (int t = 0; t < 2; ++t) {
        int kl = t * 32 + quad * 8;
        #pragma unroll
        for (int c = 0; c < 8; ++c) {
            s8v b = *reinterpret_cast<const s8v*>(&Wt[c * 16 + l15][kl]);
            acc[0][c] = __builtin_amdgcn_mfma_f32_16x16x32_bf16(af[h][t][0], b, acc[0][c], 0, 0, 0);
            acc[1][c] = __builtin_amdgcn_mfma_f32_16x16x32_bf16(af[h][t][1], b, acc[1][c], 0, 0, 0);
        }
    }
}

// acc += af (x) Wf  (full-k, 8 col-tiles, 64 MFMA)
__device__ __forceinline__ void mfmaWfFull(f4v acc[2][8], const s8v af[2][2][2],
                                           u16 (*Wf)[136], int l15, int quad) {
    #pragma unroll
    for (int h = 0; h < 2; ++h)
        #pragma unroll
        for (int t = 0; t < 2; ++t) {
            int kl = h * 64 + t * 32 + quad * 8;
            #pragma unroll
            for (int c = 0; c < 8; ++c) {
                s8v b = *reinterpret_cast<const s8v*>(&Wf[c * 16 + l15][kl]);
                acc[0][c] = __builtin_amdgcn_mfma_f32_16x16x32_bf16(af[h][t][0], b, acc[0][c], 0, 0, 0);
                acc[1][c] = __builtin_amdgcn_mfma_f32_16x16x32_bf16(af[h][t][1], b, acc[1][c], 0, 0, 0);
            }
        }
}

// ================= mega prep kernel (main path) =================
// One dispatch covering: featconv, relW/gateW transpose, WsfB(direct GEMM),
// featWB/fusWbB, c1, attW1B, vattW1p, W12b/rgb, and count. Segments are
// independent (disjoint outputs); count's atomic latency hides under the
// streaming/compute segments.
#define PAE0 3200000                      // featconv (float4 chunks)
#define PAE1 (PAE0 + 49152)               // relWb/gateWb transpose
#define PAE2 (PAE1 + 16384)               // WsfB direct
#define PAE3 (PAE2 + 16384)               // featWB + fusWbB
#define PAE4 (PAE3 + 128)                 // c1
#define PAE5 (PAE4 + 16384)               // attW1B
#define PAE6 (PAE5 + 24576)               // vattW1p
#define PAE7 (PAE6 + 49152)               // W12b
#define PAE8 (PAE7 + 384)                 // rgb
#define PAE9 (PAE8 + (VV * EE))           // count
#define PA_GRID ((PAE9 + 255) / 256)

__global__ __launch_bounds__(256) void prep_all_kernel(
        const float* __restrict__ feat, u16* __restrict__ featB,
        const float* __restrict__ relW, const float* __restrict__ gateW,
        u16* __restrict__ relWb, u16* __restrict__ gateWb,
        const float* __restrict__ selfW, const float* __restrict__ selfb,
        const float* __restrict__ fusW, const float* __restrict__ fusb,
        u16* __restrict__ WsfB, float* __restrict__ c1,
        const float* __restrict__ featW, u16* __restrict__ featWB,
        u16* __restrict__ fusWbB,
        const float* __restrict__ attW1, u16* __restrict__ attW1B,
        const float* __restrict__ vattW1, const float* __restrict__ view_pref,
        u16* __restrict__ vattW1p,
        const float* __restrict__ relb, u16* __restrict__ W12b,
        float* __restrict__ rgb,
        const int* __restrict__ edst, int* __restrict__ C) {
    int id = blockIdx.x * 256 + threadIdx.x;
    if (id < PAE0) {
        // featconv: feat fp32 -> bf16
        float4 q = *reinterpret_cast<const float4*>(feat + (size_t)id * 4);
        ushort4 r;
        r.x = f2bf(q.x); r.y = f2bf(q.y); r.z = f2bf(q.z); r.w = f2bf(q.w);
        *reinterpret_cast<ushort4*>(featB + (size_t)id * 4) = r;
    } else if (id < PAE1) {
        int t = id - PAE0;
        int v = t >> 14, rem = t & 16383, n = rem >> 7, k = rem & 127;
        size_t o = ((size_t)v * 128 + n) * 128 + k;
        size_t i = ((size_t)v * 128 + k) * 128 + n;
        relWb[o]  = f2bf(relW[i]);
        gateWb[o] = f2bf(gateW[i]);
    } else if (id < PAE2) {
        // WsfB[n][k] = bf16( (selfW @ fusW_top)[k][n] )  (direct dot)
        int t = id - PAE1;
        int n = t >> 7, k = t & 127;
        float acc = 0.f;
        for (int m = 0; m < 128; ++m)
            acc += selfW[k * 128 + m] * fusW[m * 128 + n];
        WsfB[n * 128 + k] = f2bf(acc);
    } else if (id < PAE3) {
        int t = id - PAE2;
        int n = t >> 7, k = t & 127;
        featWB[n * 128 + k] = f2bf(featW[k * 128 + n]);
        fusWbB[n * 128 + k] = f2bf(fusW[(size_t)(128 + k) * 128 + n]);
    } else if (id < PAE4) {
        int o = id - PAE3;
        float acc = 0.f;
        for (int m = 0; m < 128; ++m)
            acc += selfb[m] * fusW[m * 128 + o];
        c1[o] = acc + fusb[o];
    } else if (id < PAE5) {
        int t = id - PAE4;
        int o = t >> 7, k = t & 127;
        int c = o >> 6, h = o & 63;
        attW1B[o * 128 + k] = f2bf(attW1[((size_t)c * 128 + k) * 64 + h]);
    } else if (id < PAE6) {
        int t = id - PAE5;
        int v = t / 8192, rem = t - v * 8192, h = rem >> 7, k = rem & 127;
        vattW1p[((size_t)v * 64 + h) * 128 + k] =
            f2bf(view_pref[v * 128 + k] * vattW1[k * 64 + h]);
    } else if (id < PAE7) {
        int t = id - PAE6;
        int v = t >> 14, rem = t & 16383, d = rem >> 7, p = rem & 127;
        const float* gW = gateW + (size_t)v * 128 * 128;
        const float* rW = relW + ((size_t)v * 128 + d) * 128;
        float acc = 0.f;
        for (int o = 0; o < 128; ++o) acc += rW[o] * gW[o * 128 + p];
        W12b[((size_t)v * 128 + p) * 128 + d] = f2bf(acc);
    } else if (id < PAE8) {
        int t = id - PAE7;
        int v = t >> 7, p = t & 127;
        const float* gW = gateW + (size_t)v * 128 * 128;
        const float* rb = relb + (size_t)v * 128;
        float acc = 0.f;
        for (int o = 0; o < 128; ++o) acc += rb[o] * gW[o * 128 + p];
        rgb[v * 128 + p] = acc;
    } else if (id < PAE9) {
        int t = id - PAE8;
        int v = t / EE;
        atomicAdd(&C[v * NN + edst[t]], 1);
    }
}

// ---------------- prep (fallback path): Wsf = selfW @ fusW_top ; c1 ----
__global__ void prep_kernel(const float* __restrict__ selfW, const float* __restrict__ selfb,
                            const float* __restrict__ fusW, const float* __restrict__ fusb,
                            float* __restrict__ Wsf, float* __restrict__ c1) {
    int o = threadIdx.x;
    int k = blockIdx.x;
    if (k < 128) {
        float acc = 0.f;
        for (int m = 0; m < 128; ++m)
            acc += selfW[k * 128 + m] * fusW[m * 128 + o];
        Wsf[k * 128 + o] = acc;
    } else {
        float acc = 0.f;
        for (int m = 0; m < 128; ++m)
            acc += selfb[m] * fusW[m * 128 + o];
        c1[o] = acc + fusb[o];
    }
}

// ================= CSR build (hierarchical scan) + gather =================

__global__ __launch_bounds__(256) void scanA_kernel(
        const int* __restrict__ C, int* __restrict__ bs) {
    int b = blockIdx.x, t = threadIdx.x;
    int i = b * 256 + t;
    int v = (i < TOT) ? C[i] : 0;
    __shared__ int s[256];
    s[t] = v;
    __syncthreads();
    #pragma unroll
    for (int off = 128; off > 0; off >>= 1) {
        if (t < off) s[t] += s[t + off];
        __syncthreads();
    }
    if (t == 0) bs[b] = s[0];
}

__global__ __launch_bounds__(1024) void scanB_kernel(int* __restrict__ bs) {
    __shared__ int s[2048];
    int t = threadIdx.x;
    int v0 = (t < NB) ? bs[t] : 0;
    int v1 = (t + 1024 < NB) ? bs[t + 1024] : 0;
    s[t] = v0; s[t + 1024] = v1;
    __syncthreads();
    #pragma unroll
    for (int off = 1; off < 2048; off <<= 1) {
        int x0 = (t >= off) ? s[t - off] : 0;
        int x1 = (t + 1024 >= off) ? s[t + 1024 - off] : 0;
        __syncthreads();
        s[t] += x0; s[t + 1024] += x1;
        __syncthreads();
    }
    if (t < NB) bs[t] = s[t] - v0;
    if (t + 1024 < NB) bs[t + 1024] = s[t + 1024] - v1;
}

__global__ __launch_bounds__(256) void scanC_kernel(
        int* __restrict__ C, const int* __restrict__ bs) {
    int b = blockIdx.x, t = threadIdx.x;
    int i = b * 256 + t;
    int v = (i < TOT) ? C[i] : 0;
    __shared__ int s[256];
    s[t] = v;
    __syncthreads();
    #pragma unroll
    for (int off = 1; off < 256; off <<= 1) {
        int x = (t >= off) ? s[t - off] : 0;
        __syncthreads();
        s[t] += x;
        __syncthreads();
    }
    if (i < TOT) C[i] = s[t] - v + bs[b];
}

// count (fallback path; main path counts inside prep_all)
__global__ __launch_bounds__(256) void count_kernel(
        const int* __restrict__ edst, int* __restrict__ C) {
    int t = blockIdx.x * 256 + threadIdx.x;
    if (t >= VV * EE) return;
    int v = t / EE;
    atomicAdd(&C[v * NN + edst[t]], 1);
}

// fill: packed (src, w) per bucket slot; C becomes inclusive row ends
__global__ __launch_bounds__(256) void fill_kernel(
        const int* __restrict__ esrc, const int* __restrict__ edst,
        const float* __restrict__ ew, int* __restrict__ C,
        int2* __restrict__ bsw) {
    int t = blockIdx.x * 256 + threadIdx.x;
    if (t >= VV * EE) return;
    int v = t / EE;
    int pos = atomicAdd(&C[v * NN + edst[t]], 1);
    int2 p;
    p.x = esrc[t];
    p.y = __float_as_int(ew[t]);
    bsw[pos] = p;
}

// one wave per (v,dst) row, unroll-4 to overlap the load chains
__global__ __launch_bounds__(256) void gather_kernel(
        const u16* __restrict__ featB, const int* __restrict__ C,
        const int2* __restrict__ bsw,
        u16* __restrict__ aggB, float* __restrict__ wsum) {
    int wid = (blockIdx.x * 256 + threadIdx.x) >> 6;
    int lane = threadIdx.x & 63;
    int end = C[wid];
    int start = (wid == 0) ? 0 : C[wid - 1];
    float a0 = 0.f, a1 = 0.f, wacc = 0.f;
    int e = start;
    for (; e + 4 <= end; e += 4) {
        int2 p0 = bsw[e], p1 = bsw[e + 1], p2 = bsw[e + 2], p3 = bsw[e + 3];
        u32 f0 = *reinterpret_cast<const u32*>(featB + (size_t)p0.x * DD + lane * 2);
        u32 f1 = *reinterpret_cast<const u32*>(featB + (size_t)p1.x * DD + lane * 2);
        u32 f2 = *reinterpret_cast<const u32*>(featB + (size_t)p2.x * DD + lane * 2);
        u32 f3 = *reinterpret_cast<const u32*>(featB + (size_t)p3.x * DD + lane * 2);
        float w0 = __int_as_float(p0.y), w1 = __int_as_float(p1.y);
        float w2 = __int_as_float(p2.y), w3 = __int_as_float(p3.y);
        a0 = fmaf(w0, bf2f((u16)(f0 & 0xffffu)), a0);
        a1 = fmaf(w0, bf2f((u16)(f0 >> 16)), a1);
        a0 = fmaf(w1, bf2f((u16)(f1 & 0xffffu)), a0);
        a1 = fmaf(w1, bf2f((u16)(f1 >> 16)), a1);
        a0 = fmaf(w2, bf2f((u16)(f2 & 0xffffu)), a0);
        a1 = fmaf(w2, bf2f((u16)(f2 >> 16)), a1);
        a0 = fmaf(w3, bf2f((u16)(f3 & 0xffffu)), a0);
        a1 = fmaf(w3, bf2f((u16)(f3 >> 16)), a1);
        wacc += (w0 + w1) + (w2 + w3);
    }
    for (; e < end; ++e) {
        int2 p = bsw[e];
        float w = __int_as_float(p.y);
        u32 f = *reinterpret_cast<const u32*>(featB + (size_t)p.x * DD + lane * 2);
        a0 = fmaf(w, bf2f((u16)(f & 0xffffu)), a0);
        a1 = fmaf(w, bf2f((u16)(f >> 16)), a1);
        wacc += w;
    }
    u32 packed = (u32)f2bf(a0) | ((u32)f2bf(a1) << 16);
    *reinterpret_cast<u32*>(aggB + (size_t)wid * DD + lane * 2) = packed;
    if (lane == 0) wsum[wid] = wacc;
}

// ================= fallback: atomic scatter =================
__global__ __launch_bounds__(256) void scatter_kernel(
        const int* __restrict__ esrc, const int* __restrict__ edst,
        const float* __restrict__ ew, const float* __restrict__ feat,
        u16* __restrict__ aggB, float* __restrict__ wsum) {
    long long t = (long long)blockIdx.x * 256 + threadIdx.x;
    int lane = (int)(t & 31);
    int eg = (int)(t >> 5);
    int v = eg / EE;
    int src = 0, dst = 0; float w = 0.f;
    if (lane == 0) {
        src = esrc[eg]; dst = edst[eg]; w = ew[eg];
    }
    src = __shfl(src, 0, 32);
    dst = __shfl(dst, 0, 32);
    w   = __shfl(w, 0, 32);
    const float* fr = feat + (size_t)src * DD + lane * 4;
    float4 q = *reinterpret_cast<const float4*>(fr);
    u16* outp = aggB + ((size_t)v * NN + dst) * DD + lane * 4;
    atomAddBf16x2(outp,     w * q.x, w * q.y);
    atomAddBf16x2(outp + 2, w * q.z, w * q.w);
    if (lane == 0) atomicAdd(wsum + v * NN + dst, w);
}

// ---------------- fallback VALU label ----------------
__global__ __launch_bounds__(256) void label_kernel(
        const float* __restrict__ feat, const float* __restrict__ clsW, const float* __restrict__ clsb,
        const float* __restrict__ attW1, const float* __restrict__ attb1,
        const float* __restrict__ attW2, const float* __restrict__ attb2,
        const float* __restrict__ att_bias,
        float* __restrict__ node_att, float* __restrict__ probs_out) {
    __shared__ float Xs[32][132];
    __shared__ float Ws[64][132];
    int tid = threadIdx.x;
    int row0 = blockIdx.x * 32;
    stage_x_f32<132, 256>(&Xs[0][0], feat + (size_t)row0 * DD, tid);
    int to = tid & 31, tn = tid >> 5;
    int o0 = to * 4, n0 = tn * 4;
    float acc[4][4] = {};
    for (int half = 0; half < 2; ++half) {
        __syncthreads();
        #pragma unroll
        for (int rep = 0; rep < 8; ++rep) {
            int flat = rep * 256 + tid;
            int kk = flat >> 5, o4 = flat & 31;
            int o = o4 * 4;
            int c = o >> 6, h = o & 63;
            int k = half * 64 + kk;
            float4 q = *reinterpret_cast<const float4*>(attW1 + (size_t)(c * 128 + k) * 64 + h);
            *reinterpret_cast<float4*>(&Ws[kk][o]) = q;
        }
        __syncthreads();
        gemm16<132, 132>(acc, &Xs[0][0], &Ws[0][0], n0, o0, half * 64);
    }
    int c = o0 >> 6, h0 = o0 & 63;
    float b1j[4], w2j[4];
    #pragma unroll
    for (int j = 0; j < 4; ++j) {
        b1j[j] = attb1[c * 64 + h0 + j];
        w2j[j] = attW2[c * 64 + h0 + j];
    }
    float part[4];
    #pragma unroll
    for (int i = 0; i < 4; ++i) {
        float s = 0.f;
        #pragma unroll
        for (int j = 0; j < 4; ++j) {
            float hv = acc[i][j] + b1j[j];
            hv = hv > 0.f ? hv : 0.f;
            s += hv * w2j[j];
        }
        part[i] = s;
    }
    __syncthreads();
    float* red = &Ws[0][0];          // [32][33]
    float* Ssc = red + 32 * 33;      // [32][2]
    float* Lsc = Ssc + 64;           // [32][2]
    #pragma unroll
    for (int i = 0; i < 4; ++i) red[(n0 + i) * 33 + to] = part[i];
    __syncthreads();
    if (tid < 64) {
        int n = tid >> 1, cc = tid & 1;
        float l = 0.f;
        for (int k = 0; k < 128; k += 4) {
            float4 x = *reinterpret_cast<const float4*>(&Xs[n][k]);
            l += x.x * clsW[(k + 0) * 2 + cc];
            l += x.y * clsW[(k + 1) * 2 + cc];
            l += x.z * clsW[(k + 2) * 2 + cc];
            l += x.w * clsW[(k + 3) * 2 + cc];
        }
        Lsc[n * 2 + cc] = l + clsb[cc];
        float s = 0.f;
        for (int u = 0; u < 16; ++u) s += red[n * 33 + cc * 16 + u];
        s += attb2[cc];
        Ssc[n * 2 + cc] = 1.f / (1.f + expf(-s));
    }
    __syncthreads();
    if (tid < 32) {
        int n = tid;
        float l0 = Lsc[n * 2], l1 = Lsc[n * 2 + 1];
        float m = fmaxf(l0, l1);
        float e0 = expf(l0 - m), e1 = expf(l1 - m);
        float inv = 1.f / (e0 + e1);
        float p0 = e0 * inv, p1 = e1 * inv;
        float na = p0 * Ssc[n * 2] + p1 * Ssc[n * 2 + 1] + att_bias[0];
        int row = row0 + n;
        node_att[row] = na;
        probs_out[row * 2]     = p0;
        probs_out[row * 2 + 1] = p1;
    }
}

// ---------------- MFMA relgate (unchained via W12) + fused view-score ----
// EXACT R1 version (best measured: ~113 us warm).
__global__ __launch_bounds__(256, 3) void relgate_mfma_kernel(
        const u16* __restrict__ relWb, const float* __restrict__ relb,
        const u16* __restrict__ W12b, const float* __restrict__ rgbv,
        const float* __restrict__ gateb,
        const u16* __restrict__ vattW1p, const float* __restrict__ vattb1,
        const float* __restrict__ vattW2, const float* __restrict__ vattb2,
        u16* __restrict__ aggB, const float* __restrict__ wsum,
        float* __restrict__ vscores) {
    __shared__ u16 Wf[128][136];   // X, then relW full, then view_out
    __shared__ u16 Wt[128][72];    // W12 halves, then vatt weights
    int tid = threadIdx.x;
    int wv = tid >> 6, lane = tid & 63;
    int quad = lane >> 4, l15 = lane & 15;
    int v = blockIdx.y;
    int row0 = blockIdx.x * 128;
    const size_t vbase = (size_t)v * NN;

    // ---- stage X ----
    #pragma unroll
    for (int rep = 0; rep < 8; ++rep) {
        int flat = rep * 256 + tid;
        int n = flat >> 4, c8 = flat & 15;
        int gr = row0 + n; if (gr >= NN) gr = NN - 1;
        uint4 q = *reinterpret_cast<const uint4*>(aggB + (vbase + gr) * DD + c8 * 8);
        *reinterpret_cast<uint4*>(&Wf[n][c8 * 8]) = q;
    }
    __syncthreads();                                     // S1

    // ---- A fragments (whole K) into registers, shared by both GEMMs ----
    s8v af[2][2][2];
    loadFrags(af, Wf, wv, l15, quad);
    __syncthreads();                                     // S2

    // ---- stage relW FULL -> Wf ; W12 half0 -> Wt ----
    const u16* W1 = relWb + (size_t)v * DD * DD;
    const u16* W2 = W12b + (size_t)v * DD * DD;
    stageWf(Wf, W1, tid);
    stageWtHalf(Wt, W2, tid);
    __syncthreads();                                     // S3

    f4v acc1[2][8], acc2[2][8];
    #pragma unroll
    for (int rt = 0; rt < 2; ++rt)
        #pragma unroll
        for (int c = 0; c < 8; ++c) {
            acc1[rt][c] = f4v{0.f, 0.f, 0.f, 0.f};
            acc2[rt][c] = f4v{0.f, 0.f, 0.f, 0.f};
        }

    // acc1: full rel GEMM (64 MFMA/wave) + acc2 half0 (32 MFMA/wave)
    mfmaWfFull(acc1, af, Wf, l15, quad);
    mfmaWt8(acc2, af, 0, Wt, l15, quad);
    __syncthreads();                                     // S4

    // ---- stage W12 half1 -> Wt ----
    stageWtHalf(Wt, W2 + 64, tid);
    __syncthreads();                                     // S5
    mfmaWt8(acc2, af, 1, Wt, l15, quad);

    // ---- epilogue: agg, gate, view_out -> Wf (bf16) ----
    float wsn[2][4];
    #pragma unroll
    for (int rt = 0; rt < 2; ++rt)
        #pragma unroll
        for (int r = 0; r < 4; ++r) {
            int gr = row0 + wv * 32 + rt * 16 + quad * 4 + r;
            wsn[rt][r] = wsum[vbase + (gr < NN ? gr : NN - 1)];
        }
    float rb[8], rg2[8], gb[8];
    #pragma unroll
    for (int c = 0; c < 8; ++c) {
        int col = c * 16 + l15;
        rb[c]  = relb[v * DD + col];
        rg2[c] = rgbv[v * DD + col];
        gb[c]  = gateb[v * DD + col];
    }
    #pragma unroll
    for (int rt = 0; rt < 2; ++rt)
        #pragma unroll
        for (int c = 0; c < 8; ++c)
            #pragma unroll
            for (int r = 0; r < 4; ++r) {
                float a = acc1[rt][c][r] + wsn[rt][r] * rb[c];
                float g = fsigmoid(acc2[rt][c][r] + wsn[rt][r] * rg2[c] + gb[c]);
                Wf[wv * 32 + rt * 16 + quad * 4 + r][c * 16 + l15] = f2bf(g * a);
            }
    __syncthreads();                                     // S6

    // ---- stage vatt -> Wt, dump view_out -> aggB, a2 frags ----
    {
        const u16* Wv = vattW1p + (size_t)v * 64 * DD;
        #pragma unroll
        for (int rep = 0; rep < 4; ++rep) {
            int flat = rep * 256 + tid;
            int n = flat >> 4, c8 = flat & 15;
            uint4 q = *reinterpret_cast<const uint4*>(Wv + (size_t)n * DD + c8 * 8);
            int half = c8 >> 3;
            *reinterpret_cast<uint4*>(&Wt[half * 64 + n][(c8 & 7) * 8]) = q;
        }
    }
    s8v a2[2][2][2];
    loadFrags(a2, Wf, wv, l15, quad);
    #pragma unroll
    for (int rep = 0; rep < 8; ++rep) {
        int flat = rep * 256 + tid;
        int n = flat >> 4, c8 = flat & 15;
        int gr = row0 + n;
        if (gr < NN)
            *reinterpret_cast<uint4*>(aggB + (vbase + gr) * DD + c8 * 8) =
                *reinterpret_cast<const uint4*>(&Wf[n][c8 * 8]);
    }
    __syncthreads();                                     // S7

    // ---- fused view-score GEMM ----
    f4v acc3[2][4];
    #pragma unroll
    for (int rt = 0; rt < 2; ++rt)
        #pragma unroll
        for (int c = 0; c < 4; ++c)
            acc3[rt][c] = f4v{0.f, 0.f, 0.f, 0.f};
    #pragma unroll
    for (int h = 0; h < 2; ++h)
        #pragma unroll
        for (int t = 0; t < 2; ++t) {
            int kl = t * 32 + quad * 8;
            #pragma unroll
            for (int c = 0; c < 4; ++c) {
                s8v b = *reinterpret_cast<const s8v*>(&Wt[h * 64 + c * 16 + l15][kl]);
                acc3[0][c] = __builtin_amdgcn_mfma_f32_16x16x32_bf16(a2[h][t][0], b, acc3[0][c], 0, 0, 0);
                acc3[1][c] = __builtin_amdgcn_mfma_f32_16x16x32_bf16(a2[h][t][1], b, acc3[1][c], 0, 0, 0);
            }
        }
    float vb1[4], vw2[4];
    #pragma unroll
    for (int c = 0; c < 4; ++c) {
        int col = c * 16 + l15;
        vb1[c] = vattb1[col];
        vw2[c] = vattW2[col];
    }
    float vb2 = vattb2[0];
    #pragma unroll
    for (int rt = 0; rt < 2; ++rt)
        #pragma unroll
        for (int r = 0; r < 4; ++r) {
            float p = 0.f;
            #pragma unroll
            for (int c = 0; c < 4; ++c) {
                float hv = acc3[rt][c][r] + vb1[c];
                hv = hv > 0.f ? hv : 0.f;
                p += hv * vw2[c];
            }
            #pragma unroll
            for (int m = 1; m < 16; m <<= 1)
                p += __shfl_xor(p, m);
            int gr = row0 + wv * 32 + rt * 16 + quad * 4 + r;
            if (l15 == 0 && gr < NN)
                vscores[vbase + gr] = p + vb2;
        }
}

// ---------------- fallback VALU relgate ----------------
__global__ __launch_bounds__(256) void relgate_kernel(
        const float* __restrict__ relW, const float* __restrict__ relb,
        const float* __restrict__ gateW, const float* __restrict__ gateb,
        u16* __restrict__ aggB, const float* __restrict__ wsum) {
    __shared__ float Xs[32][128];
    __shared__ float Ws[64][132];
    int tid = threadIdx.x;
    int v = blockIdx.y;
    int row0 = blockIdx.x * 32;
    u16* base = aggB + ((size_t)v * NN + row0) * DD;
    stage_x_bf16<128, 256>(&Xs[0][0], base, tid);
    int to = tid & 31, tn = tid >> 5;
    int o0 = to * 4, n0 = tn * 4;
    float acc[4][4] = {};
    const float* W1 = relW + (size_t)v * DD * DD;
    for (int half = 0; half < 2; ++half) {
        __syncthreads();
        stage_w_f32<132, 256>(&Ws[0][0], W1 + half * 64 * DD, tid);
        __syncthreads();
        gemm16<128, 132>(acc, &Xs[0][0], &Ws[0][0], n0, o0, half * 64);
    }
    float wsn[4], rb[4];
    #pragma unroll
    for (int i = 0; i < 4; ++i) wsn[i] = wsum[v * NN + row0 + n0 + i];
    #pragma unroll
    for (int j = 0; j < 4; ++j) rb[j] = relb[v * DD + o0 + j];
    #pragma unroll
    for (int i = 0; i < 4; ++i)
        #pragma unroll
        for (int j = 0; j < 4; ++j) acc[i][j] += wsn[i] * rb[j];
    __syncthreads();
    #pragma unroll
    for (int i = 0; i < 4; ++i)
        *reinterpret_cast<float4*>(&Xs[n0 + i][o0]) = make_float4(acc[i][0], acc[i][1], acc[i][2], acc[i][3]);
    float acc2[4][4] = {};
    const float* W2 = gateW + (size_t)v * DD * DD;
    for (int half = 0; half < 2; ++half) {
        __syncthreads();
        stage_w_f32<132, 256>(&Ws[0][0], W2 + half * 64 * DD, tid);
        __syncthreads();
        gemm16<128, 132>(acc2, &Xs[0][0], &Ws[0][0], n0, o0, half * 64);
    }
    float gb[4];
    #pragma unroll
    for (int j = 0; j < 4; ++j) gb[j] = gateb[v * DD + o0 + j];
    #pragma unroll
    for (int i = 0; i < 4; ++i) {
        float g0 = 1.f / (1.f + expf(-(acc2[i][0] + gb[0])));
        float g1 = 1.f / (1.f + expf(-(acc2[i][1] + gb[1])));
        float g2 = 1.f / (1.f + expf(-(acc2[i][2] + gb[2])));
        float g3 = 1.f / (1.f + expf(-(acc2[i][3] + gb[3])));
        ushort4 r;
        r.x = f2bf(g0 * acc[i][0]); r.y = f2bf(g1 * acc[i][1]);
        r.z = f2bf(g2 * acc[i][2]); r.w = f2bf(g3 * acc[i][3]);
        *reinterpret_cast<ushort4*>(base + (size_t)(n0 + i) * DD + o0) = r;
    }
}

// ---------------- fallback view attention scores ----------------
__global__ __launch_bounds__(128) void vatt_kernel(
        const u16* __restrict__ aggB, const float* __restrict__ view_pref,
        const float* __restrict__ vattW1, const float* __restrict__ vattb1,
        const float* __restrict__ vattW2, const float* __restrict__ vattb2,
        float* __restrict__ vscores) {
    __shared__ float Xs[32][132];
    __shared__ float Ws[128][68];
    int tid = threadIdx.x;
    int v = blockIdx.y;
    int row0 = blockIdx.x * 32;
    const u16* base = aggB + ((size_t)v * NN + row0) * DD;
    #pragma unroll
    for (int rep = 0; rep < 4; ++rep) {
        int flat = rep * 128 + tid;
        int n = flat >> 4, c8 = flat & 15;
        uint4 q = *reinterpret_cast<const uint4*>(base + (size_t)n * DD + c8 * 8);
        float4 pa = *reinterpret_cast<const float4*>(view_pref + v * DD + c8 * 8);
        float4 pb = *reinterpret_cast<const float4*>(view_pref + v * DD + c8 * 8 + 4);
        float* d = &Xs[n][c8 * 8];
        d[0] = bf2f((u16)(q.x & 0xffffu)) * pa.x; d[1] = bf2f((u16)(q.x >> 16)) * pa.y;
        d[2] = bf2f((u16)(q.y & 0xffffu)) * pa.z; d[3] = bf2f((u16)(q.y >> 16)) * pa.w;
        d[4] = bf2f((u16)(q.z & 0xffffu)) * pb.x; d[5] = bf2f((u16)(q.z >> 16)) * pb.y;
        d[6] = bf2f((u16)(q.w & 0xffffu)) * pb.z; d[7] = bf2f((u16)(q.w >> 16)) * pb.w;
    }
    #pragma unroll
    for (int rep = 0; rep < 16; ++rep) {
        int flat = rep * 128 + tid;
        int k = flat >> 4, c4 = flat & 15;
        float4 q = *reinterpret_cast<const float4*>(vattW1 + k * 64 + c4 * 4);
        *reinterpret_cast<float4*>(&Ws[k][c4 * 4]) = q;
    }
    __syncthreads();
    int to = tid & 15, tn = tid >> 4;
    int o0 = to * 4, n0 = tn * 4;
    float acc[4][4] = {};
    gemm16<132, 68>(acc, &Xs[0][0], &Ws[0][0], n0, o0, 0);
    gemm16<132, 68>(acc, &Xs[0][0], &Ws[64][0], n0, o0, 64);
    float b1[4], w2[4];
    #pragma unroll
    for (int j = 0; j < 4; ++j) {
        b1[j] = vattb1[o0 + j];
        w2[j] = vattW2[o0 + j];
    }
    float part[4];
    #pragma unroll
    for (int i = 0; i < 4; ++i) {
        float s = 0.f;
        #pragma unroll
        for (int j = 0; j < 4; ++j) {
            float hv = acc[i][j] + b1[j];
            hv = hv > 0.f ? hv : 0.f;
            s += hv * w2[j];
        }
        part[i] = s;
    }
    __syncthreads();
    float* red = &Ws[0][0];   // [32][17]
    #pragma unroll
    for (int i = 0; i < 4; ++i) red[(n0 + i) * 17 + to] = part[i];
    __syncthreads();
    if (tid < 32) {
        float s = 0.f;
        for (int u = 0; u < 16; ++u) s += red[tid * 17 + u];
        vscores[(size_t)v * NN + row0 + tid] = s + vattb2[0];
    }
}

// ---------------- fallback combine ----------------
__global__ __launch_bounds__(256) void combine_kernel(
        u16* __restrict__ aggB, const float* __restrict__ vscores,
        const float* __restrict__ node_att) {
    int t = blockIdx.x * 256 + threadIdx.x;
    int n = t >> 5, c4 = t & 31;
    float s0 = vscores[n], s1 = vscores[NN + n], s2 = vscores[2 * NN + n];
    float m = fmaxf(s0, fmaxf(s1, s2));
    float e0 = expf(s0 - m), e1 = expf(s1 - m), e2 = expf(s2 - m);
    float inv = 1.f / (e0 + e1 + e2);
    float w0 = e0 * inv, w1 = e1 * inv, w2 = e2 * inv;
    float na = node_att[n];
    size_t off = (size_t)n * DD + c4 * 4;
    ushort4 q0 = *reinterpret_cast<const ushort4*>(aggB + off);
    ushort4 q1 = *reinterpret_cast<const ushort4*>(aggB + (size_t)NN * DD + off);
    ushort4 q2 = *reinterpret_cast<const ushort4*>(aggB + 2 * (size_t)NN * DD + off);
    ushort4 r;
    r.x = f2bf((bf2f(q0.x) * w0 + bf2f(q1.x) * w1 + bf2f(q2.x) * w2) * na);
    r.y = f2bf((bf2f(q0.y) * w0 + bf2f(q1.y) * w1 + bf2f(q2.y) * w2) * na);
    r.z = f2bf((bf2f(q0.z) * w0 + bf2f(q1.z) * w1 + bf2f(q2.z) * w2) * na);
    r.w = f2bf((bf2f(q0.w) * w0 + bf2f(q1.w) * w1 + bf2f(q2.w) * w2) * na);
    *reinterpret_cast<ushort4*>(aggB + off) = r;
}

// ---------------- MFMA final + fused LABEL + fused combine (R7 version) ----
__global__ __launch_bounds__(256, 3) void final_mfma_kernel(
        const u16* __restrict__ featB, const u16* __restrict__ aggB,
        const float* __restrict__ vsc,
        const u16* __restrict__ attW1B,
        const float* __restrict__ clsW, const float* __restrict__ clsb,
        const float* __restrict__ attb1, const float* __restrict__ attW2,
        const float* __restrict__ attb2, const float* __restrict__ att_bias,
        const u16* __restrict__ WsfB, const u16* __restrict__ featWB,
        const u16* __restrict__ fusWbB,
        const float* __restrict__ c1, const float* __restrict__ featb,
        const float* __restrict__ ln_g, const float* __restrict__ ln_b,
        float* __restrict__ outp, float* __restrict__ probs_out) {
    __shared__ u16 Wf[128][136];   // featB, then Wsf, then combined; cols 128..133 = rw
    __shared__ u16 Wt[128][72];
    __shared__ float naS[128];
    int tid = threadIdx.x;
    int wv = tid >> 6, lane = tid & 63;
    int quad = lane >> 4, l15 = lane & 15;
    int row0 = blockIdx.x * 128;

    // stage featB -> Wf ; attW1B half0 -> Wt
    #pragma unroll
    for (int rep = 0; rep < 8; ++rep) {
        int flat = rep * 256 + tid;
        int n = flat >> 4, c8 = flat & 15;
        int gr = row0 + n; if (gr >= NN) gr = NN - 1;
        uint4 q = *reinterpret_cast<const uint4*>(featB + (size_t)gr * DD + c8 * 8);
        *reinterpret_cast<uint4*>(&Wf[n][c8 * 8]) = q;
    }
    stageWtHalf(Wt, attW1B, tid);
    __syncthreads();                                     // S1

    s8v af[2][2][2];
    loadFrags(af, Wf, wv, l15, quad);

    // ---------- label attention phase (fused) ----------
    {
        f4v accL[2][8];
        #pragma unroll
        for (int rt = 0; rt < 2; ++rt)
            #pragma unroll
            for (int c = 0; c < 8; ++c)
                accL[rt][c] = f4v{0.f, 0.f, 0.f, 0.f};
        mfmaWt8(accL, af, 0, Wt, l15, quad);
        __syncthreads();                                 // S2
        stageWtHalf(Wt, attW1B + 64, tid);
        __syncthreads();                                 // S3
        mfmaWt8(accL, af, 1, Wt, l15, quad);

        float ab1[8], aw2[8];
        #pragma unroll
        for (int c = 0; c < 8; ++c) {
            int col = c * 16 + l15;
            ab1[c] = attb1[col];
            aw2[c] = attW2[col];
        }
        float cw0[8], cw1[8];
        #pragma unroll
        for (int j = 0; j < 8; ++j) {
            int k = l15 * 8 + j;
            cw0[j] = clsW[k * 2];
            cw1[j] = clsW[k * 2 + 1];
        }
        float cb0 = clsb[0], cb1 = clsb[1];
        float b20 = attb2[0], b21 = attb2[1];
        float abias = att_bias[0];

        #pragma unroll
        for (int rt = 0; rt < 2; ++rt)
            #pragma unroll
            for (int r = 0; r < 4; ++r) {
                int n = wv * 32 + rt * 16 + quad * 4 + r;
                int gr = row0 + n;
                float p0 = 0.f, p1 = 0.f;
                #pragma unroll
                for (int c = 0; c < 4; ++c) {
                    float hv = accL[rt][c][r] + ab1[c];
                    hv = hv > 0.f ? hv : 0.f;
                    p0 += hv * aw2[c];
                }
                #pragma unroll
                for (int c = 4; c < 8; ++c) {
                    float hv = accL[rt][c][r] + ab1[c];
                    hv = hv > 0.f ? hv : 0.f;
                    p1 += hv * aw2[c];
                }
                uint4 q = *reinterpret_cast<const uint4*>(&Wf[n][l15 * 8]);
                float f[8];
                f[0] = bf2f((u16)(q.x & 0xffffu)); f[1] = bf2f((u16)(q.x >> 16));
                f[2] = bf2f((u16)(q.y & 0xffffu)); f[3] = bf2f((u16)(q.y >> 16));
                f[4] = bf2f((u16)(q.z & 0xffffu)); f[5] = bf2f((u16)(q.z >> 16));
                f[6] = bf2f((u16)(q.w & 0xffffu)); f[7] = bf2f((u16)(q.w >> 16));
                float l0 = 0.f, l1 = 0.f;
                #pragma unroll
                for (int j = 0; j < 8; ++j) {
                    l0 = fmaf(f[j], cw0[j], l0);
                    l1 = fmaf(f[j], cw1[j], l1);
                }
                #pragma unroll
                for (int m = 1; m < 16; m <<= 1) {
                    p0 += __shfl_xor(p0, m);
                    p1 += __shfl_xor(p1, m);
                    l0 += __shfl_xor(l0, m);
                    l1 += __shfl_xor(l1, m);
                }
                if (l15 == 0) {
                    float s0 = 1.f / (1.f + expf(-(p0 + b20)));
                    float s1 = 1.f / (1.f + expf(-(p1 + b21)));
                    l0 += cb0; l1 += cb1;
                    float mm = fmaxf(l0, l1);
                    float e0 = expf(l0 - mm), e1 = expf(l1 - mm);
                    float inv = 1.f / (e0 + e1);
                    float q0 = e0 * inv, q1 = e1 * inv;
                    naS[n] = q0 * s0 + q1 * s1 + abias;
                    if (gr < NN) {
                        probs_out[gr * 2]     = q0;
                        probs_out[gr * 2 + 1] = q1;
                    }
                }
            }
    }
    __syncthreads();                                     // S4: naS visible

    // per-row combine weights (softmax over views * node_att) -> Wf row padding
    if (tid < 128) {
        int gr = row0 + tid; if (gr >= NN) gr = NN - 1;
        float s0 = vsc[gr], s1 = vsc[NN + gr], s2 = vsc[2 * NN + gr];
        float m = fmaxf(s0, fmaxf(s1, s2));
        const float L2E = 1.4426950408889634f;
        float e0 = fexp2((s0 - m) * L2E);
        float e1 = fexp2((s1 - m) * L2E);
        float e2 = fexp2((s2 - m) * L2E);
        float na = naS[tid] * frcp(e0 + e1 + e2);
        float* rwp = reinterpret_cast<float*>(&Wf[tid][128]);
        rwp[0] = e0 * na;
        rwp[1] = e1 * na;
        rwp[2] = e2 * na;
    }

    // stage WsfB FULL -> Wf (cols 0..127 only; padding preserved) ; featWB h0 -> Wt
    stageWf(Wf, WsfB, tid);
    stageWtHalf(Wt, featWB, tid);
    __syncthreads();                                     // S5

    f4v acc1[2][8], acc2[2][8];
    #pragma unroll
    for (int rt = 0; rt < 2; ++rt)
        #pragma unroll
        for (int c = 0; c < 8; ++c) {
            acc1[rt][c] = f4v{0.f, 0.f, 0.f, 0.f};
            acc2[rt][c] = f4v{0.f, 0.f, 0.f, 0.f};
        }

    mfmaWfFull(acc1, af, Wf, l15, quad);      // X @ Wsf
    mfmaWt8(acc2, af, 0, Wt, l15, quad);      // X @ featW (h0)
    __syncthreads();                                     // S6
    stageWtHalf(Wt, featWB + 64, tid);
    __syncthreads();                                     // S7
    mfmaWt8(acc2, af, 1, Wt, l15, quad);      // X @ featW (h1)

    // fused combine: Wf cols 0..127 = bf16( rw0*view0 + rw1*view1 + rw2*view2 )
    #pragma unroll
    for (int rep = 0; rep < 8; ++rep) {
        int flat = rep * 256 + tid;
        int n = flat >> 4, c8 = flat & 15;
        int gr = row0 + n; if (gr >= NN) gr = NN - 1;
        size_t off = (size_t)gr * DD + c8 * 8;
        uint4 q0 = *reinterpret_cast<const uint4*>(aggB + off);
        uint4 q1 = *reinterpret_cast<const uint4*>(aggB + (size_t)NN * DD + off);
        uint4 q2 = *reinterpret_cast<const uint4*>(aggB + 2 * (size_t)NN * DD + off);
        const float* rwp = reinterpret_cast<const float*>(&Wf[n][128]);
        float w0 = rwp[0], w1 = rwp[1], w2 = rwp[2];
        u32 o[4];
        const u32* a = &q0.x; const u32* b = &q1.x; const u32* c = &q2.x;
        #pragma unroll
        for (int j = 0; j < 4; ++j) {
            float lo = bf2f((u16)(a[j] & 0xffffu)) * w0 + bf2f((u16)(b[j] & 0xffffu)) * w1
                     + bf2f((u16)(c[j] & 0xffffu)) * w2;
            float hi = bf2f((u16)(a[j] >> 16)) * w0 + bf2f((u16)(b[j] >> 16)) * w1
                     + bf2f((u16)(c[j] >> 16)) * w2;
            o[j] = (u32)f2bf(lo) | ((u32)f2bf(hi) << 16);
        }
        uint4 r; r.x = o[0]; r.y = o[1]; r.z = o[2]; r.w = o[3];
        *reinterpret_cast<uint4*>(&Wf[n][c8 * 8]) = r;
    }
    __syncthreads();                                     // S8

    // fus GEMM half0
    stageWtHalf(Wt, fusWbB, tid);
    __syncthreads();                                     // S9
    #pragma unroll
    for (int t = 0; t < 2; ++t) {
        int kl = t * 32 + quad * 8;
        s8v a0 = *reinterpret_cast<const s8v*>(&Wf[wv * 32 + l15][kl]);
        s8v a1 = *reinterpret_cast<const s8v*>(&Wf[wv * 32 + 16 + l15][kl]);
        #pragma unroll
        for (int c = 0; c < 8; ++c) {
            s8v b = *reinterpret_cast<const s8v*>(&Wt[c * 16 + l15][kl]);
            acc1[0][c] = __builtin_amdgcn_mfma_f32_16x16x32_bf16(a0, b, acc1[0][c], 0, 0, 0);
            acc1[1][c] = __builtin_amdgcn_mfma_f32_16x16x32_bf16(a1, b, acc1[1][c], 0, 0, 0);
        }
    }
    __syncthreads();                                     // S10
    stageWtHalf(Wt, fusWbB + 64, tid);
    __syncthreads();                                     // S11
    #pragma unroll
    for (int t = 0; t < 2; ++t) {
        int kl = t * 32 + quad * 8;
        s8v a0 = *reinterpret_cast<const s8v*>(&Wf[wv * 32 + l15][64 + kl]);
        s8v a1 = *reinterpret_cast<const s8v*>(&Wf[wv * 32 + 16 + l15][64 + kl]);
        #pragma unroll
        for (int c = 0; c < 8; ++c) {
            s8v b = *reinterpret_cast<const s8v*>(&Wt[c * 16 + l15][kl]);
            acc1[0][c] = __builtin_amdgcn_mfma_f32_16x16x32_bf16(a0, b, acc1[0][c], 0, 0, 0);
            acc1[1][c] = __builtin_amdgcn_mfma_f32_16x16x32_bf16(a1, b, acc1[1][c], 0, 0, 0);
        }
    }

    float c1j[8], fbj[8], gj[8], bj[8];
    #pragma unroll
    for (int c = 0; c < 8; ++c) {
        int col = c * 16 + l15;
        c1j[c] = c1[col];
        fbj[c] = featb[col];
        gj[c]  = ln_g[col];
        bj[c]  = ln_b[col];
    }
    #pragma unroll
    for (int rt = 0; rt < 2; ++rt)
        #pragma unroll
        for (int c = 0; c < 8; ++c)
            #pragma unroll
            for (int r = 0; r < 4; ++r) {
                float f = acc1[rt][c][r] + c1j[c];
                f = f > 0.f ? f : 0.f;
                acc1[rt][c][r] = f + acc2[rt][c][r] + fbj[c];
            }
    #pragma unroll
    for (int rt = 0; rt < 2; ++rt)
        #pragma unroll
        for (int r = 0; r < 4; ++r) {
            float s = 0.f, q = 0.f;
            #pragma unroll
            for (int c = 0; c < 8; ++c) {
                float x = acc1[rt][c][r];
                s += x; q += x * x;
            }
            #pragma unroll
            for (int m = 1; m < 16; m <<= 1) {
                s += __shfl_xor(s, m);
                q += __shfl_xor(q, m);
            }
            float mu = s * (1.f / 128.f);
            float var = q * (1.f / 128.f) - mu * mu;
            float rs = rsqrtf(var + 1e-5f);
            int gr = row0 + wv * 32 + rt * 16 + quad * 4 + r;
            if (gr < NN) {
                #pragma unroll
                for (int c = 0; c < 8; ++c)
                    outp[(size_t)gr * DD + c * 16 + l15] =
                        (acc1[rt][c][r] - mu) * rs * gj[c] + bj[c];
            }
        }
}

// ---------------- fallback helper kernels (featconv / wpreps) ----------------
__global__ __launch_bounds__(256) void featconv_kernel(
        const float* __restrict__ feat, u16* __restrict__ featB) {
    int t = blockIdx.x * 256 + threadIdx.x;
    float4 q = *reinterpret_cast<const float4*>(feat + (size_t)t * 4);
    ushort4 r;
    r.x = f2bf(q.x); r.y = f2bf(q.y); r.z = f2bf(q.z); r.w = f2bf(q.w);
    *reinterpret_cast<ushort4*>(featB + (size_t)t * 4) = r;
}

// ---------------- fallback VALU final ----------------
__global__ __launch_bounds__(256) void final_kernel(
        const float* __restrict__ feat, const u16* __restrict__ weightedB,
        const float* __restrict__ Wsf, const float* __restrict__ c1,
        const float* __restrict__ fusW, const float* __restrict__ featW,
        const float* __restrict__ featb, const float* __restrict__ ln_g,
        const float* __restrict__ ln_b, float* __restrict__ outp) {
    __shared__ float Xs[32][128];
    __shared__ float Ws[64][128];
    int tid = threadIdx.x;
    int row0 = blockIdx.x * 32;
    stage_x_f32<128, 256>(&Xs[0][0], feat + (size_t)row0 * DD, tid);
    int to = tid & 31, tn = tid >> 5;
    int o0 = to * 4, n0 = tn * 4;
    float acc1[4][4] = {}, acc2[4][4] = {};
    for (int half = 0; half < 2; ++half) {
        __syncthreads();
        stage_w_f32<128, 256>(&Ws[0][0], Wsf + half * 64 * 128, tid);
        __syncthreads();
        gemm16<128, 128>(acc1, &Xs[0][0], &Ws[0][0], n0, o0, half * 64);
    }
    for (int half = 0; half < 2; ++half) {
        __syncthreads();
        stage_w_f32<128, 256>(&Ws[0][0], featW + half * 64 * 128, tid);
        __syncthreads();
        gemm16<128, 128>(acc2, &Xs[0][0], &Ws[0][0], n0, o0, half * 64);
    }
    __syncthreads();
    stage_x_bf16<128, 256>(&Xs[0][0], weightedB + (size_t)row0 * DD, tid);
    for (int half = 0; half < 2; ++half) {
        __syncthreads();
        stage_w_f32<128, 256>(&Ws[0][0], fusW + (size_t)(128 + half * 64) * 128, tid);
        __syncthreads();
        gemm16<128, 128>(acc1, &Xs[0][0], &Ws[0][0], n0, o0, half * 64);
    }
    float c1j[4], fbj[4], gj[4], bj[4];
    #pragma unroll
    for (int j = 0; j < 4; ++j) {
        c1j[j] = c1[o0 + j];
        fbj[j] = featb[o0 + j];
        gj[j]  = ln_g[o0 + j];
        bj[j]  = ln_b[o0 + j];
    }
    float val[4][4];
    #pragma unroll
    for (int i = 0; i < 4; ++i)
        #pragma unroll
        for (int j = 0; j < 4; ++j) {
            float f = acc1[i][j] + c1j[j];
            f = f > 0.f ? f : 0.f;
            val[i][j] = f + acc2[i][j] + fbj[j];
        }
    __syncthreads();
    float* red_s = &Ws[0][0];
    float* red_q = red_s + 32 * 33;
    float* mus   = red_q + 32 * 33;
    float* rss   = mus + 32;
    #pragma unroll
    for (int i = 0; i < 4; ++i) {
        float s = 0.f, q = 0.f;
        #pragma unroll
        for (int j = 0; j < 4; ++j) { s += val[i][j]; q += val[i][j] * val[i][j]; }
        red_s[(n0 + i) * 33 + to] = s;
        red_q[(n0 + i) * 33 + to] = q;
    }
    __syncthreads();
    if (tid < 32) {
        float s = 0.f, q = 0.f;
        for (int u = 0; u < 32; ++u) { s += red_s[tid * 33 + u]; q += red_q[tid * 33 + u]; }
        float mu = s / 128.f;
        float var = q / 128.f - mu * mu;
        mus[tid] = mu;
        rss[tid] = rsqrtf(var + 1e-5f);
    }
    __syncthreads();
    #pragma unroll
    for (int i = 0; i < 4; ++i) {
        float mu = mus[n0 + i], rs = rss[n0 + i];
        float4 o;
        o.x = (val[i][0] - mu) * rs * gj[0] + bj[0];
        o.y = (val[i][1] - mu) * rs * gj[1] + bj[1];
        o.z = (val[i][2] - mu) * rs * gj[2] + bj[2];
        o.w = (val[i][3] - mu) * rs * gj[3] + bj[3];
        *reinterpret_cast<float4*>(outp + (size_t)(row0 + n0 + i) * DD + o0) = o;
    }
}

extern "C" void kernel_launch(void* const* d_in, const int* in_sizes, int n_in,
                              void* d_out, int out_size, void* d_ws, size_t ws_size,
                              hipStream_t stream) {
    (void)in_sizes; (void)n_in; (void)out_size;
    const float* feat      = (const float*)d_in[0];
    const int*   esrc      = (const int*)d_in[1];
    const int*   edst      = (const int*)d_in[2];
    const float* ew        = (const float*)d_in[3];
    const float* clsW      = (const float*)d_in[4];
    const float* clsb      = (const float*)d_in[5];
    const float* attW1     = (const float*)d_in[6];
    const float* attb1     = (const float*)d_in[7];
    const float* attW2     = (const float*)d_in[8];
    const float* attb2     = (const float*)d_in[9];
    const float* att_bias  = (const float*)d_in[10];
    const float* relW      = (const float*)d_in[11];
    const float* relb      = (const float*)d_in[12];
    const float* gateW     = (const float*)d_in[13];
    const float* gateb     = (const float*)d_in[14];
    const float* view_pref = (const float*)d_in[15];
    const float* vattW1    = (const float*)d_in[16];
    const float* vattb1    = (const float*)d_in[17];
    const float* vattW2    = (const float*)d_in[18];
    const float* vattb2    = (const float*)d_in[19];
    const float* selfW     = (const float*)d_in[20];
    const float* selfb     = (const float*)d_in[21];
    const float* featW     = (const float*)d_in[22];
    const float* featb     = (const float*)d_in[23];
    const float* fusW      = (const float*)d_in[24];
    const float* fusb      = (const float*)d_in[25];
    const float* ln_g      = (const float*)d_in[26];
    const float* ln_b      = (const float*)d_in[27];

    // workspace layout (~120 MiB):
    u16*   aggB = (u16*)d_ws;                                   // [3][N][128] bf16
    float* wsum = (float*)(aggB + (size_t)VV * NN * DD);        // [3][N]
    float* natt = wsum + (size_t)VV * NN;                       // [N] (fallback only)
    float* vsc  = natt + NN;                                    // [3][N]
    float* Wsf  = vsc + (size_t)VV * NN;                        // [128][128] (fallback only)
    float* c1   = Wsf + DD * DD;                                // [128]
    u16* relWb  = (u16*)(c1 + DD);                              // [3][128][128] bf16
    u16* gateWb = relWb + (size_t)VV * DD * DD;                 // [3][128][128] bf16
    u16* WsfB   = gateWb + (size_t)VV * DD * DD;                // [128][128] bf16
    u16* featWB = WsfB + DD * DD;                               // [128][128] bf16
    u16* fusWbB = featWB + DD * DD;                             // [128][128] bf16
    u16* attW1B = fusWbB + DD * DD;                             // [128][128] bf16
    u16* vattW1p = attW1B + DD * DD;                            // [3][64][128] bf16
    u16* W12b   = vattW1p + (size_t)VV * 64 * DD;               // [3][128][128] bf16
    float* rgb  = (float*)(W12b + (size_t)VV * DD * DD);        // [3][128]
    int*   C    = (int*)(rgb + VV * DD);                        // [3N]
    int*   bs   = C + (size_t)TOT;                              // [NB]
    int2*  bsw  = (int2*)(bs + NB + 1);                         // [3E] packed (src,w)
    u16* featB  = (u16*)(bsw + (size_t)VV * EE);                // [N][128] bf16
    size_t needed = (size_t)((char*)(featB + (size_t)NN * DD) - (char*)d_ws);

    float* outp  = (float*)d_out;
    float* probs = outp + (size_t)NN * DD;

    if (ws_size >= needed) {
        hipMemsetAsync(C, 0, (size_t)TOT * sizeof(int), stream);
        prep_all_kernel<<<PA_GRID, 256, 0, stream>>>(
            feat, featB, relW, gateW, relWb, gateWb,
            selfW, selfb, fusW, fusb, WsfB, c1,
            featW, featWB, fusWbB, attW1, attW1B,
            vattW1, view_pref, vattW1p, relb, W12b, rgb,
            edst, C);
        scanA_kernel<<<NB, 256, 0, stream>>>(C, bs);
        scanB_kernel<<<1, 1024, 0, stream>>>(bs);
        scanC_kernel<<<NB, 256, 0, stream>>>(C, bs);
        fill_kernel<<<(VV * EE + 255) / 256, 256, 0, stream>>>(esrc, edst, ew, C, bsw);
        gather_kernel<<<(VV * NN) / 4, 256, 0, stream>>>(featB, C, bsw, aggB, wsum);
        relgate_mfma_kernel<<<dim3(RGB, 3), 256, 0, stream>>>(relWb, relb, W12b, rgb, gateb,
                                                              vattW1p, vattb1, vattW2, vattb2,
                                                              aggB, wsum, vsc);
        final_mfma_kernel<<<RGB, 256, 0, stream>>>(featB, aggB, vsc,
                                                   attW1B, clsW, clsb, attb1, attW2,
                                                   attb2, att_bias,
                                                   WsfB, featWB, fusWbB,
                                                   c1, featb, ln_g, ln_b, outp, probs);
    } else {
        prep_kernel<<<129, 128, 0, stream>>>(selfW, selfb, fusW, fusb, Wsf, c1);
        label_kernel<<<3125, 256, 0, stream>>>(feat, clsW, clsb, attW1, attb1, attW2, attb2,
                                               att_bias, natt, probs);
        hipMemsetAsync(d_ws, 0,
                       (size_t)VV * NN * DD * sizeof(u16) + (size_t)VV * NN * sizeof(float),
                       stream);
        scatter_kernel<<<187500, 256, 0, stream>>>(esrc, edst, ew, feat, aggB, wsum);
        relgate_kernel<<<dim3(3125, 3), 256, 0, stream>>>(relW, relb, gateW, gateb, aggB, wsum);
        vatt_kernel<<<dim3(3125, 3), 128, 0, stream>>>(aggB, view_pref, vattW1, vattb1,
                                                       vattW2, vattb2, vsc);
        combine_kernel<<<12500, 256, 0, stream>>>(aggB, vsc, natt);
        final_kernel<<<3125, 256, 0, stream>>>(feat, aggB, Wsf, c1, fusW, featW, featb,
                                               ln_g, ln_b, outp);
    }
}

// Round 9
// 579.427 us; speedup vs baseline: 1.6263x; 1.1019x over previous
//
#include <hip/hip_runtime.h>
#include <hip/hip_bf16.h>

#define NN 100000
#define DD 128
#define VV 3
#define EE 500000
#define TOT (VV * NN)                 // 300000 rows
#define NB ((TOT + 255) / 256)        // 1172 scan blocks
#define RGB ((NN + 127) / 128)        // 782 mfma blocks

typedef unsigned short u16;
typedef unsigned int u32;
typedef short s8v __attribute__((ext_vector_type(8)));   // 8 bf16 (4 VGPRs)
typedef float f4v __attribute__((ext_vector_type(4)));   // MFMA accumulator

__device__ __forceinline__ float bf2f(u16 u) {
    return __uint_as_float(((u32)u) << 16);
}
__device__ __forceinline__ u16 f2bf(float f) {
    u32 x = __float_as_uint(f);
    u32 r = (x + 0x7fffu + ((x >> 16) & 1u)) >> 16;
    return (u16)r;
}

__device__ __forceinline__ float fexp2(float x) {
#if __has_builtin(__builtin_amdgcn_exp2f)
    return __builtin_amdgcn_exp2f(x);
#else
    return exp2f(x);
#endif
}
__device__ __forceinline__ float frcp(float x) {
#if __has_builtin(__builtin_amdgcn_rcpf)
    return __builtin_amdgcn_rcpf(x);
#else
    return 1.f / x;
#endif
}
__device__ __forceinline__ float fsigmoid(float x) {
    return frcp(1.f + fexp2(-1.4426950408889634f * x));
}

// packed bf16 atomic add (fallback path only)
__device__ __forceinline__ void atomAddBf16x2(u16* addr, float f0, float f1) {
#if __has_builtin(__builtin_amdgcn_global_atomic_fadd_v2bf16)
    typedef short v2s __attribute__((ext_vector_type(2)));
    typedef v2s __attribute__((address_space(1)))* v2s_gp;
    v2s v;
    v.x = (short)f2bf(f0);
    v.y = (short)f2bf(f1);
    __builtin_amdgcn_global_atomic_fadd_v2bf16((v2s_gp)(void*)addr, v);
#else
    u32* p = (u32*)addr;
    u32 old = *(volatile u32*)p;
    while (true) {
        float lo = bf2f((u16)(old & 0xffffu)) + f0;
        float hi = bf2f((u16)(old >> 16)) + f1;
        u32 nv = (u32)f2bf(lo) | ((u32)f2bf(hi) << 16);
        u32 prev = atomicCAS(p, old, nv);
        if (prev == old) break;
        old = prev;
    }
#endif
}

// ---- generic VALU GEMM accumulate (fallback path) ----
template<int XSTR, int WSTR>
__device__ __forceinline__ void gemm16(float acc[4][4], const float* Xs,
                                       const float* Ws, int n0, int o0, int kbase) {
    #pragma unroll 4
    for (int kk = 0; kk < 64; kk += 4) {
        float4 w0 = *reinterpret_cast<const float4*>(Ws + (kk + 0) * WSTR + o0);
        float4 w1 = *reinterpret_cast<const float4*>(Ws + (kk + 1) * WSTR + o0);
        float4 w2 = *reinterpret_cast<const float4*>(Ws + (kk + 2) * WSTR + o0);
        float4 w3 = *reinterpret_cast<const float4*>(Ws + (kk + 3) * WSTR + o0);
        #pragma unroll
        for (int i = 0; i < 4; ++i) {
            float4 x = *reinterpret_cast<const float4*>(Xs + (n0 + i) * XSTR + kbase + kk);
            acc[i][0] = fmaf(x.x, w0.x, fmaf(x.y, w1.x, fmaf(x.z, w2.x, fmaf(x.w, w3.x, acc[i][0]))));
            acc[i][1] = fmaf(x.x, w0.y, fmaf(x.y, w1.y, fmaf(x.z, w2.y, fmaf(x.w, w3.y, acc[i][1]))));
            acc[i][2] = fmaf(x.x, w0.z, fmaf(x.y, w1.z, fmaf(x.z, w2.z, fmaf(x.w, w3.z, acc[i][2]))));
            acc[i][3] = fmaf(x.x, w0.w, fmaf(x.y, w1.w, fmaf(x.z, w2.w, fmaf(x.w, w3.w, acc[i][3]))));
        }
    }
}

template<int WSTR, int NT>
__device__ __forceinline__ void stage_w_f32(float* Ws, const float* __restrict__ src, int tid) {
    #pragma unroll
    for (int rep = 0; rep < 2048 / NT; ++rep) {
        int flat = rep * NT + tid;
        int kk = flat >> 5;
        int c4 = flat & 31;
        float4 q = *reinterpret_cast<const float4*>(src + kk * 128 + c4 * 4);
        *reinterpret_cast<float4*>(Ws + kk * WSTR + c4 * 4) = q;
    }
}

template<int XSTR, int NT>
__device__ __forceinline__ void stage_x_f32(float* Xs, const float* __restrict__ src, int tid) {
    #pragma unroll
    for (int rep = 0; rep < 1024 / NT; ++rep) {
        int flat = rep * NT + tid;
        int n = flat >> 5;
        int c4 = flat & 31;
        float4 q = *reinterpret_cast<const float4*>(src + (size_t)n * 128 + c4 * 4);
        *reinterpret_cast<float4*>(Xs + n * XSTR + c4 * 4) = q;
    }
}

template<int XSTR, int NT>
__device__ __forceinline__ void stage_x_bf16(float* Xs, const u16* __restrict__ src, int tid) {
    #pragma unroll
    for (int rep = 0; rep < 512 / NT; ++rep) {
        int flat = rep * NT + tid;
        int n = flat >> 4;
        int c8 = flat & 15;
        uint4 q = *reinterpret_cast<const uint4*>(src + (size_t)n * 128 + c8 * 8);
        float* d = Xs + n * XSTR + c8 * 8;
        d[0] = bf2f((u16)(q.x & 0xffffu)); d[1] = bf2f((u16)(q.x >> 16));
        d[2] = bf2f((u16)(q.y & 0xffffu)); d[3] = bf2f((u16)(q.y >> 16));
        d[4] = bf2f((u16)(q.z & 0xffffu)); d[5] = bf2f((u16)(q.z >> 16));
        d[6] = bf2f((u16)(q.w & 0xffffu)); d[7] = bf2f((u16)(q.w >> 16));
    }
}

// ======== MFMA staging / fragment helpers (256 threads) ========

// full 128x128 bf16 weight tile -> Wf (cols 0..127; row padding untouched)
__device__ __forceinline__ void stageWf(u16 (*Wf)[136], const u16* __restrict__ src, int tid) {
    #pragma unroll
    for (int rep = 0; rep < 8; ++rep) {
        int flat = rep * 256 + tid;
        int n = flat >> 4, c8 = flat & 15;
        *reinterpret_cast<uint4*>(&Wf[n][c8 * 8]) =
            *reinterpret_cast<const uint4*>(src + (size_t)n * DD + c8 * 8);
    }
}

// 128x64 half-k weight tile -> Wt (src already offset by h*64)
__device__ __forceinline__ void stageWtHalf(u16 (*Wt)[72], const u16* __restrict__ src, int tid) {
    #pragma unroll
    for (int rep = 0; rep < 4; ++rep) {
        int flat = rep * 256 + tid;
        int n = flat >> 3, c8 = flat & 7;
        *reinterpret_cast<uint4*>(&Wt[n][c8 * 8]) =
            *reinterpret_cast<const uint4*>(src + (size_t)n * DD + c8 * 8);
    }
}

// 128-row X tile (row-clamped) -> Wf
__device__ __forceinline__ void stageX(u16 (*Wf)[136], const u16* __restrict__ src,
                                       int row0, int tid) {
    #pragma unroll
    for (int rep = 0; rep < 8; ++rep) {
        int flat = rep * 256 + tid;
        int n = flat >> 4, c8 = flat & 15;
        int gr = row0 + n; if (gr >= NN) gr = NN - 1;
        *reinterpret_cast<uint4*>(&Wf[n][c8 * 8]) =
            *reinterpret_cast<const uint4*>(src + (size_t)gr * DD + c8 * 8);
    }
}

// A-fragments (whole K=128) for this wave's 32 rows
__device__ __forceinline__ void loadFrags(s8v af[2][2][2], u16 (*Wf)[136],
                                          int wv, int l15, int quad) {
    #pragma unroll
    for (int h = 0; h < 2; ++h)
        #pragma unroll
        for (int t = 0; t < 2; ++t) {
            int kl = h * 64 + t * 32 + quad * 8;
            af[h][t][0] = *reinterpret_cast<const s8v*>(&Wf[wv * 32 + l15][kl]);
            af[h][t][1] = *reinterpret_cast<const s8v*>(&Wf[wv * 32 + 16 + l15][kl]);
        }
}

// acc += af[h] (x) Wt  (half-k, 8 col-tiles, 32 MFMA)
__device__ __forceinline__ void mfmaWt8(f4v acc[2][8], const s8v af[2][2][2], int h,
                                        u16 (*Wt)[72], int l15, int quad) {
    #pragma unroll
    for (int t = 0; t < 2; ++t) {
        int kl = t * 32 + quad * 8;
        #pragma unroll
        for (int c = 0; c < 8; ++c) {
            s8v b = *reinterpret_cast<const s8v*>(&Wt[c * 16 + l15][kl]);
            acc[0][c] = __builtin_amdgcn_mfma_f32_16x16x32_bf16(af[h][t][0], b, acc[0][c], 0, 0, 0);
            acc[1][c] = __builtin_amdgcn_mfma_f32_16x16x32_bf16(af[h][t][1], b, acc[1][c], 0, 0, 0);
        }
    }
}

// acc += af (x) Wf  (full-k, 8 col-tiles, 64 MFMA)
__device__ __forceinline__ void mfmaWfFull(f4v acc[2][8], const s8v af[2][2][2],
                                           u16 (*Wf)[136], int l15, int quad) {
    #pragma unroll
    for (int h = 0; h < 2; ++h)
        #pragma unroll
        for (int t = 0; t < 2; ++t) {
            int kl = h * 64 + t * 32 + quad * 8;
            #pragma unroll
            for (int c = 0; c < 8; ++c) {
                s8v b = *reinterpret_cast<const s8v*>(&Wf[c * 16 + l15][kl]);
                acc[0][c] = __builtin_amdgcn_mfma_f32_16x16x32_bf16(af[h][t][0], b, acc[0][c], 0, 0, 0);
                acc[1][c] = __builtin_amdgcn_mfma_f32_16x16x32_bf16(af[h][t][1], b, acc[1][c], 0, 0, 0);
            }
        }
}

// ================= mega prep kernel (main path) =================
// One dispatch covering: featconv, relW/gateW transpose, WsfB(direct GEMM),
// featWB/fusWbB, c1, attW1B, vattW1p, W12b/rgb, and count(+rank). Segments
// are independent (disjoint outputs); count's atomic latency hides under the
// streaming/compute segments. rank[t] = edge's slot within its dst bucket
// (the atomicAdd return value) -> fill needs NO atomics.
#define PAE0 3200000                      // featconv (float4 chunks)
#define PAE1 (PAE0 + 49152)               // relWb/gateWb transpose
#define PAE2 (PAE1 + 16384)               // WsfB direct
#define PAE3 (PAE2 + 16384)               // featWB + fusWbB
#define PAE4 (PAE3 + 128)                 // c1
#define PAE5 (PAE4 + 16384)               // attW1B
#define PAE6 (PAE5 + 24576)               // vattW1p
#define PAE7 (PAE6 + 49152)               // W12b
#define PAE8 (PAE7 + 384)                 // rgb
#define PAE9 (PAE8 + (VV * EE))           // count + rank
#define PA_GRID ((PAE9 + 255) / 256)

__global__ __launch_bounds__(256) void prep_all_kernel(
        const float* __restrict__ feat, u16* __restrict__ featB,
        const float* __restrict__ relW, const float* __restrict__ gateW,
        u16* __restrict__ relWb, u16* __restrict__ gateWb,
        const float* __restrict__ selfW, const float* __restrict__ selfb,
        const float* __restrict__ fusW, const float* __restrict__ fusb,
        u16* __restrict__ WsfB, float* __restrict__ c1,
        const float* __restrict__ featW, u16* __restrict__ featWB,
        u16* __restrict__ fusWbB,
        const float* __restrict__ attW1, u16* __restrict__ attW1B,
        const float* __restrict__ vattW1, const float* __restrict__ view_pref,
        u16* __restrict__ vattW1p,
        const float* __restrict__ relb, u16* __restrict__ W12b,
        float* __restrict__ rgb,
        const int* __restrict__ edst, int* __restrict__ C,
        int* __restrict__ rankA) {
    int id = blockIdx.x * 256 + threadIdx.x;
    if (id < PAE0) {
        // featconv: feat fp32 -> bf16
        float4 q = *reinterpret_cast<const float4*>(feat + (size_t)id * 4);
        ushort4 r;
        r.x = f2bf(q.x); r.y = f2bf(q.y); r.z = f2bf(q.z); r.w = f2bf(q.w);
        *reinterpret_cast<ushort4*>(featB + (size_t)id * 4) = r;
    } else if (id < PAE1) {
        int t = id - PAE0;
        int v = t >> 14, rem = t & 16383, n = rem >> 7, k = rem & 127;
        size_t o = ((size_t)v * 128 + n) * 128 + k;
        size_t i = ((size_t)v * 128 + k) * 128 + n;
        relWb[o]  = f2bf(relW[i]);
        gateWb[o] = f2bf(gateW[i]);
    } else if (id < PAE2) {
        // WsfB[n][k] = bf16( (selfW @ fusW_top)[k][n] )  (direct dot)
        int t = id - PAE1;
        int n = t >> 7, k = t & 127;
        float acc = 0.f;
        for (int m = 0; m < 128; ++m)
            acc += selfW[k * 128 + m] * fusW[m * 128 + n];
        WsfB[n * 128 + k] = f2bf(acc);
    } else if (id < PAE3) {
        int t = id - PAE2;
        int n = t >> 7, k = t & 127;
        featWB[n * 128 + k] = f2bf(featW[k * 128 + n]);
        fusWbB[n * 128 + k] = f2bf(fusW[(size_t)(128 + k) * 128 + n]);
    } else if (id < PAE4) {
        int o = id - PAE3;
        float acc = 0.f;
        for (int m = 0; m < 128; ++m)
            acc += selfb[m] * fusW[m * 128 + o];
        c1[o] = acc + fusb[o];
    } else if (id < PAE5) {
        int t = id - PAE4;
        int o = t >> 7, k = t & 127;
        int c = o >> 6, h = o & 63;
        attW1B[o * 128 + k] = f2bf(attW1[((size_t)c * 128 + k) * 64 + h]);
    } else if (id < PAE6) {
        int t = id - PAE5;
        int v = t / 8192, rem = t - v * 8192, h = rem >> 7, k = rem & 127;
        vattW1p[((size_t)v * 64 + h) * 128 + k] =
            f2bf(view_pref[v * 128 + k] * vattW1[k * 64 + h]);
    } else if (id < PAE7) {
        int t = id - PAE6;
        int v = t >> 14, rem = t & 16383, d = rem >> 7, p = rem & 127;
        const float* gW = gateW + (size_t)v * 128 * 128;
        const float* rW = relW + ((size_t)v * 128 + d) * 128;
        float acc = 0.f;
        for (int o = 0; o < 128; ++o) acc += rW[o] * gW[o * 128 + p];
        W12b[((size_t)v * 128 + p) * 128 + d] = f2bf(acc);
    } else if (id < PAE8) {
        int t = id - PAE7;
        int v = t >> 7, p = t & 127;
        const float* gW = gateW + (size_t)v * 128 * 128;
        const float* rb = relb + (size_t)v * 128;
        float acc = 0.f;
        for (int o = 0; o < 128; ++o) acc += rb[o] * gW[o * 128 + p];
        rgb[v * 128 + p] = acc;
    } else if (id < PAE9) {
        int t = id - PAE8;
        int v = t / EE;
        rankA[t] = atomicAdd(&C[v * NN + edst[t]], 1);
    }
}

// ---------------- prep (fallback path): Wsf = selfW @ fusW_top ; c1 ----
__global__ void prep_kernel(const float* __restrict__ selfW, const float* __restrict__ selfb,
                            const float* __restrict__ fusW, const float* __restrict__ fusb,
                            float* __restrict__ Wsf, float* __restrict__ c1) {
    int o = threadIdx.x;
    int k = blockIdx.x;
    if (k < 128) {
        float acc = 0.f;
        for (int m = 0; m < 128; ++m)
            acc += selfW[k * 128 + m] * fusW[m * 128 + o];
        Wsf[k * 128 + o] = acc;
    } else {
        float acc = 0.f;
        for (int m = 0; m < 128; ++m)
            acc += selfb[m] * fusW[m * 128 + o];
        c1[o] = acc + fusb[o];
    }
}

// ================= CSR build (hierarchical scan) + gather =================

__global__ __launch_bounds__(256) void scanA_kernel(
        const int* __restrict__ C, int* __restrict__ bs) {
    int b = blockIdx.x, t = threadIdx.x;
    int i = b * 256 + t;
    int v = (i < TOT) ? C[i] : 0;
    __shared__ int s[256];
    s[t] = v;
    __syncthreads();
    #pragma unroll
    for (int off = 128; off > 0; off >>= 1) {
        if (t < off) s[t] += s[t + off];
        __syncthreads();
    }
    if (t == 0) bs[b] = s[0];
}

__global__ __launch_bounds__(1024) void scanB_kernel(int* __restrict__ bs) {
    __shared__ int s[2048];
    int t = threadIdx.x;
    int v0 = (t < NB) ? bs[t] : 0;
    int v1 = (t + 1024 < NB) ? bs[t + 1024] : 0;
    s[t] = v0; s[t + 1024] = v1;
    __syncthreads();
    #pragma unroll
    for (int off = 1; off < 2048; off <<= 1) {
        int x0 = (t >= off) ? s[t - off] : 0;
        int x1 = (t + 1024 >= off) ? s[t + 1024 - off] : 0;
        __syncthreads();
        s[t] += x0; s[t + 1024] += x1;
        __syncthreads();
    }
    if (t < NB) bs[t] = s[t] - v0;
    if (t + 1024 < NB) bs[t + 1024] = s[t + 1024] - v1;
}

__global__ __launch_bounds__(256) void scanC_kernel(
        int* __restrict__ C, const int* __restrict__ bs) {
    int b = blockIdx.x, t = threadIdx.x;
    int i = b * 256 + t;
    int v = (i < TOT) ? C[i] : 0;
    __shared__ int s[256];
    s[t] = v;
    __syncthreads();
    #pragma unroll
    for (int off = 1; off < 256; off <<= 1) {
        int x = (t >= off) ? s[t - off] : 0;
        __syncthreads();
        s[t] += x;
        __syncthreads();
    }
    if (i < TOT) C[i] = s[t] - v + bs[b];
}

// count (fallback path; main path counts inside prep_all)
__global__ __launch_bounds__(256) void count_kernel(
        const int* __restrict__ edst, int* __restrict__ C) {
    int t = blockIdx.x * 256 + threadIdx.x;
    if (t >= VV * EE) return;
    int v = t / EE;
    atomicAdd(&C[v * NN + edst[t]], 1);
}

// fill: ATOMIC-FREE. pos = exclusive bucket start (C, untouched) + precomputed
// rank. bsw write is fire-and-forget; C reads hit L2 (1.2 MB array).
__global__ __launch_bounds__(256) void fill_kernel(
        const int* __restrict__ esrc, const int* __restrict__ edst,
        const float* __restrict__ ew, const int* __restrict__ C,
        const int* __restrict__ rankA, int2* __restrict__ bsw) {
    int t = blockIdx.x * 256 + threadIdx.x;
    if (t >= VV * EE) return;
    int v = t / EE;
    int pos = C[v * NN + edst[t]] + rankA[t];
    int2 p;
    p.x = esrc[t];
    p.y = __float_as_int(ew[t]);
    bsw[pos] = p;
}

// one wave per (v,dst) row; C holds EXCLUSIVE start offsets
__global__ __launch_bounds__(256) void gather_kernel(
        const u16* __restrict__ featB, const int* __restrict__ C,
        const int2* __restrict__ bsw,
        u16* __restrict__ aggB, float* __restrict__ wsum) {
    int wid = (blockIdx.x * 256 + threadIdx.x) >> 6;
    int lane = threadIdx.x & 63;
    int start = C[wid];
    int end = (wid < TOT - 1) ? C[wid + 1] : (VV * EE);
    float a0 = 0.f, a1 = 0.f, wacc = 0.f;
    int e = start;
    for (; e + 4 <= end; e += 4) {
        int2 p0 = bsw[e], p1 = bsw[e + 1], p2 = bsw[e + 2], p3 = bsw[e + 3];
        u32 f0 = *reinterpret_cast<const u32*>(featB + (size_t)p0.x * DD + lane * 2);
        u32 f1 = *reinterpret_cast<const u32*>(featB + (size_t)p1.x * DD + lane * 2);
        u32 f2 = *reinterpret_cast<const u32*>(featB + (size_t)p2.x * DD + lane * 2);
        u32 f3 = *reinterpret_cast<const u32*>(featB + (size_t)p3.x * DD + lane * 2);
        float w0 = __int_as_float(p0.y), w1 = __int_as_float(p1.y);
        float w2 = __int_as_float(p2.y), w3 = __int_as_float(p3.y);
        a0 = fmaf(w0, bf2f((u16)(f0 & 0xffffu)), a0);
        a1 = fmaf(w0, bf2f((u16)(f0 >> 16)), a1);
        a0 = fmaf(w1, bf2f((u16)(f1 & 0xffffu)), a0);
        a1 = fmaf(w1, bf2f((u16)(f1 >> 16)), a1);
        a0 = fmaf(w2, bf2f((u16)(f2 & 0xffffu)), a0);
        a1 = fmaf(w2, bf2f((u16)(f2 >> 16)), a1);
        a0 = fmaf(w3, bf2f((u16)(f3 & 0xffffu)), a0);
        a1 = fmaf(w3, bf2f((u16)(f3 >> 16)), a1);
        wacc += (w0 + w1) + (w2 + w3);
    }
    for (; e < end; ++e) {
        int2 p = bsw[e];
        float w = __int_as_float(p.y);
        u32 f = *reinterpret_cast<const u32*>(featB + (size_t)p.x * DD + lane * 2);
        a0 = fmaf(w, bf2f((u16)(f & 0xffffu)), a0);
        a1 = fmaf(w, bf2f((u16)(f >> 16)), a1);
        wacc += w;
    }
    u32 packed = (u32)f2bf(a0) | ((u32)f2bf(a1) << 16);
    *reinterpret_cast<u32*>(aggB + (size_t)wid * DD + lane * 2) = packed;
    if (lane == 0) wsum[wid] = wacc;
}

// ================= fallback: atomic scatter =================
__global__ __launch_bounds__(256) void scatter_kernel(
        const int* __restrict__ esrc, const int* __restrict__ edst,
        const float* __restrict__ ew, const float* __restrict__ feat,
        u16* __restrict__ aggB, float* __restrict__ wsum) {
    long long t = (long long)blockIdx.x * 256 + threadIdx.x;
    int lane = (int)(t & 31);
    int eg = (int)(t >> 5);
    int v = eg / EE;
    int src = 0, dst = 0; float w = 0.f;
    if (lane == 0) {
        src = esrc[eg]; dst = edst[eg]; w = ew[eg];
    }
    src = __shfl(src, 0, 32);
    dst = __shfl(dst, 0, 32);
    w   = __shfl(w, 0, 32);
    const float* fr = feat + (size_t)src * DD + lane * 4;
    float4 q = *reinterpret_cast<const float4*>(fr);
    u16* outp = aggB + ((size_t)v * NN + dst) * DD + lane * 4;
    atomAddBf16x2(outp,     w * q.x, w * q.y);
    atomAddBf16x2(outp + 2, w * q.z, w * q.w);
    if (lane == 0) atomicAdd(wsum + v * NN + dst, w);
}

// ---------------- fallback VALU label ----------------
__global__ __launch_bounds__(256) void label_kernel(
        const float* __restrict__ feat, const float* __restrict__ clsW, const float* __restrict__ clsb,
        const float* __restrict__ attW1, const float* __restrict__ attb1,
        const float* __restrict__ attW2, const float* __restrict__ attb2,
        const float* __restrict__ att_bias,
        float* __restrict__ node_att, float* __restrict__ probs_out) {
    __shared__ float Xs[32][132];
    __shared__ float Ws[64][132];
    int tid = threadIdx.x;
    int row0 = blockIdx.x * 32;
    stage_x_f32<132, 256>(&Xs[0][0], feat + (size_t)row0 * DD, tid);
    int to = tid & 31, tn = tid >> 5;
    int o0 = to * 4, n0 = tn * 4;
    float acc[4][4] = {};
    for (int half = 0; half < 2; ++half) {
        __syncthreads();
        #pragma unroll
        for (int rep = 0; rep < 8; ++rep) {
            int flat = rep * 256 + tid;
            int kk = flat >> 5, o4 = flat & 31;
            int o = o4 * 4;
            int c = o >> 6, h = o & 63;
            int k = half * 64 + kk;
            float4 q = *reinterpret_cast<const float4*>(attW1 + (size_t)(c * 128 + k) * 64 + h);
            *reinterpret_cast<float4*>(&Ws[kk][o]) = q;
        }
        __syncthreads();
        gemm16<132, 132>(acc, &Xs[0][0], &Ws[0][0], n0, o0, half * 64);
    }
    int c = o0 >> 6, h0 = o0 & 63;
    float b1j[4], w2j[4];
    #pragma unroll
    for (int j = 0; j < 4; ++j) {
        b1j[j] = attb1[c * 64 + h0 + j];
        w2j[j] = attW2[c * 64 + h0 + j];
    }
    float part[4];
    #pragma unroll
    for (int i = 0; i < 4; ++i) {
        float s = 0.f;
        #pragma unroll
        for (int j = 0; j < 4; ++j) {
            float hv = acc[i][j] + b1j[j];
            hv = hv > 0.f ? hv : 0.f;
            s += hv * w2j[j];
        }
        part[i] = s;
    }
    __syncthreads();
    float* red = &Ws[0][0];          // [32][33]
    float* Ssc = red + 32 * 33;      // [32][2]
    float* Lsc = Ssc + 64;           // [32][2]
    #pragma unroll
    for (int i = 0; i < 4; ++i) red[(n0 + i) * 33 + to] = part[i];
    __syncthreads();
    if (tid < 64) {
        int n = tid >> 1, cc = tid & 1;
        float l = 0.f;
        for (int k = 0; k < 128; k += 4) {
            float4 x = *reinterpret_cast<const float4*>(&Xs[n][k]);
            l += x.x * clsW[(k + 0) * 2 + cc];
            l += x.y * clsW[(k + 1) * 2 + cc];
            l += x.z * clsW[(k + 2) * 2 + cc];
            l += x.w * clsW[(k + 3) * 2 + cc];
        }
        Lsc[n * 2 + cc] = l + clsb[cc];
        float s = 0.f;
        for (int u = 0; u < 16; ++u) s += red[n * 33 + cc * 16 + u];
        s += attb2[cc];
        Ssc[n * 2 + cc] = 1.f / (1.f + expf(-s));
    }
    __syncthreads();
    if (tid < 32) {
        int n = tid;
        float l0 = Lsc[n * 2], l1 = Lsc[n * 2 + 1];
        float m = fmaxf(l0, l1);
        float e0 = expf(l0 - m), e1 = expf(l1 - m);
        float inv = 1.f / (e0 + e1);
        float p0 = e0 * inv, p1 = e1 * inv;
        float na = p0 * Ssc[n * 2] + p1 * Ssc[n * 2 + 1] + att_bias[0];
        int row = row0 + n;
        node_att[row] = na;
        probs_out[row * 2]     = p0;
        probs_out[row * 2 + 1] = p1;
    }
}

// ---------------- MFMA relgate (unchained via W12) + fused view-score ----
// EXACT R1 version (best measured: ~113 us warm).
__global__ __launch_bounds__(256, 3) void relgate_mfma_kernel(
        const u16* __restrict__ relWb, const float* __restrict__ relb,
        const u16* __restrict__ W12b, const float* __restrict__ rgbv,
        const float* __restrict__ gateb,
        const u16* __restrict__ vattW1p, const float* __restrict__ vattb1,
        const float* __restrict__ vattW2, const float* __restrict__ vattb2,
        u16* __restrict__ aggB, const float* __restrict__ wsum,
        float* __restrict__ vscores) {
    __shared__ u16 Wf[128][136];   // X, then relW full, then view_out
    __shared__ u16 Wt[128][72];    // W12 halves, then vatt weights
    int tid = threadIdx.x;
    int wv = tid >> 6, lane = tid & 63;
    int quad = lane >> 4, l15 = lane & 15;
    int v = blockIdx.y;
    int row0 = blockIdx.x * 128;
    const size_t vbase = (size_t)v * NN;

    // ---- stage X ----
    #pragma unroll
    for (int rep = 0; rep < 8; ++rep) {
        int flat = rep * 256 + tid;
        int n = flat >> 4, c8 = flat & 15;
        int gr = row0 + n; if (gr >= NN) gr = NN - 1;
        uint4 q = *reinterpret_cast<const uint4*>(aggB + (vbase + gr) * DD + c8 * 8);
        *reinterpret_cast<uint4*>(&Wf[n][c8 * 8]) = q;
    }
    __syncthreads();                                     // S1

    // ---- A fragments (whole K) into registers, shared by both GEMMs ----
    s8v af[2][2][2];
    loadFrags(af, Wf, wv, l15, quad);
    __syncthreads();                                     // S2

    // ---- stage relW FULL -> Wf ; W12 half0 -> Wt ----
    const u16* W1 = relWb + (size_t)v * DD * DD;
    const u16* W2 = W12b + (size_t)v * DD * DD;
    stageWf(Wf, W1, tid);
    stageWtHalf(Wt, W2, tid);
    __syncthreads();                                     // S3

    f4v acc1[2][8], acc2[2][8];
    #pragma unroll
    for (int rt = 0; rt < 2; ++rt)
        #pragma unroll
        for (int c = 0; c < 8; ++c) {
            acc1[rt][c] = f4v{0.f, 0.f, 0.f, 0.f};
            acc2[rt][c] = f4v{0.f, 0.f, 0.f, 0.f};
        }

    // acc1: full rel GEMM (64 MFMA/wave) + acc2 half0 (32 MFMA/wave)
    mfmaWfFull(acc1, af, Wf, l15, quad);
    mfmaWt8(acc2, af, 0, Wt, l15, quad);
    __syncthreads();                                     // S4

    // ---- stage W12 half1 -> Wt ----
    stageWtHalf(Wt, W2 + 64, tid);
    __syncthreads();                                     // S5
    mfmaWt8(acc2, af, 1, Wt, l15, quad);

    // ---- epilogue: agg, gate, view_out -> Wf (bf16) ----
    float wsn[2][4];
    #pragma unroll
    for (int rt = 0; rt < 2; ++rt)
        #pragma unroll
        for (int r = 0; r < 4; ++r) {
            int gr = row0 + wv * 32 + rt * 16 + quad * 4 + r;
            wsn[rt][r] = wsum[vbase + (gr < NN ? gr : NN - 1)];
        }
    float rb[8], rg2[8], gb[8];
    #pragma unroll
    for (int c = 0; c < 8; ++c) {
        int col = c * 16 + l15;
        rb[c]  = relb[v * DD + col];
        rg2[c] = rgbv[v * DD + col];
        gb[c]  = gateb[v * DD + col];
    }
    #pragma unroll
    for (int rt = 0; rt < 2; ++rt)
        #pragma unroll
        for (int c = 0; c < 8; ++c)
            #pragma unroll
            for (int r = 0; r < 4; ++r) {
                float a = acc1[rt][c][r] + wsn[rt][r] * rb[c];
                float g = fsigmoid(acc2[rt][c][r] + wsn[rt][r] * rg2[c] + gb[c]);
                Wf[wv * 32 + rt * 16 + quad * 4 + r][c * 16 + l15] = f2bf(g * a);
            }
    __syncthreads();                                     // S6

    // ---- stage vatt -> Wt, dump view_out -> aggB, a2 frags ----
    {
        const u16* Wv = vattW1p + (size_t)v * 64 * DD;
        #pragma unroll
        for (int rep = 0; rep < 4; ++rep) {
            int flat = rep * 256 + tid;
            int n = flat >> 4, c8 = flat & 15;
            uint4 q = *reinterpret_cast<const uint4*>(Wv + (size_t)n * DD + c8 * 8);
            int half = c8 >> 3;
            *reinterpret_cast<uint4*>(&Wt[half * 64 + n][(c8 & 7) * 8]) = q;
        }
    }
    s8v a2[2][2][2];
    loadFrags(a2, Wf, wv, l15, quad);
    #pragma unroll
    for (int rep = 0; rep < 8; ++rep) {
        int flat = rep * 256 + tid;
        int n = flat >> 4, c8 = flat & 15;
        int gr = row0 + n;
        if (gr < NN)
            *reinterpret_cast<uint4*>(aggB + (vbase + gr) * DD + c8 * 8) =
                *reinterpret_cast<const uint4*>(&Wf[n][c8 * 8]);
    }
    __syncthreads();                                     // S7

    // ---- fused view-score GEMM ----
    f4v acc3[2][4];
    #pragma unroll
    for (int rt = 0; rt < 2; ++rt)
        #pragma unroll
        for (int c = 0; c < 4; ++c)
            acc3[rt][c] = f4v{0.f, 0.f, 0.f, 0.f};
    #pragma unroll
    for (int h = 0; h < 2; ++h)
        #pragma unroll
        for (int t = 0; t < 2; ++t) {
            int kl = t * 32 + quad * 8;
            #pragma unroll
            for (int c = 0; c < 4; ++c) {
                s8v b = *reinterpret_cast<const s8v*>(&Wt[h * 64 + c * 16 + l15][kl]);
                acc3[0][c] = __builtin_amdgcn_mfma_f32_16x16x32_bf16(a2[h][t][0], b, acc3[0][c], 0, 0, 0);
                acc3[1][c] = __builtin_amdgcn_mfma_f32_16x16x32_bf16(a2[h][t][1], b, acc3[1][c], 0, 0, 0);
            }
        }
    float vb1[4], vw2[4];
    #pragma unroll
    for (int c = 0; c < 4; ++c) {
        int col = c * 16 + l15;
        vb1[c] = vattb1[col];
        vw2[c] = vattW2[col];
    }
    float vb2 = vattb2[0];
    #pragma unroll
    for (int rt = 0; rt < 2; ++rt)
        #pragma unroll
        for (int r = 0; r < 4; ++r) {
            float p = 0.f;
            #pragma unroll
            for (int c = 0; c < 4; ++c) {
                float hv = acc3[rt][c][r] + vb1[c];
                hv = hv > 0.f ? hv : 0.f;
                p += hv * vw2[c];
            }
            #pragma unroll
            for (int m = 1; m < 16; m <<= 1)
                p += __shfl_xor(p, m);
            int gr = row0 + wv * 32 + rt * 16 + quad * 4 + r;
            if (l15 == 0 && gr < NN)
                vscores[vbase + gr] = p + vb2;
        }
}

// ---------------- fallback VALU relgate ----------------
__global__ __launch_bounds__(256) void relgate_kernel(
        const float* __restrict__ relW, const float* __restrict__ relb,
        const float* __restrict__ gateW, const float* __restrict__ gateb,
        u16* __restrict__ aggB, const float* __restrict__ wsum) {
    __shared__ float Xs[32][128];
    __shared__ float Ws[64][132];
    int tid = threadIdx.x;
    int v = blockIdx.y;
    int row0 = blockIdx.x * 32;
    u16* base = aggB + ((size_t)v * NN + row0) * DD;
    stage_x_bf16<128, 256>(&Xs[0][0], base, tid);
    int to = tid & 31, tn = tid >> 5;
    int o0 = to * 4, n0 = tn * 4;
    float acc[4][4] = {};
    const float* W1 = relW + (size_t)v * DD * DD;
    for (int half = 0; half < 2; ++half) {
        __syncthreads();
        stage_w_f32<132, 256>(&Ws[0][0], W1 + half * 64 * DD, tid);
        __syncthreads();
        gemm16<128, 132>(acc, &Xs[0][0], &Ws[0][0], n0, o0, half * 64);
    }
    float wsn[4], rb[4];
    #pragma unroll
    for (int i = 0; i < 4; ++i) wsn[i] = wsum[v * NN + row0 + n0 + i];
    #pragma unroll
    for (int j = 0; j < 4; ++j) rb[j] = relb[v * DD + o0 + j];
    #pragma unroll
    for (int i = 0; i < 4; ++i)
        #pragma unroll
        for (int j = 0; j < 4; ++j) acc[i][j] += wsn[i] * rb[j];
    __syncthreads();
    #pragma unroll
    for (int i = 0; i < 4; ++i)
        *reinterpret_cast<float4*>(&Xs[n0 + i][o0]) = make_float4(acc[i][0], acc[i][1], acc[i][2], acc[i][3]);
    float acc2[4][4] = {};
    const float* W2 = gateW + (size_t)v * DD * DD;
    for (int half = 0; half < 2; ++half) {
        __syncthreads();
        stage_w_f32<132, 256>(&Ws[0][0], W2 + half * 64 * DD, tid);
        __syncthreads();
        gemm16<128, 132>(acc2, &Xs[0][0], &Ws[0][0], n0, o0, half * 64);
    }
    float gb[4];
    #pragma unroll
    for (int j = 0; j < 4; ++j) gb[j] = gateb[v * DD + o0 + j];
    #pragma unroll
    for (int i = 0; i < 4; ++i) {
        float g0 = 1.f / (1.f + expf(-(acc2[i][0] + gb[0])));
        float g1 = 1.f / (1.f + expf(-(acc2[i][1] + gb[1])));
        float g2 = 1.f / (1.f + expf(-(acc2[i][2] + gb[2])));
        float g3 = 1.f / (1.f + expf(-(acc2[i][3] + gb[3])));
        ushort4 r;
        r.x = f2bf(g0 * acc[i][0]); r.y = f2bf(g1 * acc[i][1]);
        r.z = f2bf(g2 * acc[i][2]); r.w = f2bf(g3 * acc[i][3]);
        *reinterpret_cast<ushort4*>(base + (size_t)(n0 + i) * DD + o0) = r;
    }
}

// ---------------- fallback view attention scores ----------------
__global__ __launch_bounds__(128) void vatt_kernel(
        const u16* __restrict__ aggB, const float* __restrict__ view_pref,
        const float* __restrict__ vattW1, const float* __restrict__ vattb1,
        const float* __restrict__ vattW2, const float* __restrict__ vattb2,
        float* __restrict__ vscores) {
    __shared__ float Xs[32][132];
    __shared__ float Ws[128][68];
    int tid = threadIdx.x;
    int v = blockIdx.y;
    int row0 = blockIdx.x * 32;
    const u16* base = aggB + ((size_t)v * NN + row0) * DD;
    #pragma unroll
    for (int rep = 0; rep < 4; ++rep) {
        int flat = rep * 128 + tid;
        int n = flat >> 4, c8 = flat & 15;
        uint4 q = *reinterpret_cast<const uint4*>(base + (size_t)n * DD + c8 * 8);
        float4 pa = *reinterpret_cast<const float4*>(view_pref + v * DD + c8 * 8);
        float4 pb = *reinterpret_cast<const float4*>(view_pref + v * DD + c8 * 8 + 4);
        float* d = &Xs[n][c8 * 8];
        d[0] = bf2f((u16)(q.x & 0xffffu)) * pa.x; d[1] = bf2f((u16)(q.x >> 16)) * pa.y;
        d[2] = bf2f((u16)(q.y & 0xffffu)) * pa.z; d[3] = bf2f((u16)(q.y >> 16)) * pa.w;
        d[4] = bf2f((u16)(q.z & 0xffffu)) * pb.x; d[5] = bf2f((u16)(q.z >> 16)) * pb.y;
        d[6] = bf2f((u16)(q.w & 0xffffu)) * pb.z; d[7] = bf2f((u16)(q.w >> 16)) * pb.w;
    }
    #pragma unroll
    for (int rep = 0; rep < 16; ++rep) {
        int flat = rep * 128 + tid;
        int k = flat >> 4, c4 = flat & 15;
        float4 q = *reinterpret_cast<const float4*>(vattW1 + k * 64 + c4 * 4);
        *reinterpret_cast<float4*>(&Ws[k][c4 * 4]) = q;
    }
    __syncthreads();
    int to = tid & 15, tn = tid >> 4;
    int o0 = to * 4, n0 = tn * 4;
    float acc[4][4] = {};
    gemm16<132, 68>(acc, &Xs[0][0], &Ws[0][0], n0, o0, 0);
    gemm16<132, 68>(acc, &Xs[0][0], &Ws[64][0], n0, o0, 64);
    float b1[4], w2[4];
    #pragma unroll
    for (int j = 0; j < 4; ++j) {
        b1[j] = vattb1[o0 + j];
        w2[j] = vattW2[o0 + j];
    }
    float part[4];
    #pragma unroll
    for (int i = 0; i < 4; ++i) {
        float s = 0.f;
        #pragma unroll
        for (int j = 0; j < 4; ++j) {
            float hv = acc[i][j] + b1[j];
            hv = hv > 0.f ? hv : 0.f;
            s += hv * w2[j];
        }
        part[i] = s;
    }
    __syncthreads();
    float* red = &Ws[0][0];   // [32][17]
    #pragma unroll
    for (int i = 0; i < 4; ++i) red[(n0 + i) * 17 + to] = part[i];
    __syncthreads();
    if (tid < 32) {
        float s = 0.f;
        for (int u = 0; u < 16; ++u) s += red[tid * 17 + u];
        vscores[(size_t)v * NN + row0 + tid] = s + vattb2[0];
    }
}

// ---------------- fallback combine ----------------
__global__ __launch_bounds__(256) void combine_kernel(
        u16* __restrict__ aggB, const float* __restrict__ vscores,
        const float* __restrict__ node_att) {
    int t = blockIdx.x * 256 + threadIdx.x;
    int n = t >> 5, c4 = t & 31;
    float s0 = vscores[n], s1 = vscores[NN + n], s2 = vscores[2 * NN + n];
    float m = fmaxf(s0, fmaxf(s1, s2));
    float e0 = expf(s0 - m), e1 = expf(s1 - m), e2 = expf(s2 - m);
    float inv = 1.f / (e0 + e1 + e2);
    float w0 = e0 * inv, w1 = e1 * inv, w2 = e2 * inv;
    float na = node_att[n];
    size_t off = (size_t)n * DD + c4 * 4;
    ushort4 q0 = *reinterpret_cast<const ushort4*>(aggB + off);
    ushort4 q1 = *reinterpret_cast<const ushort4*>(aggB + (size_t)NN * DD + off);
    ushort4 q2 = *reinterpret_cast<const ushort4*>(aggB + 2 * (size_t)NN * DD + off);
    ushort4 r;
    r.x = f2bf((bf2f(q0.x) * w0 + bf2f(q1.x) * w1 + bf2f(q2.x) * w2) * na);
    r.y = f2bf((bf2f(q0.y) * w0 + bf2f(q1.y) * w1 + bf2f(q2.y) * w2) * na);
    r.z = f2bf((bf2f(q0.z) * w0 + bf2f(q1.z) * w1 + bf2f(q2.z) * w2) * na);
    r.w = f2bf((bf2f(q0.w) * w0 + bf2f(q1.w) * w1 + bf2f(q2.w) * w2) * na);
    *reinterpret_cast<ushort4*>(aggB + off) = r;
}

// ---------------- MFMA final + fused LABEL + fused combine (R7 version) ----
__global__ __launch_bounds__(256, 3) void final_mfma_kernel(
        const u16* __restrict__ featB, const u16* __restrict__ aggB,
        const float* __restrict__ vsc,
        const u16* __restrict__ attW1B,
        const float* __restrict__ clsW, const float* __restrict__ clsb,
        const float* __restrict__ attb1, const float* __restrict__ attW2,
        const float* __restrict__ attb2, const float* __restrict__ att_bias,
        const u16* __restrict__ WsfB, const u16* __restrict__ featWB,
        const u16* __restrict__ fusWbB,
        const float* __restrict__ c1, const float* __restrict__ featb,
        const float* __restrict__ ln_g, const float* __restrict__ ln_b,
        float* __restrict__ outp, float* __restrict__ probs_out) {
    __shared__ u16 Wf[128][136];   // featB, then Wsf, then combined; cols 128..133 = rw
    __shared__ u16 Wt[128][72];
    __shared__ float naS[128];
    int tid = threadIdx.x;
    int wv = tid >> 6, lane = tid & 63;
    int quad = lane >> 4, l15 = lane & 15;
    int row0 = blockIdx.x * 128;

    // stage featB -> Wf ; attW1B half0 -> Wt
    #pragma unroll
    for (int rep = 0; rep < 8; ++rep) {
        int flat = rep * 256 + tid;
        int n = flat >> 4, c8 = flat & 15;
        int gr = row0 + n; if (gr >= NN) gr = NN - 1;
        uint4 q = *reinterpret_cast<const uint4*>(featB + (size_t)gr * DD + c8 * 8);
        *reinterpret_cast<uint4*>(&Wf[n][c8 * 8]) = q;
    }
    stageWtHalf(Wt, attW1B, tid);
    __syncthreads();                                     // S1

    s8v af[2][2][2];
    loadFrags(af, Wf, wv, l15, quad);

    // ---------- label attention phase (fused) ----------
    {
        f4v accL[2][8];
        #pragma unroll
        for (int rt = 0; rt < 2; ++rt)
            #pragma unroll
            for (int c = 0; c < 8; ++c)
                accL[rt][c] = f4v{0.f, 0.f, 0.f, 0.f};
        mfmaWt8(accL, af, 0, Wt, l15, quad);
        __syncthreads();                                 // S2
        stageWtHalf(Wt, attW1B + 64, tid);
        __syncthreads();                                 // S3
        mfmaWt8(accL, af, 1, Wt, l15, quad);

        float ab1[8], aw2[8];
        #pragma unroll
        for (int c = 0; c < 8; ++c) {
            int col = c * 16 + l15;
            ab1[c] = attb1[col];
            aw2[c] = attW2[col];
        }
        float cw0[8], cw1[8];
        #pragma unroll
        for (int j = 0; j < 8; ++j) {
            int k = l15 * 8 + j;
            cw0[j] = clsW[k * 2];
            cw1[j] = clsW[k * 2 + 1];
        }
        float cb0 = clsb[0], cb1 = clsb[1];
        float b20 = attb2[0], b21 = attb2[1];
        float abias = att_bias[0];

        #pragma unroll
        for (int rt = 0; rt < 2; ++rt)
            #pragma unroll
            for (int r = 0; r < 4; ++r) {
                int n = wv * 32 + rt * 16 + quad * 4 + r;
                int gr = row0 + n;
                float p0 = 0.f, p1 = 0.f;
                #pragma unroll
                for (int c = 0; c < 4; ++c) {
                    float hv = accL[rt][c][r] + ab1[c];
                    hv = hv > 0.f ? hv : 0.f;
                    p0 += hv * aw2[c];
                }
                #pragma unroll
                for (int c = 4; c < 8; ++c) {
                    float hv = accL[rt][c][r] + ab1[c];
                    hv = hv > 0.f ? hv : 0.f;
                    p1 += hv * aw2[c];
                }
                uint4 q = *reinterpret_cast<const uint4*>(&Wf[n][l15 * 8]);
                float f[8];
                f[0] = bf2f((u16)(q.x & 0xffffu)); f[1] = bf2f((u16)(q.x >> 16));
                f[2] = bf2f((u16)(q.y & 0xffffu)); f[3] = bf2f((u16)(q.y >> 16));
                f[4] = bf2f((u16)(q.z & 0xffffu)); f[5] = bf2f((u16)(q.z >> 16));
                f[6] = bf2f((u16)(q.w & 0xffffu)); f[7] = bf2f((u16)(q.w >> 16));
                float l0 = 0.f, l1 = 0.f;
                #pragma unroll
                for (int j = 0; j < 8; ++j) {
                    l0 = fmaf(f[j], cw0[j], l0);
                    l1 = fmaf(f[j], cw1[j], l1);
                }
                #pragma unroll
                for (int m = 1; m < 16; m <<= 1) {
                    p0 += __shfl_xor(p0, m);
                    p1 += __shfl_xor(p1, m);
                    l0 += __shfl_xor(l0, m);
                    l1 += __shfl_xor(l1, m);
                }
                if (l15 == 0) {
                    float s0 = 1.f / (1.f + expf(-(p0 + b20)));
                    float s1 = 1.f / (1.f + expf(-(p1 + b21)));
                    l0 += cb0; l1 += cb1;
                    float mm = fmaxf(l0, l1);
                    float e0 = expf(l0 - mm), e1 = expf(l1 - mm);
                    float inv = 1.f / (e0 + e1);
                    float q0 = e0 * inv, q1 = e1 * inv;
                    naS[n] = q0 * s0 + q1 * s1 + abias;
                    if (gr < NN) {
                        probs_out[gr * 2]     = q0;
                        probs_out[gr * 2 + 1] = q1;
                    }
                }
            }
    }
    __syncthreads();                                     // S4: naS visible

    // per-row combine weights (softmax over views * node_att) -> Wf row padding
    if (tid < 128) {
        int gr = row0 + tid; if (gr >= NN) gr = NN - 1;
        float s0 = vsc[gr], s1 = vsc[NN + gr], s2 = vsc[2 * NN + gr];
        float m = fmaxf(s0, fmaxf(s1, s2));
        const float L2E = 1.4426950408889634f;
        float e0 = fexp2((s0 - m) * L2E);
        float e1 = fexp2((s1 - m) * L2E);
        float e2 = fexp2((s2 - m) * L2E);
        float na = naS[tid] * frcp(e0 + e1 + e2);
        float* rwp = reinterpret_cast<float*>(&Wf[tid][128]);
        rwp[0] = e0 * na;
        rwp[1] = e1 * na;
        rwp[2] = e2 * na;
    }

    // stage WsfB FULL -> Wf (cols 0..127 only; padding preserved) ; featWB h0 -> Wt
    stageWf(Wf, WsfB, tid);
    stageWtHalf(Wt, featWB, tid);
    __syncthreads();                                     // S5

    f4v acc1[2][8], acc2[2][8];
    #pragma unroll
    for (int rt = 0; rt < 2; ++rt)
        #pragma unroll
        for (int c = 0; c < 8; ++c) {
            acc1[rt][c] = f4v{0.f, 0.f, 0.f, 0.f};
            acc2[rt][c] = f4v{0.f, 0.f, 0.f, 0.f};
        }

    mfmaWfFull(acc1, af, Wf, l15, quad);      // X @ Wsf
    mfmaWt8(acc2, af, 0, Wt, l15, quad);      // X @ featW (h0)
    __syncthreads();                                     // S6
    stageWtHalf(Wt, featWB + 64, tid);
    __syncthreads();                                     // S7
    mfmaWt8(acc2, af, 1, Wt, l15, quad);      // X @ featW (h1)

    // fused combine: Wf cols 0..127 = bf16( rw0*view0 + rw1*view1 + rw2*view2 )
    #pragma unroll
    for (int rep = 0; rep < 8; ++rep) {
        int flat = rep * 256 + tid;
        int n = flat >> 4, c8 = flat & 15;
        int gr = row0 + n; if (gr >= NN) gr = NN - 1;
        size_t off = (size_t)gr * DD + c8 * 8;
        uint4 q0 = *reinterpret_cast<const uint4*>(aggB + off);
        uint4 q1 = *reinterpret_cast<const uint4*>(aggB + (size_t)NN * DD + off);
        uint4 q2 = *reinterpret_cast<const uint4*>(aggB + 2 * (size_t)NN * DD + off);
        const float* rwp = reinterpret_cast<const float*>(&Wf[n][128]);
        float w0 = rwp[0], w1 = rwp[1], w2 = rwp[2];
        u32 o[4];
        const u32* a = &q0.x; const u32* b = &q1.x; const u32* c = &q2.x;
        #pragma unroll
        for (int j = 0; j < 4; ++j) {
            float lo = bf2f((u16)(a[j] & 0xffffu)) * w0 + bf2f((u16)(b[j] & 0xffffu)) * w1
                     + bf2f((u16)(c[j] & 0xffffu)) * w2;
            float hi = bf2f((u16)(a[j] >> 16)) * w0 + bf2f((u16)(b[j] >> 16)) * w1
                     + bf2f((u16)(c[j] >> 16)) * w2;
            o[j] = (u32)f2bf(lo) | ((u32)f2bf(hi) << 16);
        }
        uint4 r; r.x = o[0]; r.y = o[1]; r.z = o[2]; r.w = o[3];
        *reinterpret_cast<uint4*>(&Wf[n][c8 * 8]) = r;
    }
    __syncthreads();                                     // S8

    // fus GEMM half0
    stageWtHalf(Wt, fusWbB, tid);
    __syncthreads();                                     // S9
    #pragma unroll
    for (int t = 0; t < 2; ++t) {
        int kl = t * 32 + quad * 8;
        s8v a0 = *reinterpret_cast<const s8v*>(&Wf[wv * 32 + l15][kl]);
        s8v a1 = *reinterpret_cast<const s8v*>(&Wf[wv * 32 + 16 + l15][kl]);
        #pragma unroll
        for (int c = 0; c < 8; ++c) {
            s8v b = *reinterpret_cast<const s8v*>(&Wt[c * 16 + l15][kl]);
            acc1[0][c] = __builtin_amdgcn_mfma_f32_16x16x32_bf16(a0, b, acc1[0][c], 0, 0, 0);
            acc1[1][c] = __builtin_amdgcn_mfma_f32_16x16x32_bf16(a1, b, acc1[1][c], 0, 0, 0);
        }
    }
    __syncthreads();                                     // S10
    stageWtHalf(Wt, fusWbB + 64, tid);
    __syncthreads();                                     // S11
    #pragma unroll
    for (int t = 0; t < 2; ++t) {
        int kl = t * 32 + quad * 8;
        s8v a0 = *reinterpret_cast<const s8v*>(&Wf[wv * 32 + l15][64 + kl]);
        s8v a1 = *reinterpret_cast<const s8v*>(&Wf[wv * 32 + 16 + l15][64 + kl]);
        #pragma unroll
        for (int c = 0; c < 8; ++c) {
            s8v b = *reinterpret_cast<const s8v*>(&Wt[c * 16 + l15][kl]);
            acc1[0][c] = __builtin_amdgcn_mfma_f32_16x16x32_bf16(a0, b, acc1[0][c], 0, 0, 0);
            acc1[1][c] = __builtin_amdgcn_mfma_f32_16x16x32_bf16(a1, b, acc1[1][c], 0, 0, 0);
        }
    }

    float c1j[8], fbj[8], gj[8], bj[8];
    #pragma unroll
    for (int c = 0; c < 8; ++c) {
        int col = c * 16 + l15;
        c1j[c] = c1[col];
        fbj[c] = featb[col];
        gj[c]  = ln_g[col];
        bj[c]  = ln_b[col];
    }
    #pragma unroll
    for (int rt = 0; rt < 2; ++rt)
        #pragma unroll
        for (int c = 0; c < 8; ++c)
            #pragma unroll
            for (int r = 0; r < 4; ++r) {
                float f = acc1[rt][c][r] + c1j[c];
                f = f > 0.f ? f : 0.f;
                acc1[rt][c][r] = f + acc2[rt][c][r] + fbj[c];
            }
    #pragma unroll
    for (int rt = 0; rt < 2; ++rt)
        #pragma unroll
        for (int r = 0; r < 4; ++r) {
            float s = 0.f, q = 0.f;
            #pragma unroll
            for (int c = 0; c < 8; ++c) {
                float x = acc1[rt][c][r];
                s += x; q += x * x;
            }
            #pragma unroll
            for (int m = 1; m < 16; m <<= 1) {
                s += __shfl_xor(s, m);
                q += __shfl_xor(q, m);
            }
            float mu = s * (1.f / 128.f);
            float var = q * (1.f / 128.f) - mu * mu;
            float rs = rsqrtf(var + 1e-5f);
            int gr = row0 + wv * 32 + rt * 16 + quad * 4 + r;
            if (gr < NN) {
                #pragma unroll
                for (int c = 0; c < 8; ++c)
                    outp[(size_t)gr * DD + c * 16 + l15] =
                        (acc1[rt][c][r] - mu) * rs * gj[c] + bj[c];
            }
        }
}

// ---------------- fallback helper kernels ----------------
__global__ __launch_bounds__(256) void featconv_kernel(
        const float* __restrict__ feat, u16* __restrict__ featB) {
    int t = blockIdx.x * 256 + threadIdx.x;
    float4 q = *reinterpret_cast<const float4*>(feat + (size_t)t * 4);
    ushort4 r;
    r.x = f2bf(q.x); r.y = f2bf(q.y); r.z = f2bf(q.z); r.w = f2bf(q.w);
    *reinterpret_cast<ushort4*>(featB + (size_t)t * 4) = r;
}

// ---------------- fallback VALU final ----------------
__global__ __launch_bounds__(256) void final_kernel(
        const float* __restrict__ feat, const u16* __restrict__ weightedB,
        const float* __restrict__ Wsf, const float* __restrict__ c1,
        const float* __restrict__ fusW, const float* __restrict__ featW,
        const float* __restrict__ featb, const float* __restrict__ ln_g,
        const float* __restrict__ ln_b, float* __restrict__ outp) {
    __shared__ float Xs[32][128];
    __shared__ float Ws[64][128];
    int tid = threadIdx.x;
    int row0 = blockIdx.x * 32;
    stage_x_f32<128, 256>(&Xs[0][0], feat + (size_t)row0 * DD, tid);
    int to = tid & 31, tn = tid >> 5;
    int o0 = to * 4, n0 = tn * 4;
    float acc1[4][4] = {}, acc2[4][4] = {};
    for (int half = 0; half < 2; ++half) {
        __syncthreads();
        stage_w_f32<128, 256>(&Ws[0][0], Wsf + half * 64 * 128, tid);
        __syncthreads();
        gemm16<128, 128>(acc1, &Xs[0][0], &Ws[0][0], n0, o0, half * 64);
    }
    for (int half = 0; half < 2; ++half) {
        __syncthreads();
        stage_w_f32<128, 256>(&Ws[0][0], featW + half * 64 * 128, tid);
        __syncthreads();
        gemm16<128, 128>(acc2, &Xs[0][0], &Ws[0][0], n0, o0, half * 64);
    }
    __syncthreads();
    stage_x_bf16<128, 256>(&Xs[0][0], weightedB + (size_t)row0 * DD, tid);
    for (int half = 0; half < 2; ++half) {
        __syncthreads();
        stage_w_f32<128, 256>(&Ws[0][0], fusW + (size_t)(128 + half * 64) * 128, tid);
        __syncthreads();
        gemm16<128, 128>(acc1, &Xs[0][0], &Ws[0][0], n0, o0, half * 64);
    }
    float c1j[4], fbj[4], gj[4], bj[4];
    #pragma unroll
    for (int j = 0; j < 4; ++j) {
        c1j[j] = c1[o0 + j];
        fbj[j] = featb[o0 + j];
        gj[j]  = ln_g[o0 + j];
        bj[j]  = ln_b[o0 + j];
    }
    float val[4][4];
    #pragma unroll
    for (int i = 0; i < 4; ++i)
        #pragma unroll
        for (int j = 0; j < 4; ++j) {
            float f = acc1[i][j] + c1j[j];
            f = f > 0.f ? f : 0.f;
            val[i][j] = f + acc2[i][j] + fbj[j];
        }
    __syncthreads();
    float* red_s = &Ws[0][0];
    float* red_q = red_s + 32 * 33;
    float* mus   = red_q + 32 * 33;
    float* rss   = mus + 32;
    #pragma unroll
    for (int i = 0; i < 4; ++i) {
        float s = 0.f, q = 0.f;
        #pragma unroll
        for (int j = 0; j < 4; ++j) { s += val[i][j]; q += val[i][j] * val[i][j]; }
        red_s[(n0 + i) * 33 + to] = s;
        red_q[(n0 + i) * 33 + to] = q;
    }
    __syncthreads();
    if (tid < 32) {
        float s = 0.f, q = 0.f;
        for (int u = 0; u < 32; ++u) { s += red_s[tid * 33 + u]; q += red_q[tid * 33 + u]; }
        float mu = s / 128.f;
        float var = q / 128.f - mu * mu;
        mus[tid] = mu;
        rss[tid] = rsqrtf(var + 1e-5f);
    }
    __syncthreads();
    #pragma unroll
    for (int i = 0; i < 4; ++i) {
        float mu = mus[n0 + i], rs = rss[n0 + i];
        float4 o;
        o.x = (val[i][0] - mu) * rs * gj[0] + bj[0];
        o.y = (val[i][1] - mu) * rs * gj[1] + bj[1];
        o.z = (val[i][2] - mu) * rs * gj[2] + bj[2];
        o.w = (val[i][3] - mu) * rs * gj[3] + bj[3];
        *reinterpret_cast<float4*>(outp + (size_t)(row0 + n0 + i) * DD + o0) = o;
    }
}

extern "C" void kernel_launch(void* const* d_in, const int* in_sizes, int n_in,
                              void* d_out, int out_size, void* d_ws, size_t ws_size,
                              hipStream_t stream) {
    (void)in_sizes; (void)n_in; (void)out_size;
    const float* feat      = (const float*)d_in[0];
    const int*   esrc      = (const int*)d_in[1];
    const int*   edst      = (const int*)d_in[2];
    const float* ew        = (const float*)d_in[3];
    const float* clsW      = (const float*)d_in[4];
    const float* clsb      = (const float*)d_in[5];
    const float* attW1     = (const float*)d_in[6];
    const float* attb1     = (const float*)d_in[7];
    const float* attW2     = (const float*)d_in[8];
    const float* attb2     = (const float*)d_in[9];
    const float* att_bias  = (const float*)d_in[10];
    const float* relW      = (const float*)d_in[11];
    const float* relb      = (const float*)d_in[12];
    const float* gateW     = (const float*)d_in[13];
    const float* gateb     = (const float*)d_in[14];
    const float* view_pref = (const float*)d_in[15];
    const float* vattW1    = (const float*)d_in[16];
    const float* vattb1    = (const float*)d_in[17];
    const float* vattW2    = (const float*)d_in[18];
    const float* vattb2    = (const float*)d_in[19];
    const float* selfW     = (const float*)d_in[20];
    const float* selfb     = (const float*)d_in[21];
    const float* featW     = (const float*)d_in[22];
    const float* featb     = (const float*)d_in[23];
    const float* fusW      = (const float*)d_in[24];
    const float* fusb      = (const float*)d_in[25];
    const float* ln_g      = (const float*)d_in[26];
    const float* ln_b      = (const float*)d_in[27];

    // workspace layout (~120 MiB):
    u16*   aggB = (u16*)d_ws;                                   // [3][N][128] bf16
    float* wsum = (float*)(aggB + (size_t)VV * NN * DD);        // [3][N]
    float* natt = wsum + (size_t)VV * NN;                       // [N] (fallback only)
    float* vsc  = natt + NN;                                    // [3][N]
    float* Wsf  = vsc + (size_t)VV * NN;                        // [128][128] (fallback only)
    float* c1   = Wsf + DD * DD;                                // [128]
    u16* relWb  = (u16*)(c1 + DD);                              // [3][128][128] bf16
    u16* gateWb = relWb + (size_t)VV * DD * DD;                 // [3][128][128] bf16
    u16* WsfB   = gateWb + (size_t)VV * DD * DD;                // [128][128] bf16
    u16* featWB = WsfB + DD * DD;                               // [128][128] bf16
    u16* fusWbB = featWB + DD * DD;                             // [128][128] bf16
    u16* attW1B = fusWbB + DD * DD;                             // [128][128] bf16
    u16* vattW1p = attW1B + DD * DD;                            // [3][64][128] bf16
    u16* W12b   = vattW1p + (size_t)VV * 64 * DD;               // [3][128][128] bf16
    float* rgb  = (float*)(W12b + (size_t)VV * DD * DD);        // [3][128]
    int*   C    = (int*)(rgb + VV * DD);                        // [3N]
    int*   bs   = C + (size_t)TOT;                              // [NB]
    int2*  bsw  = (int2*)(bs + NB + 1);                         // [3E] packed (src,w)
    u16* featB  = (u16*)(bsw + (size_t)VV * EE);                // [N][128] bf16
    size_t needed = (size_t)((char*)(featB + (size_t)NN * DD) - (char*)d_ws);

    // rank[t] aliases the first 6 MB of aggB: written by prep_all, read by
    // fill, dead before gather (which overwrites aggB). No extra workspace.
    int* rankA = (int*)aggB;

    float* outp  = (float*)d_out;
    float* probs = outp + (size_t)NN * DD;

    if (ws_size >= needed) {
        hipMemsetAsync(C, 0, (size_t)TOT * sizeof(int), stream);
        prep_all_kernel<<<PA_GRID, 256, 0, stream>>>(
            feat, featB, relW, gateW, relWb, gateWb,
            selfW, selfb, fusW, fusb, WsfB, c1,
            featW, featWB, fusWbB, attW1, attW1B,
            vattW1, view_pref, vattW1p, relb, W12b, rgb,
            edst, C, rankA);
        scanA_kernel<<<NB, 256, 0, stream>>>(C, bs);
        scanB_kernel<<<1, 1024, 0, stream>>>(bs);
        scanC_kernel<<<NB, 256, 0, stream>>>(C, bs);
        fill_kernel<<<(VV * EE + 255) / 256, 256, 0, stream>>>(esrc, edst, ew, C, rankA, bsw);
        gather_kernel<<<(VV * NN) / 4, 256, 0, stream>>>(featB, C, bsw, aggB, wsum);
        relgate_mfma_kernel<<<dim3(RGB, 3), 256, 0, stream>>>(relWb, relb, W12b, rgb, gateb,
                                                              vattW1p, vattb1, vattW2, vattb2,
                                                              aggB, wsum, vsc);
        final_mfma_kernel<<<RGB, 256, 0, stream>>>(featB, aggB, vsc,
                                                   attW1B, clsW, clsb, attb1, attW2,
                                                   attb2, att_bias,
                                                   WsfB, featWB, fusWbB,
                                                   c1, featb, ln_g, ln_b, outp, probs);
    } else {
        prep_kernel<<<129, 128, 0, stream>>>(selfW, selfb, fusW, fusb, Wsf, c1);
        label_kernel<<<3125, 256, 0, stream>>>(feat, clsW, clsb, attW1, attb1, attW2, attb2,
                                               att_bias, natt, probs);
        hipMemsetAsync(d_ws, 0,
                       (size_t)VV * NN * DD * sizeof(u16) + (size_t)VV * NN * sizeof(float),
                       stream);
        scatter_kernel<<<187500, 256, 0, stream>>>(esrc, edst, ew, feat, aggB, wsum);
        relgate_kernel<<<dim3(3125, 3), 256, 0, stream>>>(relW, relb, gateW, gateb, aggB, wsum);
        vatt_kernel<<<dim3(3125, 3), 128, 0, stream>>>(aggB, view_pref, vattW1, vattb1,
                                                       vattW2, vattb2, vsc);
        combine_kernel<<<12500, 256, 0, stream>>>(aggB, vsc, natt);
        final_kernel<<<3125, 256, 0, stream>>>(feat, aggB, Wsf, c1, fusW, featW, featb,
                                               ln_g, ln_b, outp);
    }
}